// Round 8
// baseline (346.107 us; speedup 1.0000x reference)
//
#include <hip/hip_runtime.h>
#include <math.h>

typedef unsigned short u16;
typedef __attribute__((ext_vector_type(8))) short bf16x8;
typedef __attribute__((ext_vector_type(4))) float f32x4;

#define C_DIM 1024
#define N_TOK 2048

static __device__ __forceinline__ u16 f2bf(float f) {
  union { float f; unsigned u; } v; v.f = f;
  unsigned r = v.u + 0x7fff + ((v.u >> 16) & 1);
  return (u16)(r >> 16);
}

// packed f32x2 -> bf16x2 (RNE, same rounding as f2bf) in ONE VALU op
static __device__ __forceinline__ unsigned cvt_pk_bf16(float lo, float hi) {
  unsigned r;
  asm("v_cvt_pk_bf16_f32 %0, %1, %2" : "=v"(r) : "v"(lo), "v"(hi));
  return r;
}

// ---------------- transpose + fp32->bf16 convert: W[K][N] -> WT[N][K] -----
__global__ __launch_bounds__(256) void convert_transpose(
    const float* __restrict__ W, u16* __restrict__ WT, int K, int N)
{
  __shared__ float tile[32][33];
  const int bx = blockIdx.x * 32;  // n
  const int by = blockIdx.y * 32;  // k
  const int tx = threadIdx.x & 31, ty = threadIdx.x >> 5;  // ty 0..7
  #pragma unroll
  for (int i = 0; i < 32; i += 8)
    tile[ty + i][tx] = W[(size_t)(by + ty + i) * N + bx + tx];
  __syncthreads();
  #pragma unroll
  for (int i = 0; i < 32; i += 8)
    WT[(size_t)(bx + ty + i) * K + by + tx] = f2bf(tile[tx][ty + i]);
}

// ---------------- LayerNorm: bf16 out (+ optional fp32 out) ---------------
__global__ __launch_bounds__(256) void ln_kernel(
    const float* __restrict__ x, const float* __restrict__ g,
    const float* __restrict__ b, u16* __restrict__ out,
    float* __restrict__ fout)
{
  const int row = blockIdx.x;
  const int t = threadIdx.x;
  const float* xr = x + (size_t)row * C_DIM;
  float4 xv = *(const float4*)(xr + t * 4);
  float s  = xv.x + xv.y + xv.z + xv.w;
  float ss = xv.x*xv.x + xv.y*xv.y + xv.z*xv.z + xv.w*xv.w;
  #pragma unroll
  for (int off = 1; off < 64; off <<= 1) {
    s  += __shfl_xor(s, off);
    ss += __shfl_xor(ss, off);
  }
  __shared__ float rs[4], rss[4];
  const int w = t >> 6;
  if ((t & 63) == 0) { rs[w] = s; rss[w] = ss; }
  __syncthreads();
  s  = rs[0] + rs[1] + rs[2] + rs[3];
  ss = rss[0] + rss[1] + rss[2] + rss[3];
  const float mean = s * (1.0f / C_DIM);
  const float var  = ss * (1.0f / C_DIM) - mean * mean;
  const float inv  = rsqrtf(var + 1e-5f);
  float4 gv = *(const float4*)(g + t * 4);
  float4 bv = *(const float4*)(b + t * 4);
  float4 o;
  o.x = (xv.x - mean) * inv * gv.x + bv.x;
  o.y = (xv.y - mean) * inv * gv.y + bv.y;
  o.z = (xv.z - mean) * inv * gv.z + bv.z;
  o.w = (xv.w - mean) * inv * gv.w + bv.w;
  ushort4 o4;
  o4.x = f2bf(o.x); o4.y = f2bf(o.y); o4.z = f2bf(o.z); o4.w = f2bf(o.w);
  *(ushort4*)(out + (size_t)row * C_DIM + t * 4) = o4;
  if (fout != nullptr)
    *(float4*)(fout + (size_t)row * C_DIM + t * 4) = o;
}

// ---------------- wbar[c][d] = mean over heads of k-weights ---------------
__global__ __launch_bounds__(256) void wbar_kernel(
    const float* __restrict__ qkv_w, float* __restrict__ wbar)
{
  const int idx = blockIdx.x * 256 + threadIdx.x;   // c*64 + d
  const int c = idx >> 6, d = idx & 63;
  float s = 0.f;
  #pragma unroll
  for (int h = 0; h < 16; h++)
    s += qkv_w[(size_t)c * 3072 + 1024 + h * 64 + d];
  wbar[idx] = s * (1.0f / 16.0f);
}

// ---------------- metric: 4 tokens/block, identical accumulation order ----
__global__ __launch_bounds__(256) void metric_gemm_kernel(
    const float* __restrict__ hf, const float* __restrict__ wbar,
    float* __restrict__ metric)
{
  __shared__ float hs[4][1024];
  const int n0 = blockIdx.x * 4;
  const int t = threadIdx.x;
  #pragma unroll
  for (int i = 0; i < 4; i++)
    *(float4*)&hs[i][t * 4] = *(const float4*)(hf + (size_t)(n0 + i) * 1024 + t * 4);
  __syncthreads();
  const int d = t & 63;
  const float* hsw = hs[t >> 6];
  float a0=0,a1=0,a2=0,a3=0,a4=0,a5=0,a6=0,a7=0;
  for (int c = 0; c < 1024; c += 8) {
    a0 += hsw[c+0] * wbar[(c+0)*64 + d];
    a1 += hsw[c+1] * wbar[(c+1)*64 + d];
    a2 += hsw[c+2] * wbar[(c+2)*64 + d];
    a3 += hsw[c+3] * wbar[(c+3)*64 + d];
    a4 += hsw[c+4] * wbar[(c+4)*64 + d];
    a5 += hsw[c+5] * wbar[(c+5)*64 + d];
    a6 += hsw[c+6] * wbar[(c+6)*64 + d];
    a7 += hsw[c+7] * wbar[(c+7)*64 + d];
  }
  float s = ((a0+a1)+(a2+a3)) + ((a4+a5)+(a6+a7));
  float sq = s * s;
  #pragma unroll
  for (int off = 1; off < 64; off <<= 1) sq += __shfl_xor(sq, off);
  metric[(size_t)(n0 + (t >> 6)) * 64 + d] = s / sqrtf(sq);
}

// ---------------- bf16 MFMA GEMM: C[M,N] = A[M,K] @ BT[N,K]^T -------------
// R6: LDS double-buffer, one barrier/iter (proven +6us).
// R7: BN templated. 128x128 tile for the three big GEMMs (m97/m93 geometry:
// 4 waves as 2x2, each wave owns 64x64 = 4x4 f32x4 acc, 32 MFMA/wave/K-step,
// 8 fragment reads per 16 MFMA = 2x the MFMA:LDS ratio of the old 128x64).
// LDS 64KB -> 2 blocks/CU, but grids are ~1.5 blocks/CU so the grid is the
// cap; dbuf covers latency intra-wave. BN=64 path (proj) is bit-identical
// to R6 (general formulas reduce to the old indices).
template<int BM, int BN, int SPLIT, bool BIAS, bool GELU, bool RES, bool OUT_BF16>
__global__ __launch_bounds__(256) void gemm_mfma(
    const u16* __restrict__ A,   // [>=gridDim.y*BM][K] bf16 (readable padding)
    const u16* __restrict__ BT,  // [N][K] bf16
    const float* __restrict__ bias, const float* __restrict__ res,
    void* __restrict__ Cout, int M, int N, int K)
{
  constexpr int TM = BM / 32;                 // 16x16 tiles per wave (rows)
  constexpr int TN = BN / 32;                 // 16x16 tiles per wave (cols)
  __shared__ u16 As[2][BM * 64] __attribute__((aligned(16)));
  __shared__ u16 Bs[2][BN * 64] __attribute__((aligned(16)));
  const int tid  = threadIdx.x;
  const int lane = tid & 63;
  const int w    = tid >> 6;
  const int bm = blockIdx.y * BM;
  const int bn = blockIdx.x * BN;
  const int wm = (w >> 1) * (BM / 2);
  const int wn = (w & 1) * (BN / 2);

  f32x4 acc[TM][TN] = {};

  const int rl = lane >> 3;                 // row-in-8-group
  const int cg = (lane & 7) ^ rl;           // swizzled source chunk

  const int kb = (K / SPLIT) * blockIdx.z;
  const int ke = kb + K / SPLIT;

#define GEMM_STAGE(buf, k0_)                                                   \
  {                                                                            \
    _Pragma("unroll")                                                          \
    for (int i = 0; i < BM / 32; i++) {                                        \
      const int r = w * (BM / 4) + i * 8 + rl;                                 \
      __builtin_amdgcn_global_load_lds(                                        \
          (const __attribute__((address_space(1))) void*)(A + (size_t)(bm + r) * K + (k0_) + cg * 8), \
          (__attribute__((address_space(3))) void*)(&As[buf][(w * (BM / 4) + i * 8) * 64]), \
          16, 0, 0);                                                           \
    }                                                                          \
    _Pragma("unroll")                                                          \
    for (int i = 0; i < BN / 32; i++) {                                        \
      const int r = w * (BN / 4) + i * 8 + rl;                                 \
      __builtin_amdgcn_global_load_lds(                                        \
          (const __attribute__((address_space(1))) void*)(BT + (size_t)(bn + r) * K + (k0_) + cg * 8), \
          (__attribute__((address_space(3))) void*)(&Bs[buf][(w * (BN / 4) + i * 8) * 64]), \
          16, 0, 0);                                                           \
    }                                                                          \
  }

  // prologue: stage first K-tile into buffer 0
  GEMM_STAGE(0, kb);
  __syncthreads();

  int cur = 0;
  for (int k0 = kb; k0 < ke; k0 += 64) {
    // issue next tile's loads into the other buffer (overlap compute)
    if (k0 + 64 < ke) GEMM_STAGE(cur ^ 1, k0 + 64);

    #pragma unroll
    for (int kk = 0; kk < 2; kk++) {
      bf16x8 af[TM], bfr[TN];
      const int slot = (kk * 4 + (lane >> 4)) ^ (lane & 7);
      #pragma unroll
      for (int i = 0; i < TM; i++)
        af[i] = *(const bf16x8*)&As[cur][(wm + i * 16 + (lane & 15)) * 64 + slot * 8];
      #pragma unroll
      for (int j = 0; j < TN; j++)
        bfr[j] = *(const bf16x8*)&Bs[cur][(wn + j * 16 + (lane & 15)) * 64 + slot * 8];
      __builtin_amdgcn_s_setprio(1);
      #pragma unroll
      for (int i = 0; i < TM; i++)
        #pragma unroll
        for (int j = 0; j < TN; j++)
          acc[i][j] = __builtin_amdgcn_mfma_f32_16x16x32_bf16(af[i], bfr[j], acc[i][j], 0, 0, 0);
      __builtin_amdgcn_s_setprio(0);
    }
    // one barrier/iter: (a) implicit vmcnt(0) makes buf[cur^1]'s staged
    // loads visible for next compute; (b) all waves done reading buf[cur]
    // so next iteration may overwrite it.
    __syncthreads();
    cur ^= 1;
  }
#undef GEMM_STAGE

  if constexpr (SPLIT > 1) {
    float* Cf = (float*)Cout;
    #pragma unroll
    for (int i = 0; i < TM; i++)
      #pragma unroll
      for (int r = 0; r < 4; r++) {
        const int m = bm + wm + i * 16 + (lane >> 4) * 4 + r;
        if (m < M) {
          #pragma unroll
          for (int j = 0; j < TN; j++) {
            const int n = bn + wn + j * 16 + (lane & 15);
            atomicAdd(&Cf[(size_t)m * N + n], acc[i][j][r]);
          }
        }
      }
  } else {
    #pragma unroll
    for (int i = 0; i < TM; i++) {
      #pragma unroll
      for (int r = 0; r < 4; r++) {
        const int m = bm + wm + i * 16 + (lane >> 4) * 4 + r;
        if (m < M) {
          #pragma unroll
          for (int j = 0; j < TN; j++) {
            const int n = bn + wn + j * 16 + (lane & 15);
            float v = acc[i][j][r];
            if (BIAS) v += bias[n];
            if (GELU) v = 0.5f * v * (1.0f + erff(v * 0.70710678118654752f));
            if (RES)  v += res[(size_t)m * N + n];
            if (OUT_BF16) ((u16*)Cout)[(size_t)m * N + n] = f2bf(v);
            else          ((float*)Cout)[(size_t)m * N + n] = v;
          }
        }
      }
    }
  }
}

// ---------------- split-K epilogue: out = acc + bias + out (in-place res) -
__global__ __launch_bounds__(256) void splitk_epilogue_kernel(
    const float* __restrict__ acc, const float* __restrict__ bias,
    float* __restrict__ out, int M)
{
  const int idx = blockIdx.x * 256 + threadIdx.x;   // float4 index
  if (idx >= M * 256) return;
  float4 a = *(const float4*)(acc + idx * 4);
  float4 bv = *(const float4*)(bias + (idx & 255) * 4);
  float4 o = *(const float4*)(out + idx * 4);
  o.x += a.x + bv.x; o.y += a.y + bv.y; o.z += a.z + bv.z; o.w += a.w + bv.w;
  *(float4*)(out + idx * 4) = o;
}

// ---------------- V transpose: qkv v-part -> vt[h][d][token] (bf16) -------
__global__ __launch_bounds__(256) void vt_kernel(
    const u16* __restrict__ qkv, u16* __restrict__ vt)
{
  const int h  = blockIdx.y;
  const int t0 = blockIdx.x * 64;
  const int tid = threadIdx.x;
  __shared__ u16 tile[64][72];
  const int row = tid >> 3;   // 0..31
  const int ch  = tid & 7;
  #pragma unroll
  for (int i = 0; i < 2; i++) {
    const int tok = row + i * 32;
    *(bf16x8*)&tile[tok][ch * 8] =
        *(const bf16x8*)(qkv + (size_t)(t0 + tok) * 3072 + 2048 + h * 64 + ch * 8);
  }
  __syncthreads();
  #pragma unroll
  for (int i = 0; i < 2; i++) {
    const int d = row + i * 32;
    u16 tmp[8];
    #pragma unroll
    for (int j = 0; j < 8; j++) tmp[j] = tile[ch * 8 + j][d];
    *(bf16x8*)(vt + (size_t)(h * 64 + d) * 2048 + t0 + ch * 8) = *(bf16x8*)tmp;
  }
}

// ---------------- MFMA flash attention, no-max softmax, S^T trick ---------
// R4 structure (proven 50.5->43.9): K double-buffered, V single-buffered,
// 2 barriers/iter, 4 blocks/CU. Latency-bound on its serial chain; parked.
template<int SPLIT>
__global__ __launch_bounds__(256) void attn_mfma(
    const u16* __restrict__ qkv, const u16* __restrict__ vt,
    const float* __restrict__ sz, float* __restrict__ opart,
    float* __restrict__ lpart)
{
  const int h   = blockIdx.y;
  const int q0  = blockIdx.x * 64;
  const int tid = threadIdx.x;
  const int lane = tid & 63;
  const int w    = tid >> 6;
  const int col  = lane & 15;
  const int quad = lane >> 4;

  __shared__ u16 Ks [2][64 * 64] __attribute__((aligned(16))); // [key][d] swizzled, dbuf
  __shared__ u16 Vts[64 * 64] __attribute__((aligned(16)));    // [d][key] swizzled, single
  __shared__ u16 Ps[4][16 * 72] __attribute__((aligned(16)));  // per-wave P[q][key]
  __shared__ float lball[N_TOK / SPLIT];                       // log2(size) per key

  bf16x8 qf[2];
  {
    const u16* qp = qkv + (size_t)(q0 + w * 16 + col) * 3072 + h * 64 + quad * 8;
    qf[0] = *(const bf16x8*)(qp);
    qf[1] = *(const bf16x8*)(qp + 32);
  }

  float l_lane = 0.f;          // all partials belong to q = q0 + w*16 + col
  f32x4 oacc[4] = {};

  const int rl = lane >> 3;
  const int cg = (lane & 7) ^ rl;
  const int kb = blockIdx.z * (N_TOK / SPLIT);
  const int ke = kb + N_TOK / SPLIT;

  // 0.125 * log2(e): fold the 1/8 scale and the nat->log2 conversion together
  constexpr float kScaleLog2e = 0.18033688011112042f;

  // ---- prologue: stage K[0], V[0]; precompute ALL log2(size) once ----
  #pragma unroll
  for (int i = 0; i < 2; i++) {
    const int r = w * 16 + i * 8 + rl;
    __builtin_amdgcn_global_load_lds(
        (const __attribute__((address_space(1))) void*)(qkv + (size_t)(kb + r) * 3072 + 1024 + h * 64 + cg * 8),
        (__attribute__((address_space(3))) void*)(&Ks[0][(w * 16 + i * 8) * 64]),
        16, 0, 0);
    __builtin_amdgcn_global_load_lds(
        (const __attribute__((address_space(1))) void*)(vt + (size_t)(h * 64 + r) * 2048 + kb + cg * 8),
        (__attribute__((address_space(3))) void*)(&Vts[(w * 16 + i * 8) * 64]),
        16, 0, 0);
  }
  #pragma unroll
  for (int i = tid; i < N_TOK / SPLIT; i += 256)
    lball[i] = __builtin_amdgcn_logf(sz[kb + i]);   // v_log_f32 = log2
  __syncthreads();   // drains prologue staging (vmcnt + lgkmcnt)

  int cur = 0;
  for (int kt = kb; kt < ke; kt += 64) {
    const int nxt = cur ^ 1;
    const bool has_next = (kt + 64 < ke);   // block-uniform

    // ---- issue NEXT K tile into the other K buffer (full-iter overlap) ---
    if (has_next) {
      #pragma unroll
      for (int i = 0; i < 2; i++) {
        const int r = w * 16 + i * 8 + rl;
        __builtin_amdgcn_global_load_lds(
            (const __attribute__((address_space(1))) void*)(qkv + (size_t)(kt + 64 + r) * 3072 + 1024 + h * 64 + cg * 8),
            (__attribute__((address_space(3))) void*)(&Ks[nxt][(w * 16 + i * 8) * 64]),
            16, 0, 0);
      }
    }

    // ---- S^T = K Q^T : lane holds S^T[key = jt*16+quad*4+r][q = col] ----
    const u16* Kc = Ks[cur];
    f32x4 sacc[4] = {};
    #pragma unroll
    for (int kk = 0; kk < 2; kk++) {
      const int slot = (kk * 4 + quad) ^ (lane & 7);
      bf16x8 kf[4];
      #pragma unroll
      for (int jt = 0; jt < 4; jt++)
        kf[jt] = *(const bf16x8*)&Kc[(jt * 16 + col) * 64 + slot * 8];
      __builtin_amdgcn_s_setprio(1);
      #pragma unroll
      for (int jt = 0; jt < 4; jt++)
        sacc[jt] = __builtin_amdgcn_mfma_f32_16x16x32_bf16(kf[jt], qf[kk], sacc[jt], 0, 0, 0);
      __builtin_amdgcn_s_setprio(0);
    }

    // exp2-domain softmax weights + packed P-writes (4x b64), l per-lane
    u16* pw = Ps[w];
    const float* lbp = &lball[kt - kb];
    #pragma unroll
    for (int jt = 0; jt < 4; jt++) {
      float4 lb4 = *(const float4*)&lbp[jt * 16 + quad * 4];
      const float p0 = __builtin_amdgcn_exp2f(fmaf(sacc[jt][0], kScaleLog2e, lb4.x));
      const float p1 = __builtin_amdgcn_exp2f(fmaf(sacc[jt][1], kScaleLog2e, lb4.y));
      const float p2 = __builtin_amdgcn_exp2f(fmaf(sacc[jt][2], kScaleLog2e, lb4.z));
      const float p3 = __builtin_amdgcn_exp2f(fmaf(sacc[jt][3], kScaleLog2e, lb4.w));
      l_lane += (p0 + p1) + (p2 + p3);
      uint2 pkk;
      pkk.x = cvt_pk_bf16(p0, p1);
      pkk.y = cvt_pk_bf16(p2, p3);
      *(uint2*)&pw[col * 72 + jt * 16 + quad * 4] = pkk;
    }
    // same-wave LDS RAW -> lgkmcnt (verified pattern); rows 144B apart
    bf16x8 pf[2];
    #pragma unroll
    for (int kk = 0; kk < 2; kk++)
      pf[kk] = *(const bf16x8*)&pw[col * 72 + kk * 32 + quad * 8];

    // barrier A: implicit vmcnt(0) drains V[this tile] (issued last iter,
    // had the whole QK+softmax above to load) + K[nxt] (usually done too)
    __syncthreads();

    // O += P V (A = P rows=q, B = V^T)
    #pragma unroll
    for (int kk = 0; kk < 2; kk++) {
      const int slot = (kk * 4 + quad) ^ (lane & 7);
      bf16x8 vf[4];
      #pragma unroll
      for (int nt = 0; nt < 4; nt++)
        vf[nt] = *(const bf16x8*)&Vts[(nt * 16 + col) * 64 + slot * 8];
      __builtin_amdgcn_s_setprio(1);
      #pragma unroll
      for (int nt = 0; nt < 4; nt++)
        oacc[nt] = __builtin_amdgcn_mfma_f32_16x16x32_bf16(pf[kk], vf[nt], oacc[nt], 0, 0, 0);
      __builtin_amdgcn_s_setprio(0);
    }

    // barrier B: all waves done reading Vts -> safe to overwrite
    __syncthreads();

    // ---- issue NEXT V tile into the single V buffer (overlaps next QK) --
    if (has_next) {
      #pragma unroll
      for (int i = 0; i < 2; i++) {
        const int r = w * 16 + i * 8 + rl;
        __builtin_amdgcn_global_load_lds(
            (const __attribute__((address_space(1))) void*)(vt + (size_t)(h * 64 + r) * 2048 + kt + 64 + cg * 8),
            (__attribute__((address_space(3))) void*)(&Vts[(w * 16 + i * 8) * 64]),
            16, 0, 0);
      }
    }
    cur = nxt;
  }

  // l: sum the 4 quads of each col group (once)
  l_lane += __shfl_xor(l_lane, 16);
  l_lane += __shfl_xor(l_lane, 32);

  #pragma unroll
  for (int r = 0; r < 4; r++) {
    const int q = q0 + w * 16 + quad * 4 + r;
    float* op = opart + (size_t)q * 1024 + h * 64 + col;
    #pragma unroll
    for (int nt = 0; nt < 4; nt++)
      atomicAdd(op + nt * 16, oacc[nt][r]);
  }
  if (quad == 0)
    atomicAdd(&lpart[(q0 + w * 16 + col) * 16 + h], l_lane);
}

// ---------------- normalize O by l, emit bf16 xa --------------------------
__global__ __launch_bounds__(256) void attn_norm_kernel(
    const float* __restrict__ opart, const float* __restrict__ lpart,
    u16* __restrict__ xa)
{
  const int q = blockIdx.x;
  const int c = threadIdx.x * 4;
  float4 o = *(const float4*)(opart + (size_t)q * 1024 + c);
  const float inv = 1.0f / lpart[q * 16 + (c >> 6)];
  ushort4 o4;
  o4.x = f2bf(o.x * inv); o4.y = f2bf(o.y * inv);
  o4.z = f2bf(o.z * inv); o4.w = f2bf(o.w * inv);
  *(ushort4*)(xa + (size_t)q * 1024 + c) = o4;
}

// ---------------- merge scores: 4 src/block, identical comparator ---------
__global__ __launch_bounds__(256) void merge_score_kernel(
    const float* __restrict__ metric, const float* __restrict__ thr,
    int* __restrict__ mask, int* __restrict__ node)
{
  const int s0 = blockIdx.x * 4;
  const int t = threadIdx.x;
  __shared__ float a[4][64];
  a[t >> 6][t & 63] = metric[(size_t)(2 * (s0 + (t >> 6))) * 64 + (t & 63)];
  __syncthreads();
  float best[4] = {-INFINITY, -INFINITY, -INFINITY, -INFINITY};
  int besti[4] = {0, 0, 0, 0};
  for (int m = t; m < 1024; m += 256) {
    const float* bp = metric + (size_t)(2 * m + 1) * 64;
    float s[4] = {0.f, 0.f, 0.f, 0.f};
    #pragma unroll
    for (int d = 0; d < 64; d += 4) {
      float4 bv = *(const float4*)(bp + d);
      #pragma unroll
      for (int j = 0; j < 4; j++) {
        float4 av = *(const float4*)&a[j][d];
        s[j] += av.x*bv.x + av.y*bv.y + av.z*bv.z + av.w*bv.w;
      }
    }
    #pragma unroll
    for (int j = 0; j < 4; j++)
      if (s[j] > best[j]) { best[j] = s[j]; besti[j] = m; }   // ascending m
  }
  #pragma unroll
  for (int j = 0; j < 4; j++) {
    float b = best[j]; int bi = besti[j];
    #pragma unroll
    for (int off = 1; off < 64; off <<= 1) {
      float ov = __shfl_xor(b, off);
      int   oi = __shfl_xor(bi, off);
      if (ov > b || (ov == b && oi < bi)) { b = ov; bi = oi; }
    }
    best[j] = b; besti[j] = bi;
  }
  __shared__ float bw_[4][4]; __shared__ int biw_[4][4];
  const int wv = t >> 6;
  if ((t & 63) == 0) {
    #pragma unroll
    for (int j = 0; j < 4; j++) { bw_[wv][j] = best[j]; biw_[wv][j] = besti[j]; }
  }
  __syncthreads();
  if (t < 4) {
    const int j = t;
    float b = bw_[0][j]; int bi = biw_[0][j];
    for (int ww = 1; ww < 4; ww++)
      if (bw_[ww][j] > b || (bw_[ww][j] == b && biw_[ww][j] < bi)) { b = bw_[ww][j]; bi = biw_[ww][j]; }
    const int n = s0 + j;
    if (n == 0) { mask[0] = 0; node[0] = 0; }
    else { mask[n] = (b > thr[0]) ? 1 : 0; node[n] = bi; }
  }
}

// ---------------- exclusive prefix-sum of !mask (1024 entries) ------------
__global__ __launch_bounds__(1024) void scan_kernel(
    const int* __restrict__ mask, int* __restrict__ pos)
{
  __shared__ int s[1024];
  const int t = threadIdx.x;
  const int v0 = mask[t] ? 0 : 1;
  s[t] = v0;
  __syncthreads();
  for (int off = 1; off < 1024; off <<= 1) {
    int v = (t >= off) ? s[t - off] : 0;
    __syncthreads();
    s[t] += v;
    __syncthreads();
  }
  pos[t] = s[t] - v0;
}

// ---------------- build merged rows (unm gather + dst base) ---------------
__global__ __launch_bounds__(256) void build_kernel(
    const float* __restrict__ xres, const float* __restrict__ sz,
    const int* __restrict__ mask, const int* __restrict__ pos,
    float* __restrict__ xm, float* __restrict__ sizem, int U)
{
  const int b = blockIdx.x;
  const int t = threadIdx.x;
  int srow, orow;
  if (b < 1024) { srow = 2 * b + 1; orow = U + b; }
  else {
    const int i = b - 1024;
    if (mask[i]) return;
    srow = 2 * i; orow = pos[i];
  }
  const float ssz = sz[srow];
  const float* xp = xres + (size_t)srow * 1024;
  float* op = xm + (size_t)orow * 1024;
  const int c = t * 4;
  float4 v = *(const float4*)(xp + c);
  v.x *= ssz; v.y *= ssz; v.z *= ssz; v.w *= ssz;
  *(float4*)(op + c) = v;
  if (t == 0) sizem[orow] = ssz;
}

// ---------------- scatter-add merged src tokens into dst rows -------------
__global__ __launch_bounds__(256) void merge_add_kernel(
    const float* __restrict__ xres, const float* __restrict__ sz,
    const int* __restrict__ mask, const int* __restrict__ node,
    float* __restrict__ xm, float* __restrict__ sizem, int U)
{
  const int i = blockIdx.x;
  if (!mask[i]) return;
  const int t = threadIdx.x;
  const int srow = 2 * i;
  const int orow = U + node[i];
  const float ssz = sz[srow];
  const float* xp = xres + (size_t)srow * 1024;
  float* op = xm + (size_t)orow * 1024;
  for (int c = t; c < 1024; c += 256)
    atomicAdd(op + c, xp[c] * ssz);
  if (t == 0) atomicAdd(sizem + orow, ssz);
}

// ---------------- divide by size; emit x and size outputs -----------------
__global__ __launch_bounds__(256) void divide_kernel(
    const float* __restrict__ xm, const float* __restrict__ sizem,
    float* __restrict__ outx, float* __restrict__ outs, int M)
{
  const int total = M * 1024;
  for (int idx = blockIdx.x * 256 + threadIdx.x; idx < total; idx += gridDim.x * 256)
    outx[idx] = xm[idx] / sizem[idx >> 10];
  const int idx2 = blockIdx.x * 256 + threadIdx.x;
  if (idx2 < M) outs[idx2] = sizem[idx2];
}

extern "C" void kernel_launch(void* const* d_in, const int* in_sizes, int n_in,
                              void* d_out, int out_size, void* d_ws, size_t ws_size,
                              hipStream_t stream) {
  const float* x      = (const float*)d_in[0];
  const float* sz     = (const float*)d_in[1];
  const float* qkv_w  = (const float*)d_in[2];
  const float* proj_w = (const float*)d_in[3];
  const float* proj_b = (const float*)d_in[4];
  const float* ln1_g  = (const float*)d_in[5];
  const float* ln1_b  = (const float*)d_in[6];
  const float* ln2_g  = (const float*)d_in[7];
  const float* ln2_b  = (const float*)d_in[8];
  const float* fc1_w  = (const float*)d_in[9];
  const float* fc1_b  = (const float*)d_in[10];
  const float* fc2_w  = (const float*)d_in[11];
  const float* fc2_b  = (const float*)d_in[12];
  const float* thr    = (const float*)d_in[13];

  const int M = out_size / 1025;
  const int U = M - 1024;
  const size_t MB = 1u << 20;
  const size_t KB = 1u << 10;

  // workspace overlays (lifetimes sequential on `stream`):
  //  early: w_qkvT[0,6) -> b_vt[0,4); wbar/met/mask@[6,7); lpart@[7,7.13);
  //         w_projT[8,10); b_qkv[10,22) -> b_xm[10,18);
  //         b_hf[22,30) -> opart[22,30) -> b_xres[22,30);
  //         b_h[30,34) -> b_xa[30,34)
  //  late:  w_fc1T[0,8); b_g[8,21); w_fc2T[21,29); facc[29,35); b_h2[35,39)
  char* ws = (char*)d_ws;
  u16*   w_qkvT  = (u16*)(ws + 0);
  float* b_wbar  = (float*)(ws + 6 * MB);
  float* b_met   = (float*)(ws + 6 * MB + 256 * KB);
  int*   b_mask  = (int*)(ws + 6 * MB + 768 * KB);
  int*   b_node  = b_mask + 1024;
  int*   b_pos   = b_node + 1024;
  float* b_szm   = (float*)(b_pos + 1024);
  float* b_lpart = (float*)(ws + 7 * MB);
  u16*   w_projT = (u16*)(ws + 8 * MB);
  u16*   b_qkv   = (u16*)(ws + 10 * MB);
  float* b_xm    = (float*)(ws + 10 * MB);   // over dead b_qkv
  float* b_hf    = (float*)(ws + 22 * MB);
  float* b_opart = (float*)(ws + 22 * MB);   // over dead b_hf
  float* b_xres  = (float*)(ws + 22 * MB);   // over dead opart
  u16*   b_h     = (u16*)(ws + 30 * MB);
  u16*   b_xa    = (u16*)(ws + 30 * MB);
  u16*   b_vt    = (u16*)(ws + 0);
  u16*   w_fc1T  = (u16*)(ws + 0);
  u16*   b_g     = (u16*)(ws + 8 * MB);
  u16*   w_fc2T  = (u16*)(ws + 21 * MB);
  float* b_facc  = (float*)(ws + 29 * MB);
  u16*   b_h2    = (u16*)(ws + 35 * MB);

  float* outx = (float*)d_out;
  float* outs = outx + (size_t)M * 1024;

  // 1. LN1 -> bf16 (for MFMA) + fp32 (for exact metric path)
  ln_kernel<<<2048, 256, 0, stream>>>(x, ln1_g, ln1_b, b_h, b_hf);
  // 2. mean-over-heads k-weights (fp32)
  wbar_kernel<<<256, 256, 0, stream>>>(qkv_w, b_wbar);
  // 3. weight converts for attention half
  convert_transpose<<<dim3(96, 32), 256, 0, stream>>>(qkv_w, w_qkvT, 1024, 3072);
  convert_transpose<<<dim3(32, 32), 256, 0, stream>>>(proj_w, w_projT, 1024, 1024);
  // 4. QKV GEMM (bf16 MFMA, 128x128 dbuf tile) — 384 blocks
  gemm_mfma<128, 128, 1, false, false, false, true><<<dim3(24, 16), 256, 0, stream>>>(
      b_h, w_qkvT, nullptr, nullptr, b_qkv, 2048, 3072, 1024);
  // 4b. V transpose for MFMA attention (overwrites dead w_qkvT)
  vt_kernel<<<dim3(32, 16), 256, 0, stream>>>(b_qkv, b_vt);
  // 5. exact fp32 metric (decoupled from bf16 path — merge decisions stable)
  metric_gemm_kernel<<<512, 256, 0, stream>>>(b_hf, b_wbar, b_met);
  // 6. MFMA attention: K-dbuf + single-V pipeline + lb-precompute + setprio
  hipMemsetAsync(b_opart, 0, 8 * MB, stream);
  hipMemsetAsync(b_lpart, 0, 128 * KB, stream);
  attn_mfma<2><<<dim3(32, 16, 2), 256, 0, stream>>>(b_qkv, b_vt, sz, b_opart, b_lpart);
  attn_norm_kernel<<<2048, 256, 0, stream>>>(b_opart, b_lpart, b_xa);
  // 7. proj GEMM + bias + residual(x) -> xres fp32 — 64x64 tile (grid too
  //    small for 128x128: 8x16=128 blocks = 0.5/CU), 512 blocks
  gemm_mfma<64, 64, 1, true, false, true, false><<<dim3(16, 32), 256, 0, stream>>>(
      b_xa, w_projT, proj_b, x, b_xres, 2048, 1024, 1024);
  // 8-11. merge pipeline
  merge_score_kernel<<<256, 256, 0, stream>>>(b_met, thr, b_mask, b_node);
  scan_kernel<<<1, 1024, 0, stream>>>(b_mask, b_pos);
  build_kernel<<<2048, 256, 0, stream>>>(b_xres, sz, b_mask, b_pos, b_xm, b_szm, U);
  merge_add_kernel<<<1024, 256, 0, stream>>>(b_xres, sz, b_mask, b_node, b_xm, b_szm, U);
  // 12. divide + emit outputs
  divide_kernel<<<2048, 256, 0, stream>>>(b_xm, b_szm, outx, outs, M);
  // 13. late weight converts (into now-dead regions)
  convert_transpose<<<dim3(128, 32), 256, 0, stream>>>(fc1_w, w_fc1T, 1024, 4096);
  convert_transpose<<<dim3(32, 128), 256, 0, stream>>>(fc2_w, w_fc2T, 4096, 1024);
  // 14. LN2 -> bf16
  ln_kernel<<<M, 256, 0, stream>>>(outx, ln2_g, ln2_b, b_h2, nullptr);
  // 15. fc1 + bias + exact GELU -> bf16 — 128x128 tile, 32 x ceil(M/128)
  gemm_mfma<128, 128, 1, true, true, false, true><<<dim3(32, (M + 127) / 128), 256, 0, stream>>>(
      b_h2, w_fc1T, fc1_b, nullptr, b_g, M, 4096, 1024);
  // 16. fc2 split-K=4, 128x128 tile — 8 x ceil(M/128) x 4
  hipMemsetAsync(b_facc, 0, (size_t)M * 1024 * 4, stream);
  gemm_mfma<128, 128, 4, false, false, false, false><<<dim3(8, (M + 127) / 128, 4), 256, 0, stream>>>(
      b_g, w_fc2T, nullptr, nullptr, b_facc, M, 1024, 4096);
  // 17. fc2 epilogue: outx += facc + bias (residual in-place)
  splitk_epilogue_kernel<<<(M * 256 + 255) / 256, 256, 0, stream>>>(
      b_facc, fc2_b, outx, M);
  (void)in_sizes; (void)n_in; (void)ws_size;
}

// Round 9
// 315.978 us; speedup vs baseline: 1.0954x; 1.0954x over previous
//
#include <hip/hip_runtime.h>
#include <math.h>

typedef unsigned short u16;
typedef __attribute__((ext_vector_type(8))) short bf16x8;
typedef __attribute__((ext_vector_type(4))) float f32x4;

#define C_DIM 1024
#define N_TOK 2048

static __device__ __forceinline__ u16 f2bf(float f) {
  union { float f; unsigned u; } v; v.f = f;
  unsigned r = v.u + 0x7fff + ((v.u >> 16) & 1);
  return (u16)(r >> 16);
}

// packed f32x2 -> bf16x2 (RNE, same rounding as f2bf) in ONE VALU op
static __device__ __forceinline__ unsigned cvt_pk_bf16(float lo, float hi) {
  unsigned r;
  asm("v_cvt_pk_bf16_f32 %0, %1, %2" : "=v"(r) : "v"(lo), "v"(hi));
  return r;
}

// ---------------- transpose + fp32->bf16 convert: W[K][N] -> WT[N][K] -----
__global__ __launch_bounds__(256) void convert_transpose(
    const float* __restrict__ W, u16* __restrict__ WT, int K, int N)
{
  __shared__ float tile[32][33];
  const int bx = blockIdx.x * 32;  // n
  const int by = blockIdx.y * 32;  // k
  const int tx = threadIdx.x & 31, ty = threadIdx.x >> 5;  // ty 0..7
  #pragma unroll
  for (int i = 0; i < 32; i += 8)
    tile[ty + i][tx] = W[(size_t)(by + ty + i) * N + bx + tx];
  __syncthreads();
  #pragma unroll
  for (int i = 0; i < 32; i += 8)
    WT[(size_t)(bx + ty + i) * K + by + tx] = f2bf(tile[tx][ty + i]);
}

// ---------------- LayerNorm: bf16 out (+ optional fp32 out) ---------------
__global__ __launch_bounds__(256) void ln_kernel(
    const float* __restrict__ x, const float* __restrict__ g,
    const float* __restrict__ b, u16* __restrict__ out,
    float* __restrict__ fout)
{
  const int row = blockIdx.x;
  const int t = threadIdx.x;
  const float* xr = x + (size_t)row * C_DIM;
  float4 xv = *(const float4*)(xr + t * 4);
  float s  = xv.x + xv.y + xv.z + xv.w;
  float ss = xv.x*xv.x + xv.y*xv.y + xv.z*xv.z + xv.w*xv.w;
  #pragma unroll
  for (int off = 1; off < 64; off <<= 1) {
    s  += __shfl_xor(s, off);
    ss += __shfl_xor(ss, off);
  }
  __shared__ float rs[4], rss[4];
  const int w = t >> 6;
  if ((t & 63) == 0) { rs[w] = s; rss[w] = ss; }
  __syncthreads();
  s  = rs[0] + rs[1] + rs[2] + rs[3];
  ss = rss[0] + rss[1] + rss[2] + rss[3];
  const float mean = s * (1.0f / C_DIM);
  const float var  = ss * (1.0f / C_DIM) - mean * mean;
  const float inv  = rsqrtf(var + 1e-5f);
  float4 gv = *(const float4*)(g + t * 4);
  float4 bv = *(const float4*)(b + t * 4);
  float4 o;
  o.x = (xv.x - mean) * inv * gv.x + bv.x;
  o.y = (xv.y - mean) * inv * gv.y + bv.y;
  o.z = (xv.z - mean) * inv * gv.z + bv.z;
  o.w = (xv.w - mean) * inv * gv.w + bv.w;
  ushort4 o4;
  o4.x = f2bf(o.x); o4.y = f2bf(o.y); o4.z = f2bf(o.z); o4.w = f2bf(o.w);
  *(ushort4*)(out + (size_t)row * C_DIM + t * 4) = o4;
  if (fout != nullptr)
    *(float4*)(fout + (size_t)row * C_DIM + t * 4) = o;
}

// ---------------- wbar[c][d] = mean over heads of k-weights ---------------
__global__ __launch_bounds__(256) void wbar_kernel(
    const float* __restrict__ qkv_w, float* __restrict__ wbar)
{
  const int idx = blockIdx.x * 256 + threadIdx.x;   // c*64 + d
  const int c = idx >> 6, d = idx & 63;
  float s = 0.f;
  #pragma unroll
  for (int h = 0; h < 16; h++)
    s += qkv_w[(size_t)c * 3072 + 1024 + h * 64 + d];
  wbar[idx] = s * (1.0f / 16.0f);
}

// ---------------- metric: 4 tokens/block, identical accumulation order ----
__global__ __launch_bounds__(256) void metric_gemm_kernel(
    const float* __restrict__ hf, const float* __restrict__ wbar,
    float* __restrict__ metric)
{
  __shared__ float hs[4][1024];
  const int n0 = blockIdx.x * 4;
  const int t = threadIdx.x;
  #pragma unroll
  for (int i = 0; i < 4; i++)
    *(float4*)&hs[i][t * 4] = *(const float4*)(hf + (size_t)(n0 + i) * 1024 + t * 4);
  __syncthreads();
  const int d = t & 63;
  const float* hsw = hs[t >> 6];
  float a0=0,a1=0,a2=0,a3=0,a4=0,a5=0,a6=0,a7=0;
  for (int c = 0; c < 1024; c += 8) {
    a0 += hsw[c+0] * wbar[(c+0)*64 + d];
    a1 += hsw[c+1] * wbar[(c+1)*64 + d];
    a2 += hsw[c+2] * wbar[(c+2)*64 + d];
    a3 += hsw[c+3] * wbar[(c+3)*64 + d];
    a4 += hsw[c+4] * wbar[(c+4)*64 + d];
    a5 += hsw[c+5] * wbar[(c+5)*64 + d];
    a6 += hsw[c+6] * wbar[(c+6)*64 + d];
    a7 += hsw[c+7] * wbar[(c+7)*64 + d];
  }
  float s = ((a0+a1)+(a2+a3)) + ((a4+a5)+(a6+a7));
  float sq = s * s;
  #pragma unroll
  for (int off = 1; off < 64; off <<= 1) sq += __shfl_xor(sq, off);
  metric[(size_t)(n0 + (t >> 6)) * 64 + d] = s / sqrtf(sq);
}

// ---------------- bf16 MFMA GEMM: C[M,N] = A[M,K] @ BT[N,K]^T -------------
// R6 geometry (proven 325.5us): BN=64, LDS double-buffer, one barrier/iter.
// R8's 128x128 tile REGRESSED (-20us): 384-block grid = 1.5 blk/CU at the
// 64KB-LDS 2/CU cap -> load imbalance (75% makespan) + 8 vs 12 waves/CU.
// Block-count granularity beats per-block MFMA:LDS ratio on these grids.
template<int BM, int BN, int SPLIT, bool BIAS, bool GELU, bool RES, bool OUT_BF16>
__global__ __launch_bounds__(256) void gemm_mfma(
    const u16* __restrict__ A,   // [>=gridDim.y*BM][K] bf16 (readable padding)
    const u16* __restrict__ BT,  // [N][K] bf16
    const float* __restrict__ bias, const float* __restrict__ res,
    void* __restrict__ Cout, int M, int N, int K)
{
  constexpr int TM = BM / 32;                 // 16x16 tiles per wave (rows)
  constexpr int TN = BN / 32;                 // 16x16 tiles per wave (cols)
  __shared__ u16 As[2][BM * 64] __attribute__((aligned(16)));
  __shared__ u16 Bs[2][BN * 64] __attribute__((aligned(16)));
  const int tid  = threadIdx.x;
  const int lane = tid & 63;
  const int w    = tid >> 6;
  const int bm = blockIdx.y * BM;
  const int bn = blockIdx.x * BN;
  const int wm = (w >> 1) * (BM / 2);
  const int wn = (w & 1) * (BN / 2);

  f32x4 acc[TM][TN] = {};

  const int rl = lane >> 3;                 // row-in-8-group
  const int cg = (lane & 7) ^ rl;           // swizzled source chunk

  const int kb = (K / SPLIT) * blockIdx.z;
  const int ke = kb + K / SPLIT;

#define GEMM_STAGE(buf, k0_)                                                   \
  {                                                                            \
    _Pragma("unroll")                                                          \
    for (int i = 0; i < BM / 32; i++) {                                        \
      const int r = w * (BM / 4) + i * 8 + rl;                                 \
      __builtin_amdgcn_global_load_lds(                                        \
          (const __attribute__((address_space(1))) void*)(A + (size_t)(bm + r) * K + (k0_) + cg * 8), \
          (__attribute__((address_space(3))) void*)(&As[buf][(w * (BM / 4) + i * 8) * 64]), \
          16, 0, 0);                                                           \
    }                                                                          \
    _Pragma("unroll")                                                          \
    for (int i = 0; i < BN / 32; i++) {                                        \
      const int r = w * (BN / 4) + i * 8 + rl;                                 \
      __builtin_amdgcn_global_load_lds(                                        \
          (const __attribute__((address_space(1))) void*)(BT + (size_t)(bn + r) * K + (k0_) + cg * 8), \
          (__attribute__((address_space(3))) void*)(&Bs[buf][(w * (BN / 4) + i * 8) * 64]), \
          16, 0, 0);                                                           \
    }                                                                          \
  }

  // prologue: stage first K-tile into buffer 0
  GEMM_STAGE(0, kb);
  __syncthreads();

  int cur = 0;
  for (int k0 = kb; k0 < ke; k0 += 64) {
    // issue next tile's loads into the other buffer (overlap compute)
    if (k0 + 64 < ke) GEMM_STAGE(cur ^ 1, k0 + 64);

    #pragma unroll
    for (int kk = 0; kk < 2; kk++) {
      bf16x8 af[TM], bfr[TN];
      const int slot = (kk * 4 + (lane >> 4)) ^ (lane & 7);
      #pragma unroll
      for (int i = 0; i < TM; i++)
        af[i] = *(const bf16x8*)&As[cur][(wm + i * 16 + (lane & 15)) * 64 + slot * 8];
      #pragma unroll
      for (int j = 0; j < TN; j++)
        bfr[j] = *(const bf16x8*)&Bs[cur][(wn + j * 16 + (lane & 15)) * 64 + slot * 8];
      __builtin_amdgcn_s_setprio(1);
      #pragma unroll
      for (int i = 0; i < TM; i++)
        #pragma unroll
        for (int j = 0; j < TN; j++)
          acc[i][j] = __builtin_amdgcn_mfma_f32_16x16x32_bf16(af[i], bfr[j], acc[i][j], 0, 0, 0);
      __builtin_amdgcn_s_setprio(0);
    }
    // one barrier/iter: (a) implicit vmcnt(0) makes buf[cur^1]'s staged
    // loads visible for next compute; (b) all waves done reading buf[cur]
    // so next iteration may overwrite it.
    __syncthreads();
    cur ^= 1;
  }
#undef GEMM_STAGE

  if constexpr (SPLIT > 1) {
    float* Cf = (float*)Cout;
    #pragma unroll
    for (int i = 0; i < TM; i++)
      #pragma unroll
      for (int r = 0; r < 4; r++) {
        const int m = bm + wm + i * 16 + (lane >> 4) * 4 + r;
        if (m < M) {
          #pragma unroll
          for (int j = 0; j < TN; j++) {
            const int n = bn + wn + j * 16 + (lane & 15);
            atomicAdd(&Cf[(size_t)m * N + n], acc[i][j][r]);
          }
        }
      }
  } else {
    #pragma unroll
    for (int i = 0; i < TM; i++) {
      #pragma unroll
      for (int r = 0; r < 4; r++) {
        const int m = bm + wm + i * 16 + (lane >> 4) * 4 + r;
        if (m < M) {
          #pragma unroll
          for (int j = 0; j < TN; j++) {
            const int n = bn + wn + j * 16 + (lane & 15);
            float v = acc[i][j][r];
            if (BIAS) v += bias[n];
            if (GELU) v = 0.5f * v * (1.0f + erff(v * 0.70710678118654752f));
            if (RES)  v += res[(size_t)m * N + n];
            if (OUT_BF16) ((u16*)Cout)[(size_t)m * N + n] = f2bf(v);
            else          ((float*)Cout)[(size_t)m * N + n] = v;
          }
        }
      }
    }
  }
}

// ---------------- split-K epilogue: out = acc + bias + out (in-place res) -
__global__ __launch_bounds__(256) void splitk_epilogue_kernel(
    const float* __restrict__ acc, const float* __restrict__ bias,
    float* __restrict__ out, int M)
{
  const int idx = blockIdx.x * 256 + threadIdx.x;   // float4 index
  if (idx >= M * 256) return;
  float4 a = *(const float4*)(acc + idx * 4);
  float4 bv = *(const float4*)(bias + (idx & 255) * 4);
  float4 o = *(const float4*)(out + idx * 4);
  o.x += a.x + bv.x; o.y += a.y + bv.y; o.z += a.z + bv.z; o.w += a.w + bv.w;
  *(float4*)(out + idx * 4) = o;
}

// ---------------- V transpose: qkv v-part -> vt[h][d][token] (bf16) -------
__global__ __launch_bounds__(256) void vt_kernel(
    const u16* __restrict__ qkv, u16* __restrict__ vt)
{
  const int h  = blockIdx.y;
  const int t0 = blockIdx.x * 64;
  const int tid = threadIdx.x;
  __shared__ u16 tile[64][72];
  const int row = tid >> 3;   // 0..31
  const int ch  = tid & 7;
  #pragma unroll
  for (int i = 0; i < 2; i++) {
    const int tok = row + i * 32;
    *(bf16x8*)&tile[tok][ch * 8] =
        *(const bf16x8*)(qkv + (size_t)(t0 + tok) * 3072 + 2048 + h * 64 + ch * 8);
  }
  __syncthreads();
  #pragma unroll
  for (int i = 0; i < 2; i++) {
    const int d = row + i * 32;
    u16 tmp[8];
    #pragma unroll
    for (int j = 0; j < 8; j++) tmp[j] = tile[ch * 8 + j][d];
    *(bf16x8*)(vt + (size_t)(h * 64 + d) * 2048 + t0 + ch * 8) = *(bf16x8*)tmp;
  }
}

// ---------------- MFMA flash attention, no-max softmax, S^T trick ---------
// R4 structure (proven 50.5->43.9): K double-buffered, V single-buffered,
// 2 barriers/iter, 4 blocks/CU.
// R9: PARTITIONED split-K outputs — each (q-block,h,z) block is the sole
// writer of its (q,h) range in slice z, so atomicAdd -> plain stores and
// both memsets disappear (attn_norm sums the two slices). FP-identical
// (0+a+b == a+b).
template<int SPLIT>
__global__ __launch_bounds__(256) void attn_mfma(
    const u16* __restrict__ qkv, const u16* __restrict__ vt,
    const float* __restrict__ sz, float* __restrict__ opart,
    float* __restrict__ lpart)
{
  const int h   = blockIdx.y;
  const int q0  = blockIdx.x * 64;
  const int tid = threadIdx.x;
  const int lane = tid & 63;
  const int w    = tid >> 6;
  const int col  = lane & 15;
  const int quad = lane >> 4;

  __shared__ u16 Ks [2][64 * 64] __attribute__((aligned(16))); // [key][d] swizzled, dbuf
  __shared__ u16 Vts[64 * 64] __attribute__((aligned(16)));    // [d][key] swizzled, single
  __shared__ u16 Ps[4][16 * 72] __attribute__((aligned(16)));  // per-wave P[q][key]
  __shared__ float lball[N_TOK / SPLIT];                       // log2(size) per key

  bf16x8 qf[2];
  {
    const u16* qp = qkv + (size_t)(q0 + w * 16 + col) * 3072 + h * 64 + quad * 8;
    qf[0] = *(const bf16x8*)(qp);
    qf[1] = *(const bf16x8*)(qp + 32);
  }

  float l_lane = 0.f;          // all partials belong to q = q0 + w*16 + col
  f32x4 oacc[4] = {};

  const int rl = lane >> 3;
  const int cg = (lane & 7) ^ rl;
  const int kb = blockIdx.z * (N_TOK / SPLIT);
  const int ke = kb + N_TOK / SPLIT;

  // 0.125 * log2(e): fold the 1/8 scale and the nat->log2 conversion together
  constexpr float kScaleLog2e = 0.18033688011112042f;

  // ---- prologue: stage K[0], V[0]; precompute ALL log2(size) once ----
  #pragma unroll
  for (int i = 0; i < 2; i++) {
    const int r = w * 16 + i * 8 + rl;
    __builtin_amdgcn_global_load_lds(
        (const __attribute__((address_space(1))) void*)(qkv + (size_t)(kb + r) * 3072 + 1024 + h * 64 + cg * 8),
        (__attribute__((address_space(3))) void*)(&Ks[0][(w * 16 + i * 8) * 64]),
        16, 0, 0);
    __builtin_amdgcn_global_load_lds(
        (const __attribute__((address_space(1))) void*)(vt + (size_t)(h * 64 + r) * 2048 + kb + cg * 8),
        (__attribute__((address_space(3))) void*)(&Vts[(w * 16 + i * 8) * 64]),
        16, 0, 0);
  }
  #pragma unroll
  for (int i = tid; i < N_TOK / SPLIT; i += 256)
    lball[i] = __builtin_amdgcn_logf(sz[kb + i]);   // v_log_f32 = log2
  __syncthreads();   // drains prologue staging (vmcnt + lgkmcnt)

  int cur = 0;
  for (int kt = kb; kt < ke; kt += 64) {
    const int nxt = cur ^ 1;
    const bool has_next = (kt + 64 < ke);   // block-uniform

    // ---- issue NEXT K tile into the other K buffer (full-iter overlap) ---
    if (has_next) {
      #pragma unroll
      for (int i = 0; i < 2; i++) {
        const int r = w * 16 + i * 8 + rl;
        __builtin_amdgcn_global_load_lds(
            (const __attribute__((address_space(1))) void*)(qkv + (size_t)(kt + 64 + r) * 3072 + 1024 + h * 64 + cg * 8),
            (__attribute__((address_space(3))) void*)(&Ks[nxt][(w * 16 + i * 8) * 64]),
            16, 0, 0);
      }
    }

    // ---- S^T = K Q^T : lane holds S^T[key = jt*16+quad*4+r][q = col] ----
    const u16* Kc = Ks[cur];
    f32x4 sacc[4] = {};
    #pragma unroll
    for (int kk = 0; kk < 2; kk++) {
      const int slot = (kk * 4 + quad) ^ (lane & 7);
      bf16x8 kf[4];
      #pragma unroll
      for (int jt = 0; jt < 4; jt++)
        kf[jt] = *(const bf16x8*)&Kc[(jt * 16 + col) * 64 + slot * 8];
      __builtin_amdgcn_s_setprio(1);
      #pragma unroll
      for (int jt = 0; jt < 4; jt++)
        sacc[jt] = __builtin_amdgcn_mfma_f32_16x16x32_bf16(kf[jt], qf[kk], sacc[jt], 0, 0, 0);
      __builtin_amdgcn_s_setprio(0);
    }

    // exp2-domain softmax weights + packed P-writes (4x b64), l per-lane
    u16* pw = Ps[w];
    const float* lbp = &lball[kt - kb];
    #pragma unroll
    for (int jt = 0; jt < 4; jt++) {
      float4 lb4 = *(const float4*)&lbp[jt * 16 + quad * 4];
      const float p0 = __builtin_amdgcn_exp2f(fmaf(sacc[jt][0], kScaleLog2e, lb4.x));
      const float p1 = __builtin_amdgcn_exp2f(fmaf(sacc[jt][1], kScaleLog2e, lb4.y));
      const float p2 = __builtin_amdgcn_exp2f(fmaf(sacc[jt][2], kScaleLog2e, lb4.z));
      const float p3 = __builtin_amdgcn_exp2f(fmaf(sacc[jt][3], kScaleLog2e, lb4.w));
      l_lane += (p0 + p1) + (p2 + p3);
      uint2 pkk;
      pkk.x = cvt_pk_bf16(p0, p1);
      pkk.y = cvt_pk_bf16(p2, p3);
      *(uint2*)&pw[col * 72 + jt * 16 + quad * 4] = pkk;
    }
    // same-wave LDS RAW -> lgkmcnt (verified pattern); rows 144B apart
    bf16x8 pf[2];
    #pragma unroll
    for (int kk = 0; kk < 2; kk++)
      pf[kk] = *(const bf16x8*)&pw[col * 72 + kk * 32 + quad * 8];

    // barrier A: implicit vmcnt(0) drains V[this tile] (issued last iter,
    // had the whole QK+softmax above to load) + K[nxt] (usually done too)
    __syncthreads();

    // O += P V (A = P rows=q, B = V^T)
    #pragma unroll
    for (int kk = 0; kk < 2; kk++) {
      const int slot = (kk * 4 + quad) ^ (lane & 7);
      bf16x8 vf[4];
      #pragma unroll
      for (int nt = 0; nt < 4; nt++)
        vf[nt] = *(const bf16x8*)&Vts[(nt * 16 + col) * 64 + slot * 8];
      __builtin_amdgcn_s_setprio(1);
      #pragma unroll
      for (int nt = 0; nt < 4; nt++)
        oacc[nt] = __builtin_amdgcn_mfma_f32_16x16x32_bf16(pf[kk], vf[nt], oacc[nt], 0, 0, 0);
      __builtin_amdgcn_s_setprio(0);
    }

    // barrier B: all waves done reading Vts -> safe to overwrite
    __syncthreads();

    // ---- issue NEXT V tile into the single V buffer (overlaps next QK) --
    if (has_next) {
      #pragma unroll
      for (int i = 0; i < 2; i++) {
        const int r = w * 16 + i * 8 + rl;
        __builtin_amdgcn_global_load_lds(
            (const __attribute__((address_space(1))) void*)(vt + (size_t)(h * 64 + r) * 2048 + kt + 64 + cg * 8),
            (__attribute__((address_space(3))) void*)(&Vts[(w * 16 + i * 8) * 64]),
            16, 0, 0);
      }
    }
    cur = nxt;
  }

  // l: sum the 4 quads of each col group (once)
  l_lane += __shfl_xor(l_lane, 16);
  l_lane += __shfl_xor(l_lane, 32);

  // partitioned plain stores (sole writer per (q,h,z) — no atomics)
  float* osl = opart + (size_t)blockIdx.z * ((size_t)N_TOK * 1024);
  #pragma unroll
  for (int r = 0; r < 4; r++) {
    const int q = q0 + w * 16 + quad * 4 + r;
    float* op = osl + (size_t)q * 1024 + h * 64 + col;
    #pragma unroll
    for (int nt = 0; nt < 4; nt++)
      op[nt * 16] = oacc[nt][r];
  }
  if (quad == 0)
    lpart[(size_t)blockIdx.z * (N_TOK * 16) + (q0 + w * 16 + col) * 16 + h] = l_lane;
}

// ---------------- normalize O by l (sum 2 slices), emit bf16 xa -----------
__global__ __launch_bounds__(256) void attn_norm_kernel(
    const float* __restrict__ opart, const float* __restrict__ lpart,
    u16* __restrict__ xa)
{
  const int q = blockIdx.x;
  const int c = threadIdx.x * 4;
  float4 o0 = *(const float4*)(opart + (size_t)q * 1024 + c);
  float4 o1 = *(const float4*)(opart + (size_t)N_TOK * 1024 + (size_t)q * 1024 + c);
  const float l0 = lpart[q * 16 + (c >> 6)];
  const float l1 = lpart[N_TOK * 16 + q * 16 + (c >> 6)];
  const float inv = 1.0f / (l0 + l1);
  ushort4 o4;
  o4.x = f2bf((o0.x + o1.x) * inv); o4.y = f2bf((o0.y + o1.y) * inv);
  o4.z = f2bf((o0.z + o1.z) * inv); o4.w = f2bf((o0.w + o1.w) * inv);
  *(ushort4*)(xa + (size_t)q * 1024 + c) = o4;
}

// ---------------- merge scores: 4 src/block, identical comparator ---------
__global__ __launch_bounds__(256) void merge_score_kernel(
    const float* __restrict__ metric, const float* __restrict__ thr,
    int* __restrict__ mask, int* __restrict__ node)
{
  const int s0 = blockIdx.x * 4;
  const int t = threadIdx.x;
  __shared__ float a[4][64];
  a[t >> 6][t & 63] = metric[(size_t)(2 * (s0 + (t >> 6))) * 64 + (t & 63)];
  __syncthreads();
  float best[4] = {-INFINITY, -INFINITY, -INFINITY, -INFINITY};
  int besti[4] = {0, 0, 0, 0};
  for (int m = t; m < 1024; m += 256) {
    const float* bp = metric + (size_t)(2 * m + 1) * 64;
    float s[4] = {0.f, 0.f, 0.f, 0.f};
    #pragma unroll
    for (int d = 0; d < 64; d += 4) {
      float4 bv = *(const float4*)(bp + d);
      #pragma unroll
      for (int j = 0; j < 4; j++) {
        float4 av = *(const float4*)&a[j][d];
        s[j] += av.x*bv.x + av.y*bv.y + av.z*bv.z + av.w*bv.w;
      }
    }
    #pragma unroll
    for (int j = 0; j < 4; j++)
      if (s[j] > best[j]) { best[j] = s[j]; besti[j] = m; }   // ascending m
  }
  #pragma unroll
  for (int j = 0; j < 4; j++) {
    float b = best[j]; int bi = besti[j];
    #pragma unroll
    for (int off = 1; off < 64; off <<= 1) {
      float ov = __shfl_xor(b, off);
      int   oi = __shfl_xor(bi, off);
      if (ov > b || (ov == b && oi < bi)) { b = ov; bi = oi; }
    }
    best[j] = b; besti[j] = bi;
  }
  __shared__ float bw_[4][4]; __shared__ int biw_[4][4];
  const int wv = t >> 6;
  if ((t & 63) == 0) {
    #pragma unroll
    for (int j = 0; j < 4; j++) { bw_[wv][j] = best[j]; biw_[wv][j] = besti[j]; }
  }
  __syncthreads();
  if (t < 4) {
    const int j = t;
    float b = bw_[0][j]; int bi = biw_[0][j];
    for (int ww = 1; ww < 4; ww++)
      if (bw_[ww][j] > b || (bw_[ww][j] == b && biw_[ww][j] < bi)) { b = bw_[ww][j]; bi = biw_[ww][j]; }
    const int n = s0 + j;
    if (n == 0) { mask[0] = 0; node[0] = 0; }
    else { mask[n] = (b > thr[0]) ? 1 : 0; node[n] = bi; }
  }
}

// ---------------- exclusive prefix-sum of !mask (1024 entries) ------------
__global__ __launch_bounds__(1024) void scan_kernel(
    const int* __restrict__ mask, int* __restrict__ pos)
{
  __shared__ int s[1024];
  const int t = threadIdx.x;
  const int v0 = mask[t] ? 0 : 1;
  s[t] = v0;
  __syncthreads();
  for (int off = 1; off < 1024; off <<= 1) {
    int v = (t >= off) ? s[t - off] : 0;
    __syncthreads();
    s[t] += v;
    __syncthreads();
  }
  pos[t] = s[t] - v0;
}

// ---------------- build merged rows (unm gather + dst base) ---------------
__global__ __launch_bounds__(256) void build_kernel(
    const float* __restrict__ xres, const float* __restrict__ sz,
    const int* __restrict__ mask, const int* __restrict__ pos,
    float* __restrict__ xm, float* __restrict__ sizem, int U)
{
  const int b = blockIdx.x;
  const int t = threadIdx.x;
  int srow, orow;
  if (b < 1024) { srow = 2 * b + 1; orow = U + b; }
  else {
    const int i = b - 1024;
    if (mask[i]) return;
    srow = 2 * i; orow = pos[i];
  }
  const float ssz = sz[srow];
  const float* xp = xres + (size_t)srow * 1024;
  float* op = xm + (size_t)orow * 1024;
  const int c = t * 4;
  float4 v = *(const float4*)(xp + c);
  v.x *= ssz; v.y *= ssz; v.z *= ssz; v.w *= ssz;
  *(float4*)(op + c) = v;
  if (t == 0) sizem[orow] = ssz;
}

// ---------------- scatter-add merged src tokens into dst rows -------------
__global__ __launch_bounds__(256) void merge_add_kernel(
    const float* __restrict__ xres, const float* __restrict__ sz,
    const int* __restrict__ mask, const int* __restrict__ node,
    float* __restrict__ xm, float* __restrict__ sizem, int U)
{
  const int i = blockIdx.x;
  if (!mask[i]) return;
  const int t = threadIdx.x;
  const int srow = 2 * i;
  const int orow = U + node[i];
  const float ssz = sz[srow];
  const float* xp = xres + (size_t)srow * 1024;
  float* op = xm + (size_t)orow * 1024;
  for (int c = t; c < 1024; c += 256)
    atomicAdd(op + c, xp[c] * ssz);
  if (t == 0) atomicAdd(sizem + orow, ssz);
}

// ---------------- divide by size; emit x and size outputs -----------------
__global__ __launch_bounds__(256) void divide_kernel(
    const float* __restrict__ xm, const float* __restrict__ sizem,
    float* __restrict__ outx, float* __restrict__ outs, int M)
{
  const int total = M * 1024;
  for (int idx = blockIdx.x * 256 + threadIdx.x; idx < total; idx += gridDim.x * 256)
    outx[idx] = xm[idx] / sizem[idx >> 10];
  const int idx2 = blockIdx.x * 256 + threadIdx.x;
  if (idx2 < M) outs[idx2] = sizem[idx2];
}

extern "C" void kernel_launch(void* const* d_in, const int* in_sizes, int n_in,
                              void* d_out, int out_size, void* d_ws, size_t ws_size,
                              hipStream_t stream) {
  const float* x      = (const float*)d_in[0];
  const float* sz     = (const float*)d_in[1];
  const float* qkv_w  = (const float*)d_in[2];
  const float* proj_w = (const float*)d_in[3];
  const float* proj_b = (const float*)d_in[4];
  const float* ln1_g  = (const float*)d_in[5];
  const float* ln1_b  = (const float*)d_in[6];
  const float* ln2_g  = (const float*)d_in[7];
  const float* ln2_b  = (const float*)d_in[8];
  const float* fc1_w  = (const float*)d_in[9];
  const float* fc1_b  = (const float*)d_in[10];
  const float* fc2_w  = (const float*)d_in[11];
  const float* fc2_b  = (const float*)d_in[12];
  const float* thr    = (const float*)d_in[13];

  const int M = out_size / 1025;
  const int U = M - 1024;
  const size_t MB = 1u << 20;
  const size_t KB = 1u << 10;

  // workspace overlays (lifetimes sequential on `stream`):
  //  early: w_qkvT[0,6) -> b_vt[0,4); wbar/met/mask@[6,7); lpart@[7,7.25);
  //         w_projT[8,10); b_qkv[10,22) -> b_xa[10,14) -> b_xm[10,18);
  //         b_hf[22,30) -> opart[22,38) -> b_xres[22,30);
  //         b_h[30,34) (dead after QKV GEMM; opart slice1 overlays it)
  //  late:  w_fc1T[0,8); b_g[8,21); w_fc2T[21,29); facc[29,35); b_h2[35,39)
  char* ws = (char*)d_ws;
  u16*   w_qkvT  = (u16*)(ws + 0);
  float* b_wbar  = (float*)(ws + 6 * MB);
  float* b_met   = (float*)(ws + 6 * MB + 256 * KB);
  int*   b_mask  = (int*)(ws + 6 * MB + 768 * KB);
  int*   b_node  = b_mask + 1024;
  int*   b_pos   = b_node + 1024;
  float* b_szm   = (float*)(b_pos + 1024);
  float* b_lpart = (float*)(ws + 7 * MB);            // 2 x 128KB slices
  u16*   w_projT = (u16*)(ws + 8 * MB);
  u16*   b_qkv   = (u16*)(ws + 10 * MB);
  u16*   b_xa    = (u16*)(ws + 10 * MB);   // over dead b_qkv (after attn)
  float* b_xm    = (float*)(ws + 10 * MB);   // over dead b_xa (after proj)
  float* b_hf    = (float*)(ws + 22 * MB);
  float* b_opart = (float*)(ws + 22 * MB);   // 2 x 8MB slices over dead b_hf+b_h
  float* b_xres  = (float*)(ws + 22 * MB);   // over dead opart slice0
  u16*   b_h     = (u16*)(ws + 30 * MB);
  u16*   b_vt    = (u16*)(ws + 0);
  u16*   w_fc1T  = (u16*)(ws + 0);
  u16*   b_g     = (u16*)(ws + 8 * MB);
  u16*   w_fc2T  = (u16*)(ws + 21 * MB);
  float* b_facc  = (float*)(ws + 29 * MB);
  u16*   b_h2    = (u16*)(ws + 35 * MB);

  float* outx = (float*)d_out;
  float* outs = outx + (size_t)M * 1024;

  // 1. LN1 -> bf16 (for MFMA) + fp32 (for exact metric path)
  ln_kernel<<<2048, 256, 0, stream>>>(x, ln1_g, ln1_b, b_h, b_hf);
  // 2. mean-over-heads k-weights (fp32)
  wbar_kernel<<<256, 256, 0, stream>>>(qkv_w, b_wbar);
  // 3. weight converts for attention half
  convert_transpose<<<dim3(96, 32), 256, 0, stream>>>(qkv_w, w_qkvT, 1024, 3072);
  convert_transpose<<<dim3(32, 32), 256, 0, stream>>>(proj_w, w_projT, 1024, 1024);
  // 4. QKV GEMM (bf16 MFMA, 128x64 dbuf tile, R6-proven) — 768 blocks
  gemm_mfma<128, 64, 1, false, false, false, true><<<dim3(48, 16), 256, 0, stream>>>(
      b_h, w_qkvT, nullptr, nullptr, b_qkv, 2048, 3072, 1024);
  // 4b. V transpose for MFMA attention (overwrites dead w_qkvT)
  vt_kernel<<<dim3(32, 16), 256, 0, stream>>>(b_qkv, b_vt);
  // 5. exact fp32 metric (decoupled from bf16 path — merge decisions stable)
  metric_gemm_kernel<<<512, 256, 0, stream>>>(b_hf, b_wbar, b_met);
  // 6. MFMA attention: K-dbuf + single-V pipeline, partitioned outputs
  //    (no memsets, no atomics)
  attn_mfma<2><<<dim3(32, 16, 2), 256, 0, stream>>>(b_qkv, b_vt, sz, b_opart, b_lpart);
  attn_norm_kernel<<<2048, 256, 0, stream>>>(b_opart, b_lpart, b_xa);
  // 7. proj GEMM + bias + residual(x) -> xres fp32 — 512 blocks
  gemm_mfma<64, 64, 1, true, false, true, false><<<dim3(16, 32), 256, 0, stream>>>(
      b_xa, w_projT, proj_b, x, b_xres, 2048, 1024, 1024);
  // 8-11. merge pipeline
  merge_score_kernel<<<256, 256, 0, stream>>>(b_met, thr, b_mask, b_node);
  scan_kernel<<<1, 1024, 0, stream>>>(b_mask, b_pos);
  build_kernel<<<2048, 256, 0, stream>>>(b_xres, sz, b_mask, b_pos, b_xm, b_szm, U);
  merge_add_kernel<<<1024, 256, 0, stream>>>(b_xres, sz, b_mask, b_node, b_xm, b_szm, U);
  // 12. divide + emit outputs
  divide_kernel<<<2048, 256, 0, stream>>>(b_xm, b_szm, outx, outs, M);
  // 13. late weight converts (into now-dead regions)
  convert_transpose<<<dim3(128, 32), 256, 0, stream>>>(fc1_w, w_fc1T, 1024, 4096);
  convert_transpose<<<dim3(32, 128), 256, 0, stream>>>(fc2_w, w_fc2T, 4096, 1024);
  // 14. LN2 -> bf16
  ln_kernel<<<M, 256, 0, stream>>>(outx, ln2_g, ln2_b, b_h2, nullptr);
  // 15. fc1 + bias + exact GELU -> bf16 — 768 blocks (R6-proven shape)
  gemm_mfma<128, 64, 1, true, true, false, true><<<dim3(64, (M + 127) / 128), 256, 0, stream>>>(
      b_h2, w_fc1T, fc1_b, nullptr, b_g, M, 4096, 1024);
  // 16. fc2 split-K=4, 128x64 tile (R6-proven shape)
  hipMemsetAsync(b_facc, 0, (size_t)M * 1024 * 4, stream);
  gemm_mfma<128, 64, 4, false, false, false, false><<<dim3(16, (M + 127) / 128, 4), 256, 0, stream>>>(
      b_g, w_fc2T, nullptr, nullptr, b_facc, M, 1024, 4096);
  // 17. fc2 epilogue: outx += facc + bias (residual in-place)
  splitk_epilogue_kernel<<<(M * 256 + 255) / 256, 256, 0, stream>>>(
      b_facc, fc2_b, outx, M);
  (void)in_sizes; (void)n_in; (void)ws_size;
}

// Round 10
// 311.812 us; speedup vs baseline: 1.1100x; 1.0134x over previous
//
#include <hip/hip_runtime.h>
#include <math.h>

typedef unsigned short u16;
typedef __attribute__((ext_vector_type(8))) short bf16x8;
typedef __attribute__((ext_vector_type(4))) float f32x4;

#define C_DIM 1024
#define N_TOK 2048

static __device__ __forceinline__ u16 f2bf(float f) {
  union { float f; unsigned u; } v; v.f = f;
  unsigned r = v.u + 0x7fff + ((v.u >> 16) & 1);
  return (u16)(r >> 16);
}

// packed f32x2 -> bf16x2 (RNE, same rounding as f2bf) in ONE VALU op
static __device__ __forceinline__ unsigned cvt_pk_bf16(float lo, float hi) {
  unsigned r;
  asm("v_cvt_pk_bf16_f32 %0, %1, %2" : "=v"(r) : "v"(lo), "v"(hi));
  return r;
}

// ---------------- transpose + fp32->bf16 convert: W[K][N] -> WT[N][K] -----
__global__ __launch_bounds__(256) void convert_transpose(
    const float* __restrict__ W, u16* __restrict__ WT, int K, int N)
{
  __shared__ float tile[32][33];
  const int bx = blockIdx.x * 32;  // n
  const int by = blockIdx.y * 32;  // k
  const int tx = threadIdx.x & 31, ty = threadIdx.x >> 5;  // ty 0..7
  #pragma unroll
  for (int i = 0; i < 32; i += 8)
    tile[ty + i][tx] = W[(size_t)(by + ty + i) * N + bx + tx];
  __syncthreads();
  #pragma unroll
  for (int i = 0; i < 32; i += 8)
    WT[(size_t)(bx + ty + i) * K + by + tx] = f2bf(tile[tx][ty + i]);
}

// ---------------- LayerNorm: bf16 out (+ optional fp32 out) ---------------
__global__ __launch_bounds__(256) void ln_kernel(
    const float* __restrict__ x, const float* __restrict__ g,
    const float* __restrict__ b, u16* __restrict__ out,
    float* __restrict__ fout)
{
  const int row = blockIdx.x;
  const int t = threadIdx.x;
  const float* xr = x + (size_t)row * C_DIM;
  float4 xv = *(const float4*)(xr + t * 4);
  float s  = xv.x + xv.y + xv.z + xv.w;
  float ss = xv.x*xv.x + xv.y*xv.y + xv.z*xv.z + xv.w*xv.w;
  #pragma unroll
  for (int off = 1; off < 64; off <<= 1) {
    s  += __shfl_xor(s, off);
    ss += __shfl_xor(ss, off);
  }
  __shared__ float rs[4], rss[4];
  const int w = t >> 6;
  if ((t & 63) == 0) { rs[w] = s; rss[w] = ss; }
  __syncthreads();
  s  = rs[0] + rs[1] + rs[2] + rs[3];
  ss = rss[0] + rss[1] + rss[2] + rss[3];
  const float mean = s * (1.0f / C_DIM);
  const float var  = ss * (1.0f / C_DIM) - mean * mean;
  const float inv  = rsqrtf(var + 1e-5f);
  float4 gv = *(const float4*)(g + t * 4);
  float4 bv = *(const float4*)(b + t * 4);
  float4 o;
  o.x = (xv.x - mean) * inv * gv.x + bv.x;
  o.y = (xv.y - mean) * inv * gv.y + bv.y;
  o.z = (xv.z - mean) * inv * gv.z + bv.z;
  o.w = (xv.w - mean) * inv * gv.w + bv.w;
  ushort4 o4;
  o4.x = f2bf(o.x); o4.y = f2bf(o.y); o4.z = f2bf(o.z); o4.w = f2bf(o.w);
  *(ushort4*)(out + (size_t)row * C_DIM + t * 4) = o4;
  if (fout != nullptr)
    *(float4*)(fout + (size_t)row * C_DIM + t * 4) = o;
}

// ---------------- wbar[c][d] = mean over heads of k-weights ---------------
__global__ __launch_bounds__(256) void wbar_kernel(
    const float* __restrict__ qkv_w, float* __restrict__ wbar)
{
  const int idx = blockIdx.x * 256 + threadIdx.x;   // c*64 + d
  const int c = idx >> 6, d = idx & 63;
  float s = 0.f;
  #pragma unroll
  for (int h = 0; h < 16; h++)
    s += qkv_w[(size_t)c * 3072 + 1024 + h * 64 + d];
  wbar[idx] = s * (1.0f / 16.0f);
}

// ---------------- metric: 4 tokens/block, identical accumulation order ----
__global__ __launch_bounds__(256) void metric_gemm_kernel(
    const float* __restrict__ hf, const float* __restrict__ wbar,
    float* __restrict__ metric)
{
  __shared__ float hs[4][1024];
  const int n0 = blockIdx.x * 4;
  const int t = threadIdx.x;
  #pragma unroll
  for (int i = 0; i < 4; i++)
    *(float4*)&hs[i][t * 4] = *(const float4*)(hf + (size_t)(n0 + i) * 1024 + t * 4);
  __syncthreads();
  const int d = t & 63;
  const float* hsw = hs[t >> 6];
  float a0=0,a1=0,a2=0,a3=0,a4=0,a5=0,a6=0,a7=0;
  for (int c = 0; c < 1024; c += 8) {
    a0 += hsw[c+0] * wbar[(c+0)*64 + d];
    a1 += hsw[c+1] * wbar[(c+1)*64 + d];
    a2 += hsw[c+2] * wbar[(c+2)*64 + d];
    a3 += hsw[c+3] * wbar[(c+3)*64 + d];
    a4 += hsw[c+4] * wbar[(c+4)*64 + d];
    a5 += hsw[c+5] * wbar[(c+5)*64 + d];
    a6 += hsw[c+6] * wbar[(c+6)*64 + d];
    a7 += hsw[c+7] * wbar[(c+7)*64 + d];
  }
  float s = ((a0+a1)+(a2+a3)) + ((a4+a5)+(a6+a7));
  float sq = s * s;
  #pragma unroll
  for (int off = 1; off < 64; off <<= 1) sq += __shfl_xor(sq, off);
  metric[(size_t)(n0 + (t >> 6)) * 64 + d] = s / sqrtf(sq);
}

// ---------------- bf16 MFMA GEMM: C[M,N] = A[M,K] @ BT[N,K]^T -------------
// R6 geometry (proven): BN=64, LDS double-buffer, one barrier/iter.
// R10: SPLIT>1 path writes PARTITIONED slices (plain stores, sole writer
// per (m,n,z)) instead of atomicAdd — no zero-init needed; epilogue sums.
template<int BM, int BN, int SPLIT, bool BIAS, bool GELU, bool RES, bool OUT_BF16>
__global__ __launch_bounds__(256) void gemm_mfma(
    const u16* __restrict__ A,   // [>=gridDim.y*BM][K] bf16 (readable padding)
    const u16* __restrict__ BT,  // [N][K] bf16
    const float* __restrict__ bias, const float* __restrict__ res,
    void* __restrict__ Cout, int M, int N, int K)
{
  constexpr int TM = BM / 32;                 // 16x16 tiles per wave (rows)
  constexpr int TN = BN / 32;                 // 16x16 tiles per wave (cols)
  __shared__ u16 As[2][BM * 64] __attribute__((aligned(16)));
  __shared__ u16 Bs[2][BN * 64] __attribute__((aligned(16)));
  const int tid  = threadIdx.x;
  const int lane = tid & 63;
  const int w    = tid >> 6;
  const int bm = blockIdx.y * BM;
  const int bn = blockIdx.x * BN;
  const int wm = (w >> 1) * (BM / 2);
  const int wn = (w & 1) * (BN / 2);

  f32x4 acc[TM][TN] = {};

  const int rl = lane >> 3;                 // row-in-8-group
  const int cg = (lane & 7) ^ rl;           // swizzled source chunk

  const int kb = (K / SPLIT) * blockIdx.z;
  const int ke = kb + K / SPLIT;

#define GEMM_STAGE(buf, k0_)                                                   \
  {                                                                            \
    _Pragma("unroll")                                                          \
    for (int i = 0; i < BM / 32; i++) {                                        \
      const int r = w * (BM / 4) + i * 8 + rl;                                 \
      __builtin_amdgcn_global_load_lds(                                        \
          (const __attribute__((address_space(1))) void*)(A + (size_t)(bm + r) * K + (k0_) + cg * 8), \
          (__attribute__((address_space(3))) void*)(&As[buf][(w * (BM / 4) + i * 8) * 64]), \
          16, 0, 0);                                                           \
    }                                                                          \
    _Pragma("unroll")                                                          \
    for (int i = 0; i < BN / 32; i++) {                                        \
      const int r = w * (BN / 4) + i * 8 + rl;                                 \
      __builtin_amdgcn_global_load_lds(                                        \
          (const __attribute__((address_space(1))) void*)(BT + (size_t)(bn + r) * K + (k0_) + cg * 8), \
          (__attribute__((address_space(3))) void*)(&Bs[buf][(w * (BN / 4) + i * 8) * 64]), \
          16, 0, 0);                                                           \
    }                                                                          \
  }

  // prologue: stage first K-tile into buffer 0
  GEMM_STAGE(0, kb);
  __syncthreads();

  int cur = 0;
  for (int k0 = kb; k0 < ke; k0 += 64) {
    // issue next tile's loads into the other buffer (overlap compute)
    if (k0 + 64 < ke) GEMM_STAGE(cur ^ 1, k0 + 64);

    #pragma unroll
    for (int kk = 0; kk < 2; kk++) {
      bf16x8 af[TM], bfr[TN];
      const int slot = (kk * 4 + (lane >> 4)) ^ (lane & 7);
      #pragma unroll
      for (int i = 0; i < TM; i++)
        af[i] = *(const bf16x8*)&As[cur][(wm + i * 16 + (lane & 15)) * 64 + slot * 8];
      #pragma unroll
      for (int j = 0; j < TN; j++)
        bfr[j] = *(const bf16x8*)&Bs[cur][(wn + j * 16 + (lane & 15)) * 64 + slot * 8];
      __builtin_amdgcn_s_setprio(1);
      #pragma unroll
      for (int i = 0; i < TM; i++)
        #pragma unroll
        for (int j = 0; j < TN; j++)
          acc[i][j] = __builtin_amdgcn_mfma_f32_16x16x32_bf16(af[i], bfr[j], acc[i][j], 0, 0, 0);
      __builtin_amdgcn_s_setprio(0);
    }
    // one barrier/iter: (a) implicit vmcnt(0) makes buf[cur^1]'s staged
    // loads visible for next compute; (b) all waves done reading buf[cur]
    // so next iteration may overwrite it.
    __syncthreads();
    cur ^= 1;
  }
#undef GEMM_STAGE

  if constexpr (SPLIT > 1) {
    // partitioned plain stores: slice z at Cf + z*M*N (sole writer)
    float* Cf = (float*)Cout + (size_t)blockIdx.z * ((size_t)M * N);
    #pragma unroll
    for (int i = 0; i < TM; i++)
      #pragma unroll
      for (int r = 0; r < 4; r++) {
        const int m = bm + wm + i * 16 + (lane >> 4) * 4 + r;
        if (m < M) {
          #pragma unroll
          for (int j = 0; j < TN; j++) {
            const int n = bn + wn + j * 16 + (lane & 15);
            Cf[(size_t)m * N + n] = acc[i][j][r];
          }
        }
      }
  } else {
    #pragma unroll
    for (int i = 0; i < TM; i++) {
      #pragma unroll
      for (int r = 0; r < 4; r++) {
        const int m = bm + wm + i * 16 + (lane >> 4) * 4 + r;
        if (m < M) {
          #pragma unroll
          for (int j = 0; j < TN; j++) {
            const int n = bn + wn + j * 16 + (lane & 15);
            float v = acc[i][j][r];
            if (BIAS) v += bias[n];
            if (GELU) v = 0.5f * v * (1.0f + erff(v * 0.70710678118654752f));
            if (RES)  v += res[(size_t)m * N + n];
            if (OUT_BF16) ((u16*)Cout)[(size_t)m * N + n] = f2bf(v);
            else          ((float*)Cout)[(size_t)m * N + n] = v;
          }
        }
      }
    }
  }
}

// ------ split-K epilogue: out += sum(4 slices) + bias (in-place res) ------
__global__ __launch_bounds__(256) void splitk_epilogue_kernel(
    const float* __restrict__ acc, const float* __restrict__ bias,
    float* __restrict__ out, int M)
{
  const int idx = blockIdx.x * 256 + threadIdx.x;   // float4 index
  if (idx >= M * 256) return;
  const size_t S = (size_t)M * 256;                 // slice stride in float4
  const float4* a4 = (const float4*)acc;
  float4 a0 = a4[idx], a1 = a4[idx + S], a2 = a4[idx + 2 * S], a3 = a4[idx + 3 * S];
  float4 bv = *(const float4*)(bias + (idx & 255) * 4);
  float4 o = *(const float4*)(out + (size_t)idx * 4);
  o.x += (a0.x + a1.x) + (a2.x + a3.x) + bv.x;
  o.y += (a0.y + a1.y) + (a2.y + a3.y) + bv.y;
  o.z += (a0.z + a1.z) + (a2.z + a3.z) + bv.z;
  o.w += (a0.w + a1.w) + (a2.w + a3.w) + bv.w;
  *(float4*)(out + (size_t)idx * 4) = o;
}

// ---------------- V transpose: qkv v-part -> vt[h][d][token] (bf16) -------
__global__ __launch_bounds__(256) void vt_kernel(
    const u16* __restrict__ qkv, u16* __restrict__ vt)
{
  const int h  = blockIdx.y;
  const int t0 = blockIdx.x * 64;
  const int tid = threadIdx.x;
  __shared__ u16 tile[64][72];
  const int row = tid >> 3;   // 0..31
  const int ch  = tid & 7;
  #pragma unroll
  for (int i = 0; i < 2; i++) {
    const int tok = row + i * 32;
    *(bf16x8*)&tile[tok][ch * 8] =
        *(const bf16x8*)(qkv + (size_t)(t0 + tok) * 3072 + 2048 + h * 64 + ch * 8);
  }
  __syncthreads();
  #pragma unroll
  for (int i = 0; i < 2; i++) {
    const int d = row + i * 32;
    u16 tmp[8];
    #pragma unroll
    for (int j = 0; j < 8; j++) tmp[j] = tile[ch * 8 + j][d];
    *(bf16x8*)(vt + (size_t)(h * 64 + d) * 2048 + t0 + ch * 8) = *(bf16x8*)tmp;
  }
}

// ---------------- MFMA flash attention, no-max softmax, S^T trick ---------
// R4 structure (proven): K double-buffered, V single-buffered, 2 barriers/
// iter, 4 blocks/CU. R9: partitioned outputs (plain stores, no atomics,
// no memsets) — attn dropped below 41us.
template<int SPLIT>
__global__ __launch_bounds__(256) void attn_mfma(
    const u16* __restrict__ qkv, const u16* __restrict__ vt,
    const float* __restrict__ sz, float* __restrict__ opart,
    float* __restrict__ lpart)
{
  const int h   = blockIdx.y;
  const int q0  = blockIdx.x * 64;
  const int tid = threadIdx.x;
  const int lane = tid & 63;
  const int w    = tid >> 6;
  const int col  = lane & 15;
  const int quad = lane >> 4;

  __shared__ u16 Ks [2][64 * 64] __attribute__((aligned(16))); // [key][d] swizzled, dbuf
  __shared__ u16 Vts[64 * 64] __attribute__((aligned(16)));    // [d][key] swizzled, single
  __shared__ u16 Ps[4][16 * 72] __attribute__((aligned(16)));  // per-wave P[q][key]
  __shared__ float lball[N_TOK / SPLIT];                       // log2(size) per key

  bf16x8 qf[2];
  {
    const u16* qp = qkv + (size_t)(q0 + w * 16 + col) * 3072 + h * 64 + quad * 8;
    qf[0] = *(const bf16x8*)(qp);
    qf[1] = *(const bf16x8*)(qp + 32);
  }

  float l_lane = 0.f;          // all partials belong to q = q0 + w*16 + col
  f32x4 oacc[4] = {};

  const int rl = lane >> 3;
  const int cg = (lane & 7) ^ rl;
  const int kb = blockIdx.z * (N_TOK / SPLIT);
  const int ke = kb + N_TOK / SPLIT;

  // 0.125 * log2(e): fold the 1/8 scale and the nat->log2 conversion together
  constexpr float kScaleLog2e = 0.18033688011112042f;

  // ---- prologue: stage K[0], V[0]; precompute ALL log2(size) once ----
  #pragma unroll
  for (int i = 0; i < 2; i++) {
    const int r = w * 16 + i * 8 + rl;
    __builtin_amdgcn_global_load_lds(
        (const __attribute__((address_space(1))) void*)(qkv + (size_t)(kb + r) * 3072 + 1024 + h * 64 + cg * 8),
        (__attribute__((address_space(3))) void*)(&Ks[0][(w * 16 + i * 8) * 64]),
        16, 0, 0);
    __builtin_amdgcn_global_load_lds(
        (const __attribute__((address_space(1))) void*)(vt + (size_t)(h * 64 + r) * 2048 + kb + cg * 8),
        (__attribute__((address_space(3))) void*)(&Vts[(w * 16 + i * 8) * 64]),
        16, 0, 0);
  }
  #pragma unroll
  for (int i = tid; i < N_TOK / SPLIT; i += 256)
    lball[i] = __builtin_amdgcn_logf(sz[kb + i]);   // v_log_f32 = log2
  __syncthreads();   // drains prologue staging (vmcnt + lgkmcnt)

  int cur = 0;
  for (int kt = kb; kt < ke; kt += 64) {
    const int nxt = cur ^ 1;
    const bool has_next = (kt + 64 < ke);   // block-uniform

    // ---- issue NEXT K tile into the other K buffer (full-iter overlap) ---
    if (has_next) {
      #pragma unroll
      for (int i = 0; i < 2; i++) {
        const int r = w * 16 + i * 8 + rl;
        __builtin_amdgcn_global_load_lds(
            (const __attribute__((address_space(1))) void*)(qkv + (size_t)(kt + 64 + r) * 3072 + 1024 + h * 64 + cg * 8),
            (__attribute__((address_space(3))) void*)(&Ks[nxt][(w * 16 + i * 8) * 64]),
            16, 0, 0);
      }
    }

    // ---- S^T = K Q^T : lane holds S^T[key = jt*16+quad*4+r][q = col] ----
    const u16* Kc = Ks[cur];
    f32x4 sacc[4] = {};
    #pragma unroll
    for (int kk = 0; kk < 2; kk++) {
      const int slot = (kk * 4 + quad) ^ (lane & 7);
      bf16x8 kf[4];
      #pragma unroll
      for (int jt = 0; jt < 4; jt++)
        kf[jt] = *(const bf16x8*)&Kc[(jt * 16 + col) * 64 + slot * 8];
      __builtin_amdgcn_s_setprio(1);
      #pragma unroll
      for (int jt = 0; jt < 4; jt++)
        sacc[jt] = __builtin_amdgcn_mfma_f32_16x16x32_bf16(kf[jt], qf[kk], sacc[jt], 0, 0, 0);
      __builtin_amdgcn_s_setprio(0);
    }

    // exp2-domain softmax weights + packed P-writes (4x b64), l per-lane
    u16* pw = Ps[w];
    const float* lbp = &lball[kt - kb];
    #pragma unroll
    for (int jt = 0; jt < 4; jt++) {
      float4 lb4 = *(const float4*)&lbp[jt * 16 + quad * 4];
      const float p0 = __builtin_amdgcn_exp2f(fmaf(sacc[jt][0], kScaleLog2e, lb4.x));
      const float p1 = __builtin_amdgcn_exp2f(fmaf(sacc[jt][1], kScaleLog2e, lb4.y));
      const float p2 = __builtin_amdgcn_exp2f(fmaf(sacc[jt][2], kScaleLog2e, lb4.z));
      const float p3 = __builtin_amdgcn_exp2f(fmaf(sacc[jt][3], kScaleLog2e, lb4.w));
      l_lane += (p0 + p1) + (p2 + p3);
      uint2 pkk;
      pkk.x = cvt_pk_bf16(p0, p1);
      pkk.y = cvt_pk_bf16(p2, p3);
      *(uint2*)&pw[col * 72 + jt * 16 + quad * 4] = pkk;
    }
    // same-wave LDS RAW -> lgkmcnt (verified pattern); rows 144B apart
    bf16x8 pf[2];
    #pragma unroll
    for (int kk = 0; kk < 2; kk++)
      pf[kk] = *(const bf16x8*)&pw[col * 72 + kk * 32 + quad * 8];

    // barrier A: implicit vmcnt(0) drains V[this tile] (issued last iter,
    // had the whole QK+softmax above to load) + K[nxt] (usually done too)
    __syncthreads();

    // O += P V (A = P rows=q, B = V^T)
    #pragma unroll
    for (int kk = 0; kk < 2; kk++) {
      const int slot = (kk * 4 + quad) ^ (lane & 7);
      bf16x8 vf[4];
      #pragma unroll
      for (int nt = 0; nt < 4; nt++)
        vf[nt] = *(const bf16x8*)&Vts[(nt * 16 + col) * 64 + slot * 8];
      __builtin_amdgcn_s_setprio(1);
      #pragma unroll
      for (int nt = 0; nt < 4; nt++)
        oacc[nt] = __builtin_amdgcn_mfma_f32_16x16x32_bf16(pf[kk], vf[nt], oacc[nt], 0, 0, 0);
      __builtin_amdgcn_s_setprio(0);
    }

    // barrier B: all waves done reading Vts -> safe to overwrite
    __syncthreads();

    // ---- issue NEXT V tile into the single V buffer (overlaps next QK) --
    if (has_next) {
      #pragma unroll
      for (int i = 0; i < 2; i++) {
        const int r = w * 16 + i * 8 + rl;
        __builtin_amdgcn_global_load_lds(
            (const __attribute__((address_space(1))) void*)(vt + (size_t)(h * 64 + r) * 2048 + kt + 64 + cg * 8),
            (__attribute__((address_space(3))) void*)(&Vts[(w * 16 + i * 8) * 64]),
            16, 0, 0);
      }
    }
    cur = nxt;
  }

  // l: sum the 4 quads of each col group (once)
  l_lane += __shfl_xor(l_lane, 16);
  l_lane += __shfl_xor(l_lane, 32);

  // partitioned plain stores (sole writer per (q,h,z) — no atomics)
  float* osl = opart + (size_t)blockIdx.z * ((size_t)N_TOK * 1024);
  #pragma unroll
  for (int r = 0; r < 4; r++) {
    const int q = q0 + w * 16 + quad * 4 + r;
    float* op = osl + (size_t)q * 1024 + h * 64 + col;
    #pragma unroll
    for (int nt = 0; nt < 4; nt++)
      op[nt * 16] = oacc[nt][r];
  }
  if (quad == 0)
    lpart[(size_t)blockIdx.z * (N_TOK * 16) + (q0 + w * 16 + col) * 16 + h] = l_lane;
}

// ---------------- normalize O by l (sum 2 slices), emit bf16 xa -----------
__global__ __launch_bounds__(256) void attn_norm_kernel(
    const float* __restrict__ opart, const float* __restrict__ lpart,
    u16* __restrict__ xa)
{
  const int q = blockIdx.x;
  const int c = threadIdx.x * 4;
  float4 o0 = *(const float4*)(opart + (size_t)q * 1024 + c);
  float4 o1 = *(const float4*)(opart + (size_t)N_TOK * 1024 + (size_t)q * 1024 + c);
  const float l0 = lpart[q * 16 + (c >> 6)];
  const float l1 = lpart[N_TOK * 16 + q * 16 + (c >> 6)];
  const float inv = 1.0f / (l0 + l1);
  ushort4 o4;
  o4.x = f2bf((o0.x + o1.x) * inv); o4.y = f2bf((o0.y + o1.y) * inv);
  o4.z = f2bf((o0.z + o1.z) * inv); o4.w = f2bf((o0.w + o1.w) * inv);
  *(ushort4*)(xa + (size_t)q * 1024 + c) = o4;
}

// ---------------- merge scores: 4 src/block, identical comparator ---------
__global__ __launch_bounds__(256) void merge_score_kernel(
    const float* __restrict__ metric, const float* __restrict__ thr,
    int* __restrict__ mask, int* __restrict__ node)
{
  const int s0 = blockIdx.x * 4;
  const int t = threadIdx.x;
  __shared__ float a[4][64];
  a[t >> 6][t & 63] = metric[(size_t)(2 * (s0 + (t >> 6))) * 64 + (t & 63)];
  __syncthreads();
  float best[4] = {-INFINITY, -INFINITY, -INFINITY, -INFINITY};
  int besti[4] = {0, 0, 0, 0};
  for (int m = t; m < 1024; m += 256) {
    const float* bp = metric + (size_t)(2 * m + 1) * 64;
    float s[4] = {0.f, 0.f, 0.f, 0.f};
    #pragma unroll
    for (int d = 0; d < 64; d += 4) {
      float4 bv = *(const float4*)(bp + d);
      #pragma unroll
      for (int j = 0; j < 4; j++) {
        float4 av = *(const float4*)&a[j][d];
        s[j] += av.x*bv.x + av.y*bv.y + av.z*bv.z + av.w*bv.w;
      }
    }
    #pragma unroll
    for (int j = 0; j < 4; j++)
      if (s[j] > best[j]) { best[j] = s[j]; besti[j] = m; }   // ascending m
  }
  #pragma unroll
  for (int j = 0; j < 4; j++) {
    float b = best[j]; int bi = besti[j];
    #pragma unroll
    for (int off = 1; off < 64; off <<= 1) {
      float ov = __shfl_xor(b, off);
      int   oi = __shfl_xor(bi, off);
      if (ov > b || (ov == b && oi < bi)) { b = ov; bi = oi; }
    }
    best[j] = b; besti[j] = bi;
  }
  __shared__ float bw_[4][4]; __shared__ int biw_[4][4];
  const int wv = t >> 6;
  if ((t & 63) == 0) {
    #pragma unroll
    for (int j = 0; j < 4; j++) { bw_[wv][j] = best[j]; biw_[wv][j] = besti[j]; }
  }
  __syncthreads();
  if (t < 4) {
    const int j = t;
    float b = bw_[0][j]; int bi = biw_[0][j];
    for (int ww = 1; ww < 4; ww++)
      if (bw_[ww][j] > b || (bw_[ww][j] == b && biw_[ww][j] < bi)) { b = bw_[ww][j]; bi = biw_[ww][j]; }
    const int n = s0 + j;
    if (n == 0) { mask[0] = 0; node[0] = 0; }
    else { mask[n] = (b > thr[0]) ? 1 : 0; node[n] = bi; }
  }
}

// ---------------- exclusive prefix-sum of !mask (1024 entries) ------------
__global__ __launch_bounds__(1024) void scan_kernel(
    const int* __restrict__ mask, int* __restrict__ pos)
{
  __shared__ int s[1024];
  const int t = threadIdx.x;
  const int v0 = mask[t] ? 0 : 1;
  s[t] = v0;
  __syncthreads();
  for (int off = 1; off < 1024; off <<= 1) {
    int v = (t >= off) ? s[t - off] : 0;
    __syncthreads();
    s[t] += v;
    __syncthreads();
  }
  pos[t] = s[t] - v0;
}

// ---------------- build merged rows (unm gather + dst base) ---------------
__global__ __launch_bounds__(256) void build_kernel(
    const float* __restrict__ xres, const float* __restrict__ sz,
    const int* __restrict__ mask, const int* __restrict__ pos,
    float* __restrict__ xm, float* __restrict__ sizem, int U)
{
  const int b = blockIdx.x;
  const int t = threadIdx.x;
  int srow, orow;
  if (b < 1024) { srow = 2 * b + 1; orow = U + b; }
  else {
    const int i = b - 1024;
    if (mask[i]) return;
    srow = 2 * i; orow = pos[i];
  }
  const float ssz = sz[srow];
  const float* xp = xres + (size_t)srow * 1024;
  float* op = xm + (size_t)orow * 1024;
  const int c = t * 4;
  float4 v = *(const float4*)(xp + c);
  v.x *= ssz; v.y *= ssz; v.z *= ssz; v.w *= ssz;
  *(float4*)(op + c) = v;
  if (t == 0) sizem[orow] = ssz;
}

// ---------------- scatter-add merged src tokens into dst rows -------------
__global__ __launch_bounds__(256) void merge_add_kernel(
    const float* __restrict__ xres, const float* __restrict__ sz,
    const int* __restrict__ mask, const int* __restrict__ node,
    float* __restrict__ xm, float* __restrict__ sizem, int U)
{
  const int i = blockIdx.x;
  if (!mask[i]) return;
  const int t = threadIdx.x;
  const int srow = 2 * i;
  const int orow = U + node[i];
  const float ssz = sz[srow];
  const float* xp = xres + (size_t)srow * 1024;
  float* op = xm + (size_t)orow * 1024;
  for (int c = t; c < 1024; c += 256)
    atomicAdd(op + c, xp[c] * ssz);
  if (t == 0) atomicAdd(sizem + orow, ssz);
}

// ---------------- divide by size; emit x and size outputs -----------------
__global__ __launch_bounds__(256) void divide_kernel(
    const float* __restrict__ xm, const float* __restrict__ sizem,
    float* __restrict__ outx, float* __restrict__ outs, int M)
{
  const int total = M * 1024;
  for (int idx = blockIdx.x * 256 + threadIdx.x; idx < total; idx += gridDim.x * 256)
    outx[idx] = xm[idx] / sizem[idx >> 10];
  const int idx2 = blockIdx.x * 256 + threadIdx.x;
  if (idx2 < M) outs[idx2] = sizem[idx2];
}

extern "C" void kernel_launch(void* const* d_in, const int* in_sizes, int n_in,
                              void* d_out, int out_size, void* d_ws, size_t ws_size,
                              hipStream_t stream) {
  const float* x      = (const float*)d_in[0];
  const float* sz     = (const float*)d_in[1];
  const float* qkv_w  = (const float*)d_in[2];
  const float* proj_w = (const float*)d_in[3];
  const float* proj_b = (const float*)d_in[4];
  const float* ln1_g  = (const float*)d_in[5];
  const float* ln1_b  = (const float*)d_in[6];
  const float* ln2_g  = (const float*)d_in[7];
  const float* ln2_b  = (const float*)d_in[8];
  const float* fc1_w  = (const float*)d_in[9];
  const float* fc1_b  = (const float*)d_in[10];
  const float* fc2_w  = (const float*)d_in[11];
  const float* fc2_b  = (const float*)d_in[12];
  const float* thr    = (const float*)d_in[13];

  const int M = out_size / 1025;
  const int U = M - 1024;
  const size_t MB = 1u << 20;
  const size_t KB = 1u << 10;

  // workspace overlays (lifetimes sequential on `stream`; ws >= 256 MiB
  // per the harness's full-ws poison fill):
  //  early: w_qkvT[0,6) -> b_vt[0,4); wbar/met/mask@[6,7); lpart@[7,7.25);
  //         w_projT[8,10); b_qkv[10,22) -> b_xa[10,14) -> b_xm[10,18);
  //         b_hf[22,30) -> opart[22,38) -> b_xres[22,30);
  //         b_h[30,34) (dead after QKV GEMM; opart slice1 overlays it)
  //  late:  w_fc1T[0,8); b_g[8,21); w_fc2T[21,29); b_h2[35,39);
  //         facc[39,71) (4 partitioned slices, <=32MB)
  char* ws = (char*)d_ws;
  u16*   w_qkvT  = (u16*)(ws + 0);
  float* b_wbar  = (float*)(ws + 6 * MB);
  float* b_met   = (float*)(ws + 6 * MB + 256 * KB);
  int*   b_mask  = (int*)(ws + 6 * MB + 768 * KB);
  int*   b_node  = b_mask + 1024;
  int*   b_pos   = b_node + 1024;
  float* b_szm   = (float*)(b_pos + 1024);
  float* b_lpart = (float*)(ws + 7 * MB);            // 2 x 128KB slices
  u16*   w_projT = (u16*)(ws + 8 * MB);
  u16*   b_qkv   = (u16*)(ws + 10 * MB);
  u16*   b_xa    = (u16*)(ws + 10 * MB);   // over dead b_qkv (after attn)
  float* b_xm    = (float*)(ws + 10 * MB);   // over dead b_xa (after proj)
  float* b_hf    = (float*)(ws + 22 * MB);
  float* b_opart = (float*)(ws + 22 * MB);   // 2 x 8MB slices over dead b_hf+b_h
  float* b_xres  = (float*)(ws + 22 * MB);   // over dead opart slice0
  u16*   b_h     = (u16*)(ws + 30 * MB);
  u16*   b_vt    = (u16*)(ws + 0);
  u16*   w_fc1T  = (u16*)(ws + 0);
  u16*   b_g     = (u16*)(ws + 8 * MB);
  u16*   w_fc2T  = (u16*)(ws + 21 * MB);
  u16*   b_h2    = (u16*)(ws + 35 * MB);
  float* b_facc  = (float*)(ws + 39 * MB);   // 4 partitioned slices

  float* outx = (float*)d_out;
  float* outs = outx + (size_t)M * 1024;

  // 1. LN1 -> bf16 (for MFMA) + fp32 (for exact metric path)
  ln_kernel<<<2048, 256, 0, stream>>>(x, ln1_g, ln1_b, b_h, b_hf);
  // 2. mean-over-heads k-weights (fp32)
  wbar_kernel<<<256, 256, 0, stream>>>(qkv_w, b_wbar);
  // 3. weight converts for attention half
  convert_transpose<<<dim3(96, 32), 256, 0, stream>>>(qkv_w, w_qkvT, 1024, 3072);
  convert_transpose<<<dim3(32, 32), 256, 0, stream>>>(proj_w, w_projT, 1024, 1024);
  // 4. QKV GEMM (bf16 MFMA, 128x64 dbuf tile, R6-proven) — 768 blocks
  gemm_mfma<128, 64, 1, false, false, false, true><<<dim3(48, 16), 256, 0, stream>>>(
      b_h, w_qkvT, nullptr, nullptr, b_qkv, 2048, 3072, 1024);
  // 4b. V transpose for MFMA attention (overwrites dead w_qkvT)
  vt_kernel<<<dim3(32, 16), 256, 0, stream>>>(b_qkv, b_vt);
  // 5. exact fp32 metric (decoupled from bf16 path — merge decisions stable)
  metric_gemm_kernel<<<512, 256, 0, stream>>>(b_hf, b_wbar, b_met);
  // 6. MFMA attention: K-dbuf + single-V pipeline, partitioned outputs
  attn_mfma<2><<<dim3(32, 16, 2), 256, 0, stream>>>(b_qkv, b_vt, sz, b_opart, b_lpart);
  attn_norm_kernel<<<2048, 256, 0, stream>>>(b_opart, b_lpart, b_xa);
  // 7. proj GEMM + bias + residual(x) -> xres fp32 — 512 blocks
  gemm_mfma<64, 64, 1, true, false, true, false><<<dim3(16, 32), 256, 0, stream>>>(
      b_xa, w_projT, proj_b, x, b_xres, 2048, 1024, 1024);
  // 8-11. merge pipeline
  merge_score_kernel<<<256, 256, 0, stream>>>(b_met, thr, b_mask, b_node);
  scan_kernel<<<1, 1024, 0, stream>>>(b_mask, b_pos);
  build_kernel<<<2048, 256, 0, stream>>>(b_xres, sz, b_mask, b_pos, b_xm, b_szm, U);
  merge_add_kernel<<<1024, 256, 0, stream>>>(b_xres, sz, b_mask, b_node, b_xm, b_szm, U);
  // 12. divide + emit outputs
  divide_kernel<<<2048, 256, 0, stream>>>(b_xm, b_szm, outx, outs, M);
  // 13. late weight converts (into now-dead regions)
  convert_transpose<<<dim3(128, 32), 256, 0, stream>>>(fc1_w, w_fc1T, 1024, 4096);
  convert_transpose<<<dim3(32, 128), 256, 0, stream>>>(fc2_w, w_fc2T, 4096, 1024);
  // 14. LN2 -> bf16
  ln_kernel<<<M, 256, 0, stream>>>(outx, ln2_g, ln2_b, b_h2, nullptr);
  // 15. fc1 + bias + exact GELU -> bf16 — 768 blocks (R6-proven shape)
  gemm_mfma<128, 64, 1, true, true, false, true><<<dim3(64, (M + 127) / 128), 256, 0, stream>>>(
      b_h2, w_fc1T, fc1_b, nullptr, b_g, M, 4096, 1024);
  // 16. fc2 split-K=4, partitioned slices (no memset, no atomics)
  gemm_mfma<128, 64, 4, false, false, false, false><<<dim3(16, (M + 127) / 128, 4), 256, 0, stream>>>(
      b_g, w_fc2T, nullptr, nullptr, b_facc, M, 1024, 4096);
  // 17. fc2 epilogue: outx += sum(4 slices) + bias (residual in-place)
  splitk_epilogue_kernel<<<(M * 256 + 255) / 256, 256, 0, stream>>>(
      b_facc, fc2_b, outx, M);
  (void)in_sizes; (void)n_in; (void)ws_size;
}

// Round 11
// 296.616 us; speedup vs baseline: 1.1669x; 1.0512x over previous
//
#include <hip/hip_runtime.h>
#include <math.h>

typedef unsigned short u16;
typedef __attribute__((ext_vector_type(8))) short bf16x8;
typedef __attribute__((ext_vector_type(4))) float f32x4;

#define C_DIM 1024
#define N_TOK 2048

static __device__ __forceinline__ u16 f2bf(float f) {
  union { float f; unsigned u; } v; v.f = f;
  unsigned r = v.u + 0x7fff + ((v.u >> 16) & 1);
  return (u16)(r >> 16);
}

// packed f32x2 -> bf16x2 (RNE, same rounding as f2bf) in ONE VALU op
static __device__ __forceinline__ unsigned cvt_pk_bf16(float lo, float hi) {
  unsigned r;
  asm("v_cvt_pk_bf16_f32 %0, %1, %2" : "=v"(r) : "v"(lo), "v"(hi));
  return r;
}

// ---------------- transpose body: W[K][N] tile (by,bx) -> WT[N][K] --------
static __device__ __forceinline__ void conv_body(
    const float* __restrict__ W, u16* __restrict__ WT, int K, int N,
    int bx, int by, float (*tile)[33], int tx, int ty)
{
  #pragma unroll
  for (int i = 0; i < 32; i += 8)
    tile[ty + i][tx] = W[(size_t)(by + ty + i) * N + bx + tx];
  __syncthreads();
  #pragma unroll
  for (int i = 0; i < 32; i += 8)
    WT[(size_t)(bx + ty + i) * K + by + tx] = f2bf(tile[tx][ty + i]);
}

// ------- fused early converts + wbar: qkv_w^T, proj_w^T, wbar -------------
__global__ __launch_bounds__(256) void convert_early_kernel(
    const float* __restrict__ qkv_w, u16* __restrict__ w_qkvT,
    const float* __restrict__ proj_w, u16* __restrict__ w_projT,
    float* __restrict__ wbar)
{
  __shared__ float tile[32][33];
  const int bid = blockIdx.x;
  const int tx = threadIdx.x & 31, ty = threadIdx.x >> 5;
  if (bid < 3072) {            // qkv convert: 96 x 32 tiles (N=3072, K=1024)
    conv_body(qkv_w, w_qkvT, 1024, 3072, (bid % 96) * 32, (bid / 96) * 32, tile, tx, ty);
  } else if (bid < 4096) {     // proj convert: 32 x 32 tiles
    const int b2 = bid - 3072;
    conv_body(proj_w, w_projT, 1024, 1024, (b2 % 32) * 32, (b2 / 32) * 32, tile, tx, ty);
  } else {                     // wbar: 256 blocks
    const int idx = (bid - 4096) * 256 + threadIdx.x;   // c*64 + d
    const int c = idx >> 6, d = idx & 63;
    float s = 0.f;
    #pragma unroll
    for (int h = 0; h < 16; h++)
      s += qkv_w[(size_t)c * 3072 + 1024 + h * 64 + d];
    wbar[idx] = s * (1.0f / 16.0f);
  }
}

// ------- fused late converts: fc1_w^T (N=4096,K=1024), fc2_w^T (N=1024,K=4096)
__global__ __launch_bounds__(256) void convert_late_kernel(
    const float* __restrict__ fc1_w, u16* __restrict__ w_fc1T,
    const float* __restrict__ fc2_w, u16* __restrict__ w_fc2T)
{
  __shared__ float tile[32][33];
  const int bid = blockIdx.x;
  const int tx = threadIdx.x & 31, ty = threadIdx.x >> 5;
  if (bid < 4096) {            // fc1: 128 x 32 tiles
    conv_body(fc1_w, w_fc1T, 1024, 4096, (bid % 128) * 32, (bid / 128) * 32, tile, tx, ty);
  } else {                     // fc2: 32 x 128 tiles
    const int b2 = bid - 4096;
    conv_body(fc2_w, w_fc2T, 4096, 1024, (b2 % 32) * 32, (b2 / 32) * 32, tile, tx, ty);
  }
}

// ---------------- LayerNorm: bf16 out (+ optional fp32 out) ---------------
__global__ __launch_bounds__(256) void ln_kernel(
    const float* __restrict__ x, const float* __restrict__ g,
    const float* __restrict__ b, u16* __restrict__ out,
    float* __restrict__ fout)
{
  const int row = blockIdx.x;
  const int t = threadIdx.x;
  const float* xr = x + (size_t)row * C_DIM;
  float4 xv = *(const float4*)(xr + t * 4);
  float s  = xv.x + xv.y + xv.z + xv.w;
  float ss = xv.x*xv.x + xv.y*xv.y + xv.z*xv.z + xv.w*xv.w;
  #pragma unroll
  for (int off = 1; off < 64; off <<= 1) {
    s  += __shfl_xor(s, off);
    ss += __shfl_xor(ss, off);
  }
  __shared__ float rs[4], rss[4];
  const int w = t >> 6;
  if ((t & 63) == 0) { rs[w] = s; rss[w] = ss; }
  __syncthreads();
  s  = rs[0] + rs[1] + rs[2] + rs[3];
  ss = rss[0] + rss[1] + rss[2] + rss[3];
  const float mean = s * (1.0f / C_DIM);
  const float var  = ss * (1.0f / C_DIM) - mean * mean;
  const float inv  = rsqrtf(var + 1e-5f);
  float4 gv = *(const float4*)(g + t * 4);
  float4 bv = *(const float4*)(b + t * 4);
  float4 o;
  o.x = (xv.x - mean) * inv * gv.x + bv.x;
  o.y = (xv.y - mean) * inv * gv.y + bv.y;
  o.z = (xv.z - mean) * inv * gv.z + bv.z;
  o.w = (xv.w - mean) * inv * gv.w + bv.w;
  ushort4 o4;
  o4.x = f2bf(o.x); o4.y = f2bf(o.y); o4.z = f2bf(o.z); o4.w = f2bf(o.w);
  *(ushort4*)(out + (size_t)row * C_DIM + t * 4) = o4;
  if (fout != nullptr)
    *(float4*)(fout + (size_t)row * C_DIM + t * 4) = o;
}

// -------- fused divide + LN2: v = xm/size -> outx/outs, LN(v) -> h2 -------
// Division kept elementwise (same rounding as old divide_kernel); LN
// reduction copied verbatim from ln_kernel -> bitwise-identical results.
__global__ __launch_bounds__(256) void divide_ln2_kernel(
    const float* __restrict__ xm, const float* __restrict__ sizem,
    const float* __restrict__ g, const float* __restrict__ b,
    float* __restrict__ outx, float* __restrict__ outs,
    u16* __restrict__ h2)
{
  const int row = blockIdx.x;
  const int t = threadIdx.x;
  const float sz = sizem[row];
  float4 xv = *(const float4*)(xm + (size_t)row * C_DIM + t * 4);
  xv.x = xv.x / sz; xv.y = xv.y / sz; xv.z = xv.z / sz; xv.w = xv.w / sz;
  *(float4*)(outx + (size_t)row * C_DIM + t * 4) = xv;
  if (t == 0) outs[row] = sz;
  float s  = xv.x + xv.y + xv.z + xv.w;
  float ss = xv.x*xv.x + xv.y*xv.y + xv.z*xv.z + xv.w*xv.w;
  #pragma unroll
  for (int off = 1; off < 64; off <<= 1) {
    s  += __shfl_xor(s, off);
    ss += __shfl_xor(ss, off);
  }
  __shared__ float rs[4], rss[4];
  const int w = t >> 6;
  if ((t & 63) == 0) { rs[w] = s; rss[w] = ss; }
  __syncthreads();
  s  = rs[0] + rs[1] + rs[2] + rs[3];
  ss = rss[0] + rss[1] + rss[2] + rss[3];
  const float mean = s * (1.0f / C_DIM);
  const float var  = ss * (1.0f / C_DIM) - mean * mean;
  const float inv  = rsqrtf(var + 1e-5f);
  float4 gv = *(const float4*)(g + t * 4);
  float4 bv = *(const float4*)(b + t * 4);
  float4 o;
  o.x = (xv.x - mean) * inv * gv.x + bv.x;
  o.y = (xv.y - mean) * inv * gv.y + bv.y;
  o.z = (xv.z - mean) * inv * gv.z + bv.z;
  o.w = (xv.w - mean) * inv * gv.w + bv.w;
  ushort4 o4;
  o4.x = f2bf(o.x); o4.y = f2bf(o.y); o4.z = f2bf(o.z); o4.w = f2bf(o.w);
  *(ushort4*)(h2 + (size_t)row * C_DIM + t * 4) = o4;
}

// ---------------- bf16 MFMA GEMM: C[M,N] = A[M,K] @ BT[N,K]^T -------------
// R6 geometry (proven): BN=64, LDS double-buffer, one barrier/iter.
// SPLIT>1 writes PARTITIONED slices (plain stores); epilogue sums.
template<int BM, int BN, int SPLIT, bool BIAS, bool GELU, bool RES, bool OUT_BF16>
__global__ __launch_bounds__(256) void gemm_mfma(
    const u16* __restrict__ A,   // [>=gridDim.y*BM][K] bf16 (readable padding)
    const u16* __restrict__ BT,  // [N][K] bf16
    const float* __restrict__ bias, const float* __restrict__ res,
    void* __restrict__ Cout, int M, int N, int K)
{
  constexpr int TM = BM / 32;                 // 16x16 tiles per wave (rows)
  constexpr int TN = BN / 32;                 // 16x16 tiles per wave (cols)
  __shared__ u16 As[2][BM * 64] __attribute__((aligned(16)));
  __shared__ u16 Bs[2][BN * 64] __attribute__((aligned(16)));
  const int tid  = threadIdx.x;
  const int lane = tid & 63;
  const int w    = tid >> 6;
  const int bm = blockIdx.y * BM;
  const int bn = blockIdx.x * BN;
  const int wm = (w >> 1) * (BM / 2);
  const int wn = (w & 1) * (BN / 2);

  f32x4 acc[TM][TN] = {};

  const int rl = lane >> 3;                 // row-in-8-group
  const int cg = (lane & 7) ^ rl;           // swizzled source chunk

  const int kb = (K / SPLIT) * blockIdx.z;
  const int ke = kb + K / SPLIT;

#define GEMM_STAGE(buf, k0_)                                                   \
  {                                                                            \
    _Pragma("unroll")                                                          \
    for (int i = 0; i < BM / 32; i++) {                                        \
      const int r = w * (BM / 4) + i * 8 + rl;                                 \
      __builtin_amdgcn_global_load_lds(                                        \
          (const __attribute__((address_space(1))) void*)(A + (size_t)(bm + r) * K + (k0_) + cg * 8), \
          (__attribute__((address_space(3))) void*)(&As[buf][(w * (BM / 4) + i * 8) * 64]), \
          16, 0, 0);                                                           \
    }                                                                          \
    _Pragma("unroll")                                                          \
    for (int i = 0; i < BN / 32; i++) {                                        \
      const int r = w * (BN / 4) + i * 8 + rl;                                 \
      __builtin_amdgcn_global_load_lds(                                        \
          (const __attribute__((address_space(1))) void*)(BT + (size_t)(bn + r) * K + (k0_) + cg * 8), \
          (__attribute__((address_space(3))) void*)(&Bs[buf][(w * (BN / 4) + i * 8) * 64]), \
          16, 0, 0);                                                           \
    }                                                                          \
  }

  // prologue: stage first K-tile into buffer 0
  GEMM_STAGE(0, kb);
  __syncthreads();

  int cur = 0;
  for (int k0 = kb; k0 < ke; k0 += 64) {
    // issue next tile's loads into the other buffer (overlap compute)
    if (k0 + 64 < ke) GEMM_STAGE(cur ^ 1, k0 + 64);

    #pragma unroll
    for (int kk = 0; kk < 2; kk++) {
      bf16x8 af[TM], bfr[TN];
      const int slot = (kk * 4 + (lane >> 4)) ^ (lane & 7);
      #pragma unroll
      for (int i = 0; i < TM; i++)
        af[i] = *(const bf16x8*)&As[cur][(wm + i * 16 + (lane & 15)) * 64 + slot * 8];
      #pragma unroll
      for (int j = 0; j < TN; j++)
        bfr[j] = *(const bf16x8*)&Bs[cur][(wn + j * 16 + (lane & 15)) * 64 + slot * 8];
      __builtin_amdgcn_s_setprio(1);
      #pragma unroll
      for (int i = 0; i < TM; i++)
        #pragma unroll
        for (int j = 0; j < TN; j++)
          acc[i][j] = __builtin_amdgcn_mfma_f32_16x16x32_bf16(af[i], bfr[j], acc[i][j], 0, 0, 0);
      __builtin_amdgcn_s_setprio(0);
    }
    // one barrier/iter: (a) implicit vmcnt(0) makes buf[cur^1]'s staged
    // loads visible for next compute; (b) all waves done reading buf[cur]
    // so next iteration may overwrite it.
    __syncthreads();
    cur ^= 1;
  }
#undef GEMM_STAGE

  if constexpr (SPLIT > 1) {
    // partitioned plain stores: slice z at Cf + z*M*N (sole writer)
    float* Cf = (float*)Cout + (size_t)blockIdx.z * ((size_t)M * N);
    #pragma unroll
    for (int i = 0; i < TM; i++)
      #pragma unroll
      for (int r = 0; r < 4; r++) {
        const int m = bm + wm + i * 16 + (lane >> 4) * 4 + r;
        if (m < M) {
          #pragma unroll
          for (int j = 0; j < TN; j++) {
            const int n = bn + wn + j * 16 + (lane & 15);
            Cf[(size_t)m * N + n] = acc[i][j][r];
          }
        }
      }
  } else {
    #pragma unroll
    for (int i = 0; i < TM; i++) {
      #pragma unroll
      for (int r = 0; r < 4; r++) {
        const int m = bm + wm + i * 16 + (lane >> 4) * 4 + r;
        if (m < M) {
          #pragma unroll
          for (int j = 0; j < TN; j++) {
            const int n = bn + wn + j * 16 + (lane & 15);
            float v = acc[i][j][r];
            if (BIAS) v += bias[n];
            if (GELU) v = 0.5f * v * (1.0f + erff(v * 0.70710678118654752f));
            if (RES)  v += res[(size_t)m * N + n];
            if (OUT_BF16) ((u16*)Cout)[(size_t)m * N + n] = f2bf(v);
            else          ((float*)Cout)[(size_t)m * N + n] = v;
          }
        }
      }
    }
  }
}

// ------ split-K epilogue: out += sum(4 slices) + bias (in-place res) ------
__global__ __launch_bounds__(256) void splitk_epilogue_kernel(
    const float* __restrict__ acc, const float* __restrict__ bias,
    float* __restrict__ out, int M)
{
  const int idx = blockIdx.x * 256 + threadIdx.x;   // float4 index
  if (idx >= M * 256) return;
  const size_t S = (size_t)M * 256;                 // slice stride in float4
  const float4* a4 = (const float4*)acc;
  float4 a0 = a4[idx], a1 = a4[idx + S], a2 = a4[idx + 2 * S], a3 = a4[idx + 3 * S];
  float4 bv = *(const float4*)(bias + (idx & 255) * 4);
  float4 o = *(const float4*)(out + (size_t)idx * 4);
  o.x += (a0.x + a1.x) + (a2.x + a3.x) + bv.x;
  o.y += (a0.y + a1.y) + (a2.y + a3.y) + bv.y;
  o.z += (a0.z + a1.z) + (a2.z + a3.z) + bv.z;
  o.w += (a0.w + a1.w) + (a2.w + a3.w) + bv.w;
  *(float4*)(out + (size_t)idx * 4) = o;
}

// -------- fused vt + metric (independent work, packed in one launch) ------
// bid < 512: V transpose (x = bid&31 -> t0, h = bid>>5)
// bid >= 512: metric block n0 = (bid-512)*4
__global__ __launch_bounds__(256) void vt_metric_kernel(
    const u16* __restrict__ qkv, u16* __restrict__ vt,
    const float* __restrict__ hf, const float* __restrict__ wbar,
    float* __restrict__ metric)
{
  __shared__ __attribute__((aligned(16))) char smem[16384];
  const int bid = blockIdx.x;
  const int tid = threadIdx.x;
  if (bid < 512) {
    u16 (*tile)[72] = (u16(*)[72])smem;
    const int h  = bid >> 5;
    const int t0 = (bid & 31) * 64;
    const int row = tid >> 3;   // 0..31
    const int ch  = tid & 7;
    #pragma unroll
    for (int i = 0; i < 2; i++) {
      const int tok = row + i * 32;
      *(bf16x8*)&tile[tok][ch * 8] =
          *(const bf16x8*)(qkv + (size_t)(t0 + tok) * 3072 + 2048 + h * 64 + ch * 8);
    }
    __syncthreads();
    #pragma unroll
    for (int i = 0; i < 2; i++) {
      const int d = row + i * 32;
      u16 tmp[8];
      #pragma unroll
      for (int j = 0; j < 8; j++) tmp[j] = tile[ch * 8 + j][d];
      *(bf16x8*)(vt + (size_t)(h * 64 + d) * 2048 + t0 + ch * 8) = *(bf16x8*)tmp;
    }
  } else {
    float (*hs)[1024] = (float(*)[1024])smem;
    const int n0 = (bid - 512) * 4;
    const int t = tid;
    #pragma unroll
    for (int i = 0; i < 4; i++)
      *(float4*)&hs[i][t * 4] = *(const float4*)(hf + (size_t)(n0 + i) * 1024 + t * 4);
    __syncthreads();
    const int d = t & 63;
    const float* hsw = hs[t >> 6];
    float a0=0,a1=0,a2=0,a3=0,a4=0,a5=0,a6=0,a7=0;
    for (int c = 0; c < 1024; c += 8) {
      a0 += hsw[c+0] * wbar[(c+0)*64 + d];
      a1 += hsw[c+1] * wbar[(c+1)*64 + d];
      a2 += hsw[c+2] * wbar[(c+2)*64 + d];
      a3 += hsw[c+3] * wbar[(c+3)*64 + d];
      a4 += hsw[c+4] * wbar[(c+4)*64 + d];
      a5 += hsw[c+5] * wbar[(c+5)*64 + d];
      a6 += hsw[c+6] * wbar[(c+6)*64 + d];
      a7 += hsw[c+7] * wbar[(c+7)*64 + d];
    }
    float s = ((a0+a1)+(a2+a3)) + ((a4+a5)+(a6+a7));
    float sq = s * s;
    #pragma unroll
    for (int off = 1; off < 64; off <<= 1) sq += __shfl_xor(sq, off);
    metric[(size_t)(n0 + (t >> 6)) * 64 + d] = s / sqrtf(sq);
  }
}

// ---------------- MFMA flash attention, no-max softmax, S^T trick ---------
// R4 structure (proven): K double-buffered, V single-buffered, 2 barriers/
// iter, 4 blocks/CU. R9: partitioned outputs (plain stores, no atomics).
template<int SPLIT>
__global__ __launch_bounds__(256) void attn_mfma(
    const u16* __restrict__ qkv, const u16* __restrict__ vt,
    const float* __restrict__ sz, float* __restrict__ opart,
    float* __restrict__ lpart)
{
  const int h   = blockIdx.y;
  const int q0  = blockIdx.x * 64;
  const int tid = threadIdx.x;
  const int lane = tid & 63;
  const int w    = tid >> 6;
  const int col  = lane & 15;
  const int quad = lane >> 4;

  __shared__ u16 Ks [2][64 * 64] __attribute__((aligned(16))); // [key][d] swizzled, dbuf
  __shared__ u16 Vts[64 * 64] __attribute__((aligned(16)));    // [d][key] swizzled, single
  __shared__ u16 Ps[4][16 * 72] __attribute__((aligned(16)));  // per-wave P[q][key]
  __shared__ float lball[N_TOK / SPLIT];                       // log2(size) per key

  bf16x8 qf[2];
  {
    const u16* qp = qkv + (size_t)(q0 + w * 16 + col) * 3072 + h * 64 + quad * 8;
    qf[0] = *(const bf16x8*)(qp);
    qf[1] = *(const bf16x8*)(qp + 32);
  }

  float l_lane = 0.f;          // all partials belong to q = q0 + w*16 + col
  f32x4 oacc[4] = {};

  const int rl = lane >> 3;
  const int cg = (lane & 7) ^ rl;
  const int kb = blockIdx.z * (N_TOK / SPLIT);
  const int ke = kb + N_TOK / SPLIT;

  // 0.125 * log2(e): fold the 1/8 scale and the nat->log2 conversion together
  constexpr float kScaleLog2e = 0.18033688011112042f;

  // ---- prologue: stage K[0], V[0]; precompute ALL log2(size) once ----
  #pragma unroll
  for (int i = 0; i < 2; i++) {
    const int r = w * 16 + i * 8 + rl;
    __builtin_amdgcn_global_load_lds(
        (const __attribute__((address_space(1))) void*)(qkv + (size_t)(kb + r) * 3072 + 1024 + h * 64 + cg * 8),
        (__attribute__((address_space(3))) void*)(&Ks[0][(w * 16 + i * 8) * 64]),
        16, 0, 0);
    __builtin_amdgcn_global_load_lds(
        (const __attribute__((address_space(1))) void*)(vt + (size_t)(h * 64 + r) * 2048 + kb + cg * 8),
        (__attribute__((address_space(3))) void*)(&Vts[(w * 16 + i * 8) * 64]),
        16, 0, 0);
  }
  #pragma unroll
  for (int i = tid; i < N_TOK / SPLIT; i += 256)
    lball[i] = __builtin_amdgcn_logf(sz[kb + i]);   // v_log_f32 = log2
  __syncthreads();   // drains prologue staging (vmcnt + lgkmcnt)

  int cur = 0;
  for (int kt = kb; kt < ke; kt += 64) {
    const int nxt = cur ^ 1;
    const bool has_next = (kt + 64 < ke);   // block-uniform

    // ---- issue NEXT K tile into the other K buffer (full-iter overlap) ---
    if (has_next) {
      #pragma unroll
      for (int i = 0; i < 2; i++) {
        const int r = w * 16 + i * 8 + rl;
        __builtin_amdgcn_global_load_lds(
            (const __attribute__((address_space(1))) void*)(qkv + (size_t)(kt + 64 + r) * 3072 + 1024 + h * 64 + cg * 8),
            (__attribute__((address_space(3))) void*)(&Ks[nxt][(w * 16 + i * 8) * 64]),
            16, 0, 0);
      }
    }

    // ---- S^T = K Q^T : lane holds S^T[key = jt*16+quad*4+r][q = col] ----
    const u16* Kc = Ks[cur];
    f32x4 sacc[4] = {};
    #pragma unroll
    for (int kk = 0; kk < 2; kk++) {
      const int slot = (kk * 4 + quad) ^ (lane & 7);
      bf16x8 kf[4];
      #pragma unroll
      for (int jt = 0; jt < 4; jt++)
        kf[jt] = *(const bf16x8*)&Kc[(jt * 16 + col) * 64 + slot * 8];
      __builtin_amdgcn_s_setprio(1);
      #pragma unroll
      for (int jt = 0; jt < 4; jt++)
        sacc[jt] = __builtin_amdgcn_mfma_f32_16x16x32_bf16(kf[jt], qf[kk], sacc[jt], 0, 0, 0);
      __builtin_amdgcn_s_setprio(0);
    }

    // exp2-domain softmax weights + packed P-writes (4x b64), l per-lane
    u16* pw = Ps[w];
    const float* lbp = &lball[kt - kb];
    #pragma unroll
    for (int jt = 0; jt < 4; jt++) {
      float4 lb4 = *(const float4*)&lbp[jt * 16 + quad * 4];
      const float p0 = __builtin_amdgcn_exp2f(fmaf(sacc[jt][0], kScaleLog2e, lb4.x));
      const float p1 = __builtin_amdgcn_exp2f(fmaf(sacc[jt][1], kScaleLog2e, lb4.y));
      const float p2 = __builtin_amdgcn_exp2f(fmaf(sacc[jt][2], kScaleLog2e, lb4.z));
      const float p3 = __builtin_amdgcn_exp2f(fmaf(sacc[jt][3], kScaleLog2e, lb4.w));
      l_lane += (p0 + p1) + (p2 + p3);
      uint2 pkk;
      pkk.x = cvt_pk_bf16(p0, p1);
      pkk.y = cvt_pk_bf16(p2, p3);
      *(uint2*)&pw[col * 72 + jt * 16 + quad * 4] = pkk;
    }
    // same-wave LDS RAW -> lgkmcnt (verified pattern); rows 144B apart
    bf16x8 pf[2];
    #pragma unroll
    for (int kk = 0; kk < 2; kk++)
      pf[kk] = *(const bf16x8*)&pw[col * 72 + kk * 32 + quad * 8];

    // barrier A: implicit vmcnt(0) drains V[this tile] (issued last iter,
    // had the whole QK+softmax above to load) + K[nxt] (usually done too)
    __syncthreads();

    // O += P V (A = P rows=q, B = V^T)
    #pragma unroll
    for (int kk = 0; kk < 2; kk++) {
      const int slot = (kk * 4 + quad) ^ (lane & 7);
      bf16x8 vf[4];
      #pragma unroll
      for (int nt = 0; nt < 4; nt++)
        vf[nt] = *(const bf16x8*)&Vts[(nt * 16 + col) * 64 + slot * 8];
      __builtin_amdgcn_s_setprio(1);
      #pragma unroll
      for (int nt = 0; nt < 4; nt++)
        oacc[nt] = __builtin_amdgcn_mfma_f32_16x16x32_bf16(pf[kk], vf[nt], oacc[nt], 0, 0, 0);
      __builtin_amdgcn_s_setprio(0);
    }

    // barrier B: all waves done reading Vts -> safe to overwrite
    __syncthreads();

    // ---- issue NEXT V tile into the single V buffer (overlaps next QK) --
    if (has_next) {
      #pragma unroll
      for (int i = 0; i < 2; i++) {
        const int r = w * 16 + i * 8 + rl;
        __builtin_amdgcn_global_load_lds(
            (const __attribute__((address_space(1))) void*)(vt + (size_t)(h * 64 + r) * 2048 + kt + 64 + cg * 8),
            (__attribute__((address_space(3))) void*)(&Vts[(w * 16 + i * 8) * 64]),
            16, 0, 0);
      }
    }
    cur = nxt;
  }

  // l: sum the 4 quads of each col group (once)
  l_lane += __shfl_xor(l_lane, 16);
  l_lane += __shfl_xor(l_lane, 32);

  // partitioned plain stores (sole writer per (q,h,z) — no atomics)
  float* osl = opart + (size_t)blockIdx.z * ((size_t)N_TOK * 1024);
  #pragma unroll
  for (int r = 0; r < 4; r++) {
    const int q = q0 + w * 16 + quad * 4 + r;
    float* op = osl + (size_t)q * 1024 + h * 64 + col;
    #pragma unroll
    for (int nt = 0; nt < 4; nt++)
      op[nt * 16] = oacc[nt][r];
  }
  if (quad == 0)
    lpart[(size_t)blockIdx.z * (N_TOK * 16) + (q0 + w * 16 + col) * 16 + h] = l_lane;
}

// ------ fused attn-normalize + merge-score (independent work, packed) -----
// bid < 2048: normalize O by l (sum 2 slices), emit bf16 xa (q = bid)
// bid >= 2048: merge_score block s0 = (bid-2048)*4
__global__ __launch_bounds__(256) void norm_score_kernel(
    const float* __restrict__ opart, const float* __restrict__ lpart,
    u16* __restrict__ xa,
    const float* __restrict__ metric, const float* __restrict__ thr,
    int* __restrict__ mask, int* __restrict__ node)
{
  __shared__ float a[4][64];
  __shared__ float bw_[4][4];
  __shared__ int biw_[4][4];
  const int bid = blockIdx.x;
  const int t = threadIdx.x;
  if (bid < 2048) {
    const int q = bid;
    const int c = t * 4;
    float4 o0 = *(const float4*)(opart + (size_t)q * 1024 + c);
    float4 o1 = *(const float4*)(opart + (size_t)N_TOK * 1024 + (size_t)q * 1024 + c);
    const float l0 = lpart[q * 16 + (c >> 6)];
    const float l1 = lpart[N_TOK * 16 + q * 16 + (c >> 6)];
    const float inv = 1.0f / (l0 + l1);
    ushort4 o4;
    o4.x = f2bf((o0.x + o1.x) * inv); o4.y = f2bf((o0.y + o1.y) * inv);
    o4.z = f2bf((o0.z + o1.z) * inv); o4.w = f2bf((o0.w + o1.w) * inv);
    *(ushort4*)(xa + (size_t)q * 1024 + c) = o4;
    return;
  }
  const int s0 = (bid - 2048) * 4;
  a[t >> 6][t & 63] = metric[(size_t)(2 * (s0 + (t >> 6))) * 64 + (t & 63)];
  __syncthreads();
  float best[4] = {-INFINITY, -INFINITY, -INFINITY, -INFINITY};
  int besti[4] = {0, 0, 0, 0};
  for (int m = t; m < 1024; m += 256) {
    const float* bp = metric + (size_t)(2 * m + 1) * 64;
    float s[4] = {0.f, 0.f, 0.f, 0.f};
    #pragma unroll
    for (int d = 0; d < 64; d += 4) {
      float4 bv = *(const float4*)(bp + d);
      #pragma unroll
      for (int j = 0; j < 4; j++) {
        float4 av = *(const float4*)&a[j][d];
        s[j] += av.x*bv.x + av.y*bv.y + av.z*bv.z + av.w*bv.w;
      }
    }
    #pragma unroll
    for (int j = 0; j < 4; j++)
      if (s[j] > best[j]) { best[j] = s[j]; besti[j] = m; }   // ascending m
  }
  #pragma unroll
  for (int j = 0; j < 4; j++) {
    float b = best[j]; int bi = besti[j];
    #pragma unroll
    for (int off = 1; off < 64; off <<= 1) {
      float ov = __shfl_xor(b, off);
      int   oi = __shfl_xor(bi, off);
      if (ov > b || (ov == b && oi < bi)) { b = ov; bi = oi; }
    }
    best[j] = b; besti[j] = bi;
  }
  const int wv = t >> 6;
  if ((t & 63) == 0) {
    #pragma unroll
    for (int j = 0; j < 4; j++) { bw_[wv][j] = best[j]; biw_[wv][j] = besti[j]; }
  }
  __syncthreads();
  if (t < 4) {
    const int j = t;
    float b = bw_[0][j]; int bi = biw_[0][j];
    for (int ww = 1; ww < 4; ww++)
      if (bw_[ww][j] > b || (bw_[ww][j] == b && biw_[ww][j] < bi)) { b = bw_[ww][j]; bi = biw_[ww][j]; }
    const int n = s0 + j;
    if (n == 0) { mask[0] = 0; node[0] = 0; }
    else { mask[n] = (b > thr[0]) ? 1 : 0; node[n] = bi; }
  }
}

// ---------------- exclusive prefix-sum of !mask (1024 entries) ------------
__global__ __launch_bounds__(1024) void scan_kernel(
    const int* __restrict__ mask, int* __restrict__ pos)
{
  __shared__ int s[1024];
  const int t = threadIdx.x;
  const int v0 = mask[t] ? 0 : 1;
  s[t] = v0;
  __syncthreads();
  for (int off = 1; off < 1024; off <<= 1) {
    int v = (t >= off) ? s[t - off] : 0;
    __syncthreads();
    s[t] += v;
    __syncthreads();
  }
  pos[t] = s[t] - v0;
}

// ---------------- build merged rows (unm gather + dst base) ---------------
__global__ __launch_bounds__(256) void build_kernel(
    const float* __restrict__ xres, const float* __restrict__ sz,
    const int* __restrict__ mask, const int* __restrict__ pos,
    float* __restrict__ xm, float* __restrict__ sizem, int U)
{
  const int b = blockIdx.x;
  const int t = threadIdx.x;
  int srow, orow;
  if (b < 1024) { srow = 2 * b + 1; orow = U + b; }
  else {
    const int i = b - 1024;
    if (mask[i]) return;
    srow = 2 * i; orow = pos[i];
  }
  const float ssz = sz[srow];
  const float* xp = xres + (size_t)srow * 1024;
  float* op = xm + (size_t)orow * 1024;
  const int c = t * 4;
  float4 v = *(const float4*)(xp + c);
  v.x *= ssz; v.y *= ssz; v.z *= ssz; v.w *= ssz;
  *(float4*)(op + c) = v;
  if (t == 0) sizem[orow] = ssz;
}

// ---------------- scatter-add merged src tokens into dst rows -------------
__global__ __launch_bounds__(256) void merge_add_kernel(
    const float* __restrict__ xres, const float* __restrict__ sz,
    const int* __restrict__ mask, const int* __restrict__ node,
    float* __restrict__ xm, float* __restrict__ sizem, int U)
{
  const int i = blockIdx.x;
  if (!mask[i]) return;
  const int t = threadIdx.x;
  const int srow = 2 * i;
  const int orow = U + node[i];
  const float ssz = sz[srow];
  const float* xp = xres + (size_t)srow * 1024;
  float* op = xm + (size_t)orow * 1024;
  for (int c = t; c < 1024; c += 256)
    atomicAdd(op + c, xp[c] * ssz);
  if (t == 0) atomicAdd(sizem + orow, ssz);
}

extern "C" void kernel_launch(void* const* d_in, const int* in_sizes, int n_in,
                              void* d_out, int out_size, void* d_ws, size_t ws_size,
                              hipStream_t stream) {
  const float* x      = (const float*)d_in[0];
  const float* sz     = (const float*)d_in[1];
  const float* qkv_w  = (const float*)d_in[2];
  const float* proj_w = (const float*)d_in[3];
  const float* proj_b = (const float*)d_in[4];
  const float* ln1_g  = (const float*)d_in[5];
  const float* ln1_b  = (const float*)d_in[6];
  const float* ln2_g  = (const float*)d_in[7];
  const float* ln2_b  = (const float*)d_in[8];
  const float* fc1_w  = (const float*)d_in[9];
  const float* fc1_b  = (const float*)d_in[10];
  const float* fc2_w  = (const float*)d_in[11];
  const float* fc2_b  = (const float*)d_in[12];
  const float* thr    = (const float*)d_in[13];

  const int M = out_size / 1025;
  const int U = M - 1024;
  const size_t MB = 1u << 20;
  const size_t KB = 1u << 10;

  // workspace overlays (lifetimes sequential on `stream`; ws >= 256 MiB):
  //  early: w_qkvT[0,6) -> b_vt[0,4); wbar/met/mask@[6,7); lpart@[7,7.25);
  //         w_projT[8,10); b_qkv[10,22) -> b_xa[10,14) -> b_xm[10,18);
  //         b_hf[22,30) -> opart[22,38) -> b_xres[22,30);
  //         b_h[30,34) (dead after QKV GEMM; opart slice1 overlays it)
  //  late:  w_fc1T[0,8); b_g[8,21); w_fc2T[21,29); b_h2[35,39);
  //         facc[39,71) (4 partitioned slices, <=32MB)
  char* ws = (char*)d_ws;
  u16*   w_qkvT  = (u16*)(ws + 0);
  float* b_wbar  = (float*)(ws + 6 * MB);
  float* b_met   = (float*)(ws + 6 * MB + 256 * KB);
  int*   b_mask  = (int*)(ws + 6 * MB + 768 * KB);
  int*   b_node  = b_mask + 1024;
  int*   b_pos   = b_node + 1024;
  float* b_szm   = (float*)(b_pos + 1024);
  float* b_lpart = (float*)(ws + 7 * MB);            // 2 x 128KB slices
  u16*   w_projT = (u16*)(ws + 8 * MB);
  u16*   b_qkv   = (u16*)(ws + 10 * MB);
  u16*   b_xa    = (u16*)(ws + 10 * MB);   // over dead b_qkv (after attn)
  float* b_xm    = (float*)(ws + 10 * MB);   // over dead b_xa (after proj)
  float* b_hf    = (float*)(ws + 22 * MB);
  float* b_opart = (float*)(ws + 22 * MB);   // 2 x 8MB slices over dead b_hf+b_h
  float* b_xres  = (float*)(ws + 22 * MB);   // over dead opart slice0
  u16*   b_h     = (u16*)(ws + 30 * MB);
  u16*   b_vt    = (u16*)(ws + 0);
  u16*   w_fc1T  = (u16*)(ws + 0);
  u16*   b_g     = (u16*)(ws + 8 * MB);
  u16*   w_fc2T  = (u16*)(ws + 21 * MB);
  u16*   b_h2    = (u16*)(ws + 35 * MB);
  float* b_facc  = (float*)(ws + 39 * MB);   // 4 partitioned slices

  float* outx = (float*)d_out;
  float* outs = outx + (size_t)M * 1024;

  // 1. LN1 -> bf16 (for MFMA) + fp32 (for exact metric path)
  ln_kernel<<<2048, 256, 0, stream>>>(x, ln1_g, ln1_b, b_h, b_hf);
  // 2. fused early converts + wbar (4352 blocks: qkv^T | proj^T | wbar)
  convert_early_kernel<<<4352, 256, 0, stream>>>(qkv_w, w_qkvT, proj_w, w_projT, b_wbar);
  // 3. QKV GEMM (bf16 MFMA, 128x64 dbuf tile) — 768 blocks
  gemm_mfma<128, 64, 1, false, false, false, true><<<dim3(48, 16), 256, 0, stream>>>(
      b_h, w_qkvT, nullptr, nullptr, b_qkv, 2048, 3072, 1024);
  // 4. fused V-transpose + exact fp32 metric (independent, packed)
  vt_metric_kernel<<<1024, 256, 0, stream>>>(b_qkv, b_vt, b_hf, b_wbar, b_met);
  // 5. MFMA attention: K-dbuf + single-V pipeline, partitioned outputs
  attn_mfma<2><<<dim3(32, 16, 2), 256, 0, stream>>>(b_qkv, b_vt, sz, b_opart, b_lpart);
  // 6. fused attn-normalize + merge-score (independent, packed)
  norm_score_kernel<<<2304, 256, 0, stream>>>(b_opart, b_lpart, b_xa, b_met, thr, b_mask, b_node);
  // 7. proj GEMM + bias + residual(x) -> xres fp32 — 512 blocks
  gemm_mfma<64, 64, 1, true, false, true, false><<<dim3(16, 32), 256, 0, stream>>>(
      b_xa, w_projT, proj_b, x, b_xres, 2048, 1024, 1024);
  // 8-10. merge pipeline
  scan_kernel<<<1, 1024, 0, stream>>>(b_mask, b_pos);
  build_kernel<<<2048, 256, 0, stream>>>(b_xres, sz, b_mask, b_pos, b_xm, b_szm, U);
  merge_add_kernel<<<1024, 256, 0, stream>>>(b_xres, sz, b_mask, b_node, b_xm, b_szm, U);
  // 11. fused divide + LN2 (one block per row): outx, outs, h2
  divide_ln2_kernel<<<M, 256, 0, stream>>>(b_xm, b_szm, ln2_g, ln2_b, outx, outs, b_h2);
  // 12. fused late converts (fc1^T | fc2^T) into now-dead regions
  convert_late_kernel<<<8192, 256, 0, stream>>>(fc1_w, w_fc1T, fc2_w, w_fc2T);
  // 13. fc1 + bias + exact GELU -> bf16 — 768 blocks
  gemm_mfma<128, 64, 1, true, true, false, true><<<dim3(64, (M + 127) / 128), 256, 0, stream>>>(
      b_h2, w_fc1T, fc1_b, nullptr, b_g, M, 4096, 1024);
  // 14. fc2 split-K=4, partitioned slices (no memset, no atomics)
  gemm_mfma<128, 64, 4, false, false, false, false><<<dim3(16, (M + 127) / 128, 4), 256, 0, stream>>>(
      b_g, w_fc2T, nullptr, nullptr, b_facc, M, 1024, 4096);
  // 15. fc2 epilogue: outx += sum(4 slices) + bias (residual in-place)
  splitk_epilogue_kernel<<<(M * 256 + 255) / 256, 256, 0, stream>>>(
      b_facc, fc2_b, outx, M);
  (void)in_sizes; (void)n_in; (void)ws_size;
}

// Round 12
// 292.785 us; speedup vs baseline: 1.1821x; 1.0131x over previous
//
#include <hip/hip_runtime.h>
#include <math.h>

typedef unsigned short u16;
typedef __attribute__((ext_vector_type(8))) short bf16x8;
typedef __attribute__((ext_vector_type(4))) float f32x4;

#define C_DIM 1024
#define N_TOK 2048

static __device__ __forceinline__ u16 f2bf(float f) {
  union { float f; unsigned u; } v; v.f = f;
  unsigned r = v.u + 0x7fff + ((v.u >> 16) & 1);
  return (u16)(r >> 16);
}

// packed f32x2 -> bf16x2 (RNE, same rounding as f2bf) in ONE VALU op
static __device__ __forceinline__ unsigned cvt_pk_bf16(float lo, float hi) {
  unsigned r;
  asm("v_cvt_pk_bf16_f32 %0, %1, %2" : "=v"(r) : "v"(lo), "v"(hi));
  return r;
}

// ---------------- transpose body: W[K][N] tile (by,bx) -> WT[N][K] --------
static __device__ __forceinline__ void conv_body(
    const float* __restrict__ W, u16* __restrict__ WT, int K, int N,
    int bx, int by, float (*tile)[33], int tx, int ty)
{
  #pragma unroll
  for (int i = 0; i < 32; i += 8)
    tile[ty + i][tx] = W[(size_t)(by + ty + i) * N + bx + tx];
  __syncthreads();
  #pragma unroll
  for (int i = 0; i < 32; i += 8)
    WT[(size_t)(bx + ty + i) * K + by + tx] = f2bf(tile[tx][ty + i]);
}

// ---- fused opening launch: LN1 + ALL weight converts + wbar (input-only) -
// bid ranges: [0,2048) ln1 | [2048,5120) qkv^T | [5120,6144) proj^T |
//             [6144,10240) fc1^T | [10240,14336) fc2^T | [14336,14592) wbar
__global__ __launch_bounds__(256) void fused_pre_kernel(
    const float* __restrict__ x, const float* __restrict__ ln1_g,
    const float* __restrict__ ln1_b, u16* __restrict__ b_h,
    float* __restrict__ b_hf,
    const float* __restrict__ qkv_w, u16* __restrict__ w_qkvT,
    const float* __restrict__ proj_w, u16* __restrict__ w_projT,
    const float* __restrict__ fc1_w, u16* __restrict__ w_fc1T,
    const float* __restrict__ fc2_w, u16* __restrict__ w_fc2T,
    float* __restrict__ wbar)
{
  __shared__ float tile[32][33];
  __shared__ float rs[4], rss[4];
  const int bid = blockIdx.x;
  const int t = threadIdx.x;
  const int tx = t & 31, ty = t >> 5;
  if (bid < 2048) {            // ---- LN1 (verbatim ln_kernel body) ----
    const int row = bid;
    const float* xr = x + (size_t)row * C_DIM;
    float4 xv = *(const float4*)(xr + t * 4);
    float s  = xv.x + xv.y + xv.z + xv.w;
    float ss = xv.x*xv.x + xv.y*xv.y + xv.z*xv.z + xv.w*xv.w;
    #pragma unroll
    for (int off = 1; off < 64; off <<= 1) {
      s  += __shfl_xor(s, off);
      ss += __shfl_xor(ss, off);
    }
    const int w = t >> 6;
    if ((t & 63) == 0) { rs[w] = s; rss[w] = ss; }
    __syncthreads();
    s  = rs[0] + rs[1] + rs[2] + rs[3];
    ss = rss[0] + rss[1] + rss[2] + rss[3];
    const float mean = s * (1.0f / C_DIM);
    const float var  = ss * (1.0f / C_DIM) - mean * mean;
    const float inv  = rsqrtf(var + 1e-5f);
    float4 gv = *(const float4*)(ln1_g + t * 4);
    float4 bv = *(const float4*)(ln1_b + t * 4);
    float4 o;
    o.x = (xv.x - mean) * inv * gv.x + bv.x;
    o.y = (xv.y - mean) * inv * gv.y + bv.y;
    o.z = (xv.z - mean) * inv * gv.z + bv.z;
    o.w = (xv.w - mean) * inv * gv.w + bv.w;
    ushort4 o4;
    o4.x = f2bf(o.x); o4.y = f2bf(o.y); o4.z = f2bf(o.z); o4.w = f2bf(o.w);
    *(ushort4*)(b_h + (size_t)row * C_DIM + t * 4) = o4;
    *(float4*)(b_hf + (size_t)row * C_DIM + t * 4) = o;
  } else if (bid < 5120) {     // ---- qkv^T: 96 x 32 tiles ----
    const int b2 = bid - 2048;
    conv_body(qkv_w, w_qkvT, 1024, 3072, (b2 % 96) * 32, (b2 / 96) * 32, tile, tx, ty);
  } else if (bid < 6144) {     // ---- proj^T: 32 x 32 tiles ----
    const int b2 = bid - 5120;
    conv_body(proj_w, w_projT, 1024, 1024, (b2 % 32) * 32, (b2 / 32) * 32, tile, tx, ty);
  } else if (bid < 10240) {    // ---- fc1^T: 128 x 32 tiles ----
    const int b2 = bid - 6144;
    conv_body(fc1_w, w_fc1T, 1024, 4096, (b2 % 128) * 32, (b2 / 128) * 32, tile, tx, ty);
  } else if (bid < 14336) {    // ---- fc2^T: 32 x 128 tiles ----
    const int b2 = bid - 10240;
    conv_body(fc2_w, w_fc2T, 4096, 1024, (b2 % 32) * 32, (b2 / 32) * 32, tile, tx, ty);
  } else {                     // ---- wbar: 256 blocks ----
    const int idx = (bid - 14336) * 256 + t;   // c*64 + d
    const int c = idx >> 6, d = idx & 63;
    float s = 0.f;
    #pragma unroll
    for (int h = 0; h < 16; h++)
      s += qkv_w[(size_t)c * 3072 + 1024 + h * 64 + d];
    wbar[idx] = s * (1.0f / 16.0f);
  }
}

// -------- fused divide + LN2: v = xm/size -> outx/outs, LN(v) -> h2 -------
__global__ __launch_bounds__(256) void divide_ln2_kernel(
    const float* __restrict__ xm, const float* __restrict__ sizem,
    const float* __restrict__ g, const float* __restrict__ b,
    float* __restrict__ outx, float* __restrict__ outs,
    u16* __restrict__ h2)
{
  const int row = blockIdx.x;
  const int t = threadIdx.x;
  const float sz = sizem[row];
  float4 xv = *(const float4*)(xm + (size_t)row * C_DIM + t * 4);
  xv.x = xv.x / sz; xv.y = xv.y / sz; xv.z = xv.z / sz; xv.w = xv.w / sz;
  *(float4*)(outx + (size_t)row * C_DIM + t * 4) = xv;
  if (t == 0) outs[row] = sz;
  float s  = xv.x + xv.y + xv.z + xv.w;
  float ss = xv.x*xv.x + xv.y*xv.y + xv.z*xv.z + xv.w*xv.w;
  #pragma unroll
  for (int off = 1; off < 64; off <<= 1) {
    s  += __shfl_xor(s, off);
    ss += __shfl_xor(ss, off);
  }
  __shared__ float rs[4], rss[4];
  const int w = t >> 6;
  if ((t & 63) == 0) { rs[w] = s; rss[w] = ss; }
  __syncthreads();
  s  = rs[0] + rs[1] + rs[2] + rs[3];
  ss = rss[0] + rss[1] + rss[2] + rss[3];
  const float mean = s * (1.0f / C_DIM);
  const float var  = ss * (1.0f / C_DIM) - mean * mean;
  const float inv  = rsqrtf(var + 1e-5f);
  float4 gv = *(const float4*)(g + t * 4);
  float4 bv = *(const float4*)(b + t * 4);
  float4 o;
  o.x = (xv.x - mean) * inv * gv.x + bv.x;
  o.y = (xv.y - mean) * inv * gv.y + bv.y;
  o.z = (xv.z - mean) * inv * gv.z + bv.z;
  o.w = (xv.w - mean) * inv * gv.w + bv.w;
  ushort4 o4;
  o4.x = f2bf(o.x); o4.y = f2bf(o.y); o4.z = f2bf(o.z); o4.w = f2bf(o.w);
  *(ushort4*)(h2 + (size_t)row * C_DIM + t * 4) = o4;
}

// ---------------- bf16 MFMA GEMM: C[M,N] = A[M,K] @ BT[N,K]^T -------------
// R6 geometry (proven): BN=64, LDS double-buffer, one barrier/iter.
// SPLIT>1 writes PARTITIONED slices (plain stores); epilogue sums.
template<int BM, int BN, int SPLIT, bool BIAS, bool GELU, bool RES, bool OUT_BF16>
__global__ __launch_bounds__(256) void gemm_mfma(
    const u16* __restrict__ A,   // [>=gridDim.y*BM][K] bf16 (readable padding)
    const u16* __restrict__ BT,  // [N][K] bf16
    const float* __restrict__ bias, const float* __restrict__ res,
    void* __restrict__ Cout, int M, int N, int K)
{
  constexpr int TM = BM / 32;                 // 16x16 tiles per wave (rows)
  constexpr int TN = BN / 32;                 // 16x16 tiles per wave (cols)
  __shared__ u16 As[2][BM * 64] __attribute__((aligned(16)));
  __shared__ u16 Bs[2][BN * 64] __attribute__((aligned(16)));
  const int tid  = threadIdx.x;
  const int lane = tid & 63;
  const int w    = tid >> 6;
  const int bm = blockIdx.y * BM;
  const int bn = blockIdx.x * BN;
  const int wm = (w >> 1) * (BM / 2);
  const int wn = (w & 1) * (BN / 2);

  f32x4 acc[TM][TN] = {};

  const int rl = lane >> 3;                 // row-in-8-group
  const int cg = (lane & 7) ^ rl;           // swizzled source chunk

  const int kb = (K / SPLIT) * blockIdx.z;
  const int ke = kb + K / SPLIT;

#define GEMM_STAGE(buf, k0_)                                                   \
  {                                                                            \
    _Pragma("unroll")                                                          \
    for (int i = 0; i < BM / 32; i++) {                                        \
      const int r = w * (BM / 4) + i * 8 + rl;                                 \
      __builtin_amdgcn_global_load_lds(                                        \
          (const __attribute__((address_space(1))) void*)(A + (size_t)(bm + r) * K + (k0_) + cg * 8), \
          (__attribute__((address_space(3))) void*)(&As[buf][(w * (BM / 4) + i * 8) * 64]), \
          16, 0, 0);                                                           \
    }                                                                          \
    _Pragma("unroll")                                                          \
    for (int i = 0; i < BN / 32; i++) {                                        \
      const int r = w * (BN / 4) + i * 8 + rl;                                 \
      __builtin_amdgcn_global_load_lds(                                        \
          (const __attribute__((address_space(1))) void*)(BT + (size_t)(bn + r) * K + (k0_) + cg * 8), \
          (__attribute__((address_space(3))) void*)(&Bs[buf][(w * (BN / 4) + i * 8) * 64]), \
          16, 0, 0);                                                           \
    }                                                                          \
  }

  // prologue: stage first K-tile into buffer 0
  GEMM_STAGE(0, kb);
  __syncthreads();

  int cur = 0;
  for (int k0 = kb; k0 < ke; k0 += 64) {
    // issue next tile's loads into the other buffer (overlap compute)
    if (k0 + 64 < ke) GEMM_STAGE(cur ^ 1, k0 + 64);

    #pragma unroll
    for (int kk = 0; kk < 2; kk++) {
      bf16x8 af[TM], bfr[TN];
      const int slot = (kk * 4 + (lane >> 4)) ^ (lane & 7);
      #pragma unroll
      for (int i = 0; i < TM; i++)
        af[i] = *(const bf16x8*)&As[cur][(wm + i * 16 + (lane & 15)) * 64 + slot * 8];
      #pragma unroll
      for (int j = 0; j < TN; j++)
        bfr[j] = *(const bf16x8*)&Bs[cur][(wn + j * 16 + (lane & 15)) * 64 + slot * 8];
      __builtin_amdgcn_s_setprio(1);
      #pragma unroll
      for (int i = 0; i < TM; i++)
        #pragma unroll
        for (int j = 0; j < TN; j++)
          acc[i][j] = __builtin_amdgcn_mfma_f32_16x16x32_bf16(af[i], bfr[j], acc[i][j], 0, 0, 0);
      __builtin_amdgcn_s_setprio(0);
    }
    // one barrier/iter: (a) implicit vmcnt(0) makes buf[cur^1]'s staged
    // loads visible for next compute; (b) all waves done reading buf[cur]
    // so next iteration may overwrite it.
    __syncthreads();
    cur ^= 1;
  }
#undef GEMM_STAGE

  if constexpr (SPLIT > 1) {
    // partitioned plain stores: slice z at Cf + z*M*N (sole writer)
    float* Cf = (float*)Cout + (size_t)blockIdx.z * ((size_t)M * N);
    #pragma unroll
    for (int i = 0; i < TM; i++)
      #pragma unroll
      for (int r = 0; r < 4; r++) {
        const int m = bm + wm + i * 16 + (lane >> 4) * 4 + r;
        if (m < M) {
          #pragma unroll
          for (int j = 0; j < TN; j++) {
            const int n = bn + wn + j * 16 + (lane & 15);
            Cf[(size_t)m * N + n] = acc[i][j][r];
          }
        }
      }
  } else {
    #pragma unroll
    for (int i = 0; i < TM; i++) {
      #pragma unroll
      for (int r = 0; r < 4; r++) {
        const int m = bm + wm + i * 16 + (lane >> 4) * 4 + r;
        if (m < M) {
          #pragma unroll
          for (int j = 0; j < TN; j++) {
            const int n = bn + wn + j * 16 + (lane & 15);
            float v = acc[i][j][r];
            if (BIAS) v += bias[n];
            if (GELU) v = 0.5f * v * (1.0f + erff(v * 0.70710678118654752f));
            if (RES)  v += res[(size_t)m * N + n];
            if (OUT_BF16) ((u16*)Cout)[(size_t)m * N + n] = f2bf(v);
            else          ((float*)Cout)[(size_t)m * N + n] = v;
          }
        }
      }
    }
  }
}

// ------ split-K epilogue: out += sum(4 slices) + bias (in-place res) ------
__global__ __launch_bounds__(256) void splitk_epilogue_kernel(
    const float* __restrict__ acc, const float* __restrict__ bias,
    float* __restrict__ out, int M)
{
  const int idx = blockIdx.x * 256 + threadIdx.x;   // float4 index
  if (idx >= M * 256) return;
  const size_t S = (size_t)M * 256;                 // slice stride in float4
  const float4* a4 = (const float4*)acc;
  float4 a0 = a4[idx], a1 = a4[idx + S], a2 = a4[idx + 2 * S], a3 = a4[idx + 3 * S];
  float4 bv = *(const float4*)(bias + (idx & 255) * 4);
  float4 o = *(const float4*)(out + (size_t)idx * 4);
  o.x += (a0.x + a1.x) + (a2.x + a3.x) + bv.x;
  o.y += (a0.y + a1.y) + (a2.y + a3.y) + bv.y;
  o.z += (a0.z + a1.z) + (a2.z + a3.z) + bv.z;
  o.w += (a0.w + a1.w) + (a2.w + a3.w) + bv.w;
  *(float4*)(out + (size_t)idx * 4) = o;
}

// -------- fused vt + metric (independent work, packed in one launch) ------
__global__ __launch_bounds__(256) void vt_metric_kernel(
    const u16* __restrict__ qkv, u16* __restrict__ vt,
    const float* __restrict__ hf, const float* __restrict__ wbar,
    float* __restrict__ metric)
{
  __shared__ __attribute__((aligned(16))) char smem[16384];
  const int bid = blockIdx.x;
  const int tid = threadIdx.x;
  if (bid < 512) {
    u16 (*tile)[72] = (u16(*)[72])smem;
    const int h  = bid >> 5;
    const int t0 = (bid & 31) * 64;
    const int row = tid >> 3;   // 0..31
    const int ch  = tid & 7;
    #pragma unroll
    for (int i = 0; i < 2; i++) {
      const int tok = row + i * 32;
      *(bf16x8*)&tile[tok][ch * 8] =
          *(const bf16x8*)(qkv + (size_t)(t0 + tok) * 3072 + 2048 + h * 64 + ch * 8);
    }
    __syncthreads();
    #pragma unroll
    for (int i = 0; i < 2; i++) {
      const int d = row + i * 32;
      u16 tmp[8];
      #pragma unroll
      for (int j = 0; j < 8; j++) tmp[j] = tile[ch * 8 + j][d];
      *(bf16x8*)(vt + (size_t)(h * 64 + d) * 2048 + t0 + ch * 8) = *(bf16x8*)tmp;
    }
  } else {
    float (*hs)[1024] = (float(*)[1024])smem;
    const int n0 = (bid - 512) * 4;
    const int t = tid;
    #pragma unroll
    for (int i = 0; i < 4; i++)
      *(float4*)&hs[i][t * 4] = *(const float4*)(hf + (size_t)(n0 + i) * 1024 + t * 4);
    __syncthreads();
    const int d = t & 63;
    const float* hsw = hs[t >> 6];
    float a0=0,a1=0,a2=0,a3=0,a4=0,a5=0,a6=0,a7=0;
    for (int c = 0; c < 1024; c += 8) {
      a0 += hsw[c+0] * wbar[(c+0)*64 + d];
      a1 += hsw[c+1] * wbar[(c+1)*64 + d];
      a2 += hsw[c+2] * wbar[(c+2)*64 + d];
      a3 += hsw[c+3] * wbar[(c+3)*64 + d];
      a4 += hsw[c+4] * wbar[(c+4)*64 + d];
      a5 += hsw[c+5] * wbar[(c+5)*64 + d];
      a6 += hsw[c+6] * wbar[(c+6)*64 + d];
      a7 += hsw[c+7] * wbar[(c+7)*64 + d];
    }
    float s = ((a0+a1)+(a2+a3)) + ((a4+a5)+(a6+a7));
    float sq = s * s;
    #pragma unroll
    for (int off = 1; off < 64; off <<= 1) sq += __shfl_xor(sq, off);
    metric[(size_t)(n0 + (t >> 6)) * 64 + d] = s / sqrtf(sq);
  }
}

// ---------------- MFMA flash attention, no-max softmax, S^T trick ---------
// R4 structure (proven): K double-buffered, V single-buffered, 2 barriers/
// iter, 4 blocks/CU. R9: partitioned outputs (plain stores, no atomics).
template<int SPLIT>
__global__ __launch_bounds__(256) void attn_mfma(
    const u16* __restrict__ qkv, const u16* __restrict__ vt,
    const float* __restrict__ sz, float* __restrict__ opart,
    float* __restrict__ lpart)
{
  const int h   = blockIdx.y;
  const int q0  = blockIdx.x * 64;
  const int tid = threadIdx.x;
  const int lane = tid & 63;
  const int w    = tid >> 6;
  const int col  = lane & 15;
  const int quad = lane >> 4;

  __shared__ u16 Ks [2][64 * 64] __attribute__((aligned(16))); // [key][d] swizzled, dbuf
  __shared__ u16 Vts[64 * 64] __attribute__((aligned(16)));    // [d][key] swizzled, single
  __shared__ u16 Ps[4][16 * 72] __attribute__((aligned(16)));  // per-wave P[q][key]
  __shared__ float lball[N_TOK / SPLIT];                       // log2(size) per key

  bf16x8 qf[2];
  {
    const u16* qp = qkv + (size_t)(q0 + w * 16 + col) * 3072 + h * 64 + quad * 8;
    qf[0] = *(const bf16x8*)(qp);
    qf[1] = *(const bf16x8*)(qp + 32);
  }

  float l_lane = 0.f;          // all partials belong to q = q0 + w*16 + col
  f32x4 oacc[4] = {};

  const int rl = lane >> 3;
  const int cg = (lane & 7) ^ rl;
  const int kb = blockIdx.z * (N_TOK / SPLIT);
  const int ke = kb + N_TOK / SPLIT;

  // 0.125 * log2(e): fold the 1/8 scale and the nat->log2 conversion together
  constexpr float kScaleLog2e = 0.18033688011112042f;

  // ---- prologue: stage K[0], V[0]; precompute ALL log2(size) once ----
  #pragma unroll
  for (int i = 0; i < 2; i++) {
    const int r = w * 16 + i * 8 + rl;
    __builtin_amdgcn_global_load_lds(
        (const __attribute__((address_space(1))) void*)(qkv + (size_t)(kb + r) * 3072 + 1024 + h * 64 + cg * 8),
        (__attribute__((address_space(3))) void*)(&Ks[0][(w * 16 + i * 8) * 64]),
        16, 0, 0);
    __builtin_amdgcn_global_load_lds(
        (const __attribute__((address_space(1))) void*)(vt + (size_t)(h * 64 + r) * 2048 + kb + cg * 8),
        (__attribute__((address_space(3))) void*)(&Vts[(w * 16 + i * 8) * 64]),
        16, 0, 0);
  }
  #pragma unroll
  for (int i = tid; i < N_TOK / SPLIT; i += 256)
    lball[i] = __builtin_amdgcn_logf(sz[kb + i]);   // v_log_f32 = log2
  __syncthreads();   // drains prologue staging (vmcnt + lgkmcnt)

  int cur = 0;
  for (int kt = kb; kt < ke; kt += 64) {
    const int nxt = cur ^ 1;
    const bool has_next = (kt + 64 < ke);   // block-uniform

    // ---- issue NEXT K tile into the other K buffer (full-iter overlap) ---
    if (has_next) {
      #pragma unroll
      for (int i = 0; i < 2; i++) {
        const int r = w * 16 + i * 8 + rl;
        __builtin_amdgcn_global_load_lds(
            (const __attribute__((address_space(1))) void*)(qkv + (size_t)(kt + 64 + r) * 3072 + 1024 + h * 64 + cg * 8),
            (__attribute__((address_space(3))) void*)(&Ks[nxt][(w * 16 + i * 8) * 64]),
            16, 0, 0);
      }
    }

    // ---- S^T = K Q^T : lane holds S^T[key = jt*16+quad*4+r][q = col] ----
    const u16* Kc = Ks[cur];
    f32x4 sacc[4] = {};
    #pragma unroll
    for (int kk = 0; kk < 2; kk++) {
      const int slot = (kk * 4 + quad) ^ (lane & 7);
      bf16x8 kf[4];
      #pragma unroll
      for (int jt = 0; jt < 4; jt++)
        kf[jt] = *(const bf16x8*)&Kc[(jt * 16 + col) * 64 + slot * 8];
      __builtin_amdgcn_s_setprio(1);
      #pragma unroll
      for (int jt = 0; jt < 4; jt++)
        sacc[jt] = __builtin_amdgcn_mfma_f32_16x16x32_bf16(kf[jt], qf[kk], sacc[jt], 0, 0, 0);
      __builtin_amdgcn_s_setprio(0);
    }

    // exp2-domain softmax weights + packed P-writes (4x b64), l per-lane
    u16* pw = Ps[w];
    const float* lbp = &lball[kt - kb];
    #pragma unroll
    for (int jt = 0; jt < 4; jt++) {
      float4 lb4 = *(const float4*)&lbp[jt * 16 + quad * 4];
      const float p0 = __builtin_amdgcn_exp2f(fmaf(sacc[jt][0], kScaleLog2e, lb4.x));
      const float p1 = __builtin_amdgcn_exp2f(fmaf(sacc[jt][1], kScaleLog2e, lb4.y));
      const float p2 = __builtin_amdgcn_exp2f(fmaf(sacc[jt][2], kScaleLog2e, lb4.z));
      const float p3 = __builtin_amdgcn_exp2f(fmaf(sacc[jt][3], kScaleLog2e, lb4.w));
      l_lane += (p0 + p1) + (p2 + p3);
      uint2 pkk;
      pkk.x = cvt_pk_bf16(p0, p1);
      pkk.y = cvt_pk_bf16(p2, p3);
      *(uint2*)&pw[col * 72 + jt * 16 + quad * 4] = pkk;
    }
    // same-wave LDS RAW -> lgkmcnt (verified pattern); rows 144B apart
    bf16x8 pf[2];
    #pragma unroll
    for (int kk = 0; kk < 2; kk++)
      pf[kk] = *(const bf16x8*)&pw[col * 72 + kk * 32 + quad * 8];

    // barrier A: implicit vmcnt(0) drains V[this tile] (issued last iter,
    // had the whole QK+softmax above to load) + K[nxt] (usually done too)
    __syncthreads();

    // O += P V (A = P rows=q, B = V^T)
    #pragma unroll
    for (int kk = 0; kk < 2; kk++) {
      const int slot = (kk * 4 + quad) ^ (lane & 7);
      bf16x8 vf[4];
      #pragma unroll
      for (int nt = 0; nt < 4; nt++)
        vf[nt] = *(const bf16x8*)&Vts[(nt * 16 + col) * 64 + slot * 8];
      __builtin_amdgcn_s_setprio(1);
      #pragma unroll
      for (int nt = 0; nt < 4; nt++)
        oacc[nt] = __builtin_amdgcn_mfma_f32_16x16x32_bf16(pf[kk], vf[nt], oacc[nt], 0, 0, 0);
      __builtin_amdgcn_s_setprio(0);
    }

    // barrier B: all waves done reading Vts -> safe to overwrite
    __syncthreads();

    // ---- issue NEXT V tile into the single V buffer (overlaps next QK) --
    if (has_next) {
      #pragma unroll
      for (int i = 0; i < 2; i++) {
        const int r = w * 16 + i * 8 + rl;
        __builtin_amdgcn_global_load_lds(
            (const __attribute__((address_space(1))) void*)(vt + (size_t)(h * 64 + r) * 2048 + kt + 64 + cg * 8),
            (__attribute__((address_space(3))) void*)(&Vts[(w * 16 + i * 8) * 64]),
            16, 0, 0);
      }
    }
    cur = nxt;
  }

  // l: sum the 4 quads of each col group (once)
  l_lane += __shfl_xor(l_lane, 16);
  l_lane += __shfl_xor(l_lane, 32);

  // partitioned plain stores (sole writer per (q,h,z) — no atomics)
  float* osl = opart + (size_t)blockIdx.z * ((size_t)N_TOK * 1024);
  #pragma unroll
  for (int r = 0; r < 4; r++) {
    const int q = q0 + w * 16 + quad * 4 + r;
    float* op = osl + (size_t)q * 1024 + h * 64 + col;
    #pragma unroll
    for (int nt = 0; nt < 4; nt++)
      op[nt * 16] = oacc[nt][r];
  }
  if (quad == 0)
    lpart[(size_t)blockIdx.z * (N_TOK * 16) + (q0 + w * 16 + col) * 16 + h] = l_lane;
}

// ------ fused attn-normalize + merge-score (independent work, packed) -----
__global__ __launch_bounds__(256) void norm_score_kernel(
    const float* __restrict__ opart, const float* __restrict__ lpart,
    u16* __restrict__ xa,
    const float* __restrict__ metric, const float* __restrict__ thr,
    int* __restrict__ mask, int* __restrict__ node)
{
  __shared__ float a[4][64];
  __shared__ float bw_[4][4];
  __shared__ int biw_[4][4];
  const int bid = blockIdx.x;
  const int t = threadIdx.x;
  if (bid < 2048) {
    const int q = bid;
    const int c = t * 4;
    float4 o0 = *(const float4*)(opart + (size_t)q * 1024 + c);
    float4 o1 = *(const float4*)(opart + (size_t)N_TOK * 1024 + (size_t)q * 1024 + c);
    const float l0 = lpart[q * 16 + (c >> 6)];
    const float l1 = lpart[N_TOK * 16 + q * 16 + (c >> 6)];
    const float inv = 1.0f / (l0 + l1);
    ushort4 o4;
    o4.x = f2bf((o0.x + o1.x) * inv); o4.y = f2bf((o0.y + o1.y) * inv);
    o4.z = f2bf((o0.z + o1.z) * inv); o4.w = f2bf((o0.w + o1.w) * inv);
    *(ushort4*)(xa + (size_t)q * 1024 + c) = o4;
    return;
  }
  const int s0 = (bid - 2048) * 4;
  a[t >> 6][t & 63] = metric[(size_t)(2 * (s0 + (t >> 6))) * 64 + (t & 63)];
  __syncthreads();
  float best[4] = {-INFINITY, -INFINITY, -INFINITY, -INFINITY};
  int besti[4] = {0, 0, 0, 0};
  for (int m = t; m < 1024; m += 256) {
    const float* bp = metric + (size_t)(2 * m + 1) * 64;
    float s[4] = {0.f, 0.f, 0.f, 0.f};
    #pragma unroll
    for (int d = 0; d < 64; d += 4) {
      float4 bv = *(const float4*)(bp + d);
      #pragma unroll
      for (int j = 0; j < 4; j++) {
        float4 av = *(const float4*)&a[j][d];
        s[j] += av.x*bv.x + av.y*bv.y + av.z*bv.z + av.w*bv.w;
      }
    }
    #pragma unroll
    for (int j = 0; j < 4; j++)
      if (s[j] > best[j]) { best[j] = s[j]; besti[j] = m; }   // ascending m
  }
  #pragma unroll
  for (int j = 0; j < 4; j++) {
    float b = best[j]; int bi = besti[j];
    #pragma unroll
    for (int off = 1; off < 64; off <<= 1) {
      float ov = __shfl_xor(b, off);
      int   oi = __shfl_xor(bi, off);
      if (ov > b || (ov == b && oi < bi)) { b = ov; bi = oi; }
    }
    best[j] = b; besti[j] = bi;
  }
  const int wv = t >> 6;
  if ((t & 63) == 0) {
    #pragma unroll
    for (int j = 0; j < 4; j++) { bw_[wv][j] = best[j]; biw_[wv][j] = besti[j]; }
  }
  __syncthreads();
  if (t < 4) {
    const int j = t;
    float b = bw_[0][j]; int bi = biw_[0][j];
    for (int ww = 1; ww < 4; ww++)
      if (bw_[ww][j] > b || (bw_[ww][j] == b && biw_[ww][j] < bi)) { b = bw_[ww][j]; bi = biw_[ww][j]; }
    const int n = s0 + j;
    if (n == 0) { mask[0] = 0; node[0] = 0; }
    else { mask[n] = (b > thr[0]) ? 1 : 0; node[n] = bi; }
  }
}

// ------ build merged rows; scan FOLDED IN (pos computed per-block) --------
// pos[i] = exclusive prefix count of !mask — each unmerged-src block scans
// mask[0..i) itself (<=4 iterations/thread + 2-level reduce). Removes the
// 1-block scan dispatch.
__global__ __launch_bounds__(256) void build_kernel(
    const float* __restrict__ xres, const float* __restrict__ sz,
    const int* __restrict__ mask, float* __restrict__ xm,
    float* __restrict__ sizem, int U)
{
  const int b = blockIdx.x;
  const int t = threadIdx.x;
  __shared__ int red[4];
  int srow, orow;
  if (b < 1024) { srow = 2 * b + 1; orow = U + b; }
  else {
    const int i = b - 1024;
    if (mask[i]) return;
    int cnt = 0;
    for (int j = t; j < i; j += 256) cnt += mask[j] ? 0 : 1;
    #pragma unroll
    for (int off = 1; off < 64; off <<= 1) cnt += __shfl_xor(cnt, off);
    if ((t & 63) == 0) red[t >> 6] = cnt;
    __syncthreads();
    orow = red[0] + red[1] + red[2] + red[3];
    srow = 2 * i;
  }
  const float ssz = sz[srow];
  const float* xp = xres + (size_t)srow * 1024;
  float* op = xm + (size_t)orow * 1024;
  const int c = t * 4;
  float4 v = *(const float4*)(xp + c);
  v.x *= ssz; v.y *= ssz; v.z *= ssz; v.w *= ssz;
  *(float4*)(op + c) = v;
  if (t == 0) sizem[orow] = ssz;
}

// ---------------- scatter-add merged src tokens into dst rows -------------
__global__ __launch_bounds__(256) void merge_add_kernel(
    const float* __restrict__ xres, const float* __restrict__ sz,
    const int* __restrict__ mask, const int* __restrict__ node,
    float* __restrict__ xm, float* __restrict__ sizem, int U)
{
  const int i = blockIdx.x;
  if (!mask[i]) return;
  const int t = threadIdx.x;
  const int srow = 2 * i;
  const int orow = U + node[i];
  const float ssz = sz[srow];
  const float* xp = xres + (size_t)srow * 1024;
  float* op = xm + (size_t)orow * 1024;
  for (int c = t; c < 1024; c += 256)
    atomicAdd(op + c, xp[c] * ssz);
  if (t == 0) atomicAdd(sizem + orow, ssz);
}

extern "C" void kernel_launch(void* const* d_in, const int* in_sizes, int n_in,
                              void* d_out, int out_size, void* d_ws, size_t ws_size,
                              hipStream_t stream) {
  const float* x      = (const float*)d_in[0];
  const float* sz     = (const float*)d_in[1];
  const float* qkv_w  = (const float*)d_in[2];
  const float* proj_w = (const float*)d_in[3];
  const float* proj_b = (const float*)d_in[4];
  const float* ln1_g  = (const float*)d_in[5];
  const float* ln1_b  = (const float*)d_in[6];
  const float* ln2_g  = (const float*)d_in[7];
  const float* ln2_b  = (const float*)d_in[8];
  const float* fc1_w  = (const float*)d_in[9];
  const float* fc1_b  = (const float*)d_in[10];
  const float* fc2_w  = (const float*)d_in[11];
  const float* fc2_b  = (const float*)d_in[12];
  const float* thr    = (const float*)d_in[13];

  const int M = out_size / 1025;
  const int U = M - 1024;
  const size_t MB = 1u << 20;
  const size_t KB = 1u << 10;

  // workspace layout (ws = 256 MiB; late buffers moved to fresh regions so
  // ALL weight converts can run in the opening launch):
  //  [0,6)   w_qkvT -> b_vt[0,4) (after QKV GEMM)
  //  [6,7)   wbar/met/mask/node
  //  [7,7.25) lpart (2 slices)
  //  [8,10)  w_projT
  //  [10,22) b_qkv -> b_xa[10,14) -> b_xm[10,18)
  //  [22,30) b_hf -> opart slice0 -> b_xres
  //  [30,34) b_h  -> opart slice1 overlays [30,38)
  //  [71,79) w_fc1T   [79,87) w_fc2T   [87,104) b_g
  //  [104,108) b_h2   [108,142) b_facc (4 slices)
  char* ws = (char*)d_ws;
  u16*   w_qkvT  = (u16*)(ws + 0);
  float* b_wbar  = (float*)(ws + 6 * MB);
  float* b_met   = (float*)(ws + 6 * MB + 256 * KB);
  int*   b_mask  = (int*)(ws + 6 * MB + 768 * KB);
  int*   b_node  = b_mask + 1024;
  float* b_szm   = (float*)(b_node + 1024);
  float* b_lpart = (float*)(ws + 7 * MB);            // 2 x 128KB slices
  u16*   w_projT = (u16*)(ws + 8 * MB);
  u16*   b_qkv   = (u16*)(ws + 10 * MB);
  u16*   b_xa    = (u16*)(ws + 10 * MB);   // over dead b_qkv (after attn)
  float* b_xm    = (float*)(ws + 10 * MB);   // over dead b_xa (after proj)
  float* b_hf    = (float*)(ws + 22 * MB);
  float* b_opart = (float*)(ws + 22 * MB);   // 2 x 8MB slices over dead b_hf+b_h
  float* b_xres  = (float*)(ws + 22 * MB);   // over dead opart slice0
  u16*   b_h     = (u16*)(ws + 30 * MB);
  u16*   b_vt    = (u16*)(ws + 0);
  u16*   w_fc1T  = (u16*)(ws + 71 * MB);
  u16*   w_fc2T  = (u16*)(ws + 79 * MB);
  u16*   b_g     = (u16*)(ws + 87 * MB);
  u16*   b_h2    = (u16*)(ws + 104 * MB);
  float* b_facc  = (float*)(ws + 108 * MB);  // 4 partitioned slices

  float* outx = (float*)d_out;
  float* outs = outx + (size_t)M * 1024;

  // 1. fused opening launch: LN1 + ALL weight converts + wbar
  fused_pre_kernel<<<14592, 256, 0, stream>>>(
      x, ln1_g, ln1_b, b_h, b_hf,
      qkv_w, w_qkvT, proj_w, w_projT, fc1_w, w_fc1T, fc2_w, w_fc2T, b_wbar);
  // 2. QKV GEMM (bf16 MFMA, 128x64 dbuf tile) — 768 blocks
  gemm_mfma<128, 64, 1, false, false, false, true><<<dim3(48, 16), 256, 0, stream>>>(
      b_h, w_qkvT, nullptr, nullptr, b_qkv, 2048, 3072, 1024);
  // 3. fused V-transpose + exact fp32 metric (independent, packed)
  vt_metric_kernel<<<1024, 256, 0, stream>>>(b_qkv, b_vt, b_hf, b_wbar, b_met);
  // 4. MFMA attention: K-dbuf + single-V pipeline, partitioned outputs
  attn_mfma<2><<<dim3(32, 16, 2), 256, 0, stream>>>(b_qkv, b_vt, sz, b_opart, b_lpart);
  // 5. fused attn-normalize + merge-score (independent, packed)
  norm_score_kernel<<<2304, 256, 0, stream>>>(b_opart, b_lpart, b_xa, b_met, thr, b_mask, b_node);
  // 6. proj GEMM + bias + residual(x) -> xres fp32 — 512 blocks
  gemm_mfma<64, 64, 1, true, false, true, false><<<dim3(16, 32), 256, 0, stream>>>(
      b_xa, w_projT, proj_b, x, b_xres, 2048, 1024, 1024);
  // 7. build merged rows (scan folded in)
  build_kernel<<<2048, 256, 0, stream>>>(b_xres, sz, b_mask, b_xm, b_szm, U);
  // 8. scatter-add merged src tokens
  merge_add_kernel<<<1024, 256, 0, stream>>>(b_xres, sz, b_mask, b_node, b_xm, b_szm, U);
  // 9. fused divide + LN2 (one block per row): outx, outs, h2
  divide_ln2_kernel<<<M, 256, 0, stream>>>(b_xm, b_szm, ln2_g, ln2_b, outx, outs, b_h2);
  // 10. fc1 + bias + exact GELU -> bf16 — 768 blocks
  gemm_mfma<128, 64, 1, true, true, false, true><<<dim3(64, (M + 127) / 128), 256, 0, stream>>>(
      b_h2, w_fc1T, fc1_b, nullptr, b_g, M, 4096, 1024);
  // 11. fc2 split-K=4, partitioned slices (no memset, no atomics)
  gemm_mfma<128, 64, 4, false, false, false, false><<<dim3(16, (M + 127) / 128, 4), 256, 0, stream>>>(
      b_g, w_fc2T, nullptr, nullptr, b_facc, M, 1024, 4096);
  // 12. fc2 epilogue: outx += sum(4 slices) + bias (residual in-place)
  splitk_epilogue_kernel<<<(M * 256 + 255) / 256, 256, 0, stream>>>(
      b_facc, fc2_b, outx, M);
  (void)in_sizes; (void)n_in; (void)ws_size;
}

// Round 14
// 283.670 us; speedup vs baseline: 1.2201x; 1.0321x over previous
//
#include <hip/hip_runtime.h>
#include <math.h>

typedef unsigned short u16;
typedef __attribute__((ext_vector_type(8))) short bf16x8;
typedef __attribute__((ext_vector_type(4))) float f32x4;

#define C_DIM 1024
#define N_TOK 2048

static __device__ __forceinline__ u16 f2bf(float f) {
  union { float f; unsigned u; } v; v.f = f;
  unsigned r = v.u + 0x7fff + ((v.u >> 16) & 1);
  return (u16)(r >> 16);
}

// packed f32x2 -> bf16x2 (RNE, same rounding as f2bf) in ONE VALU op
static __device__ __forceinline__ unsigned cvt_pk_bf16(float lo, float hi) {
  unsigned r;
  asm("v_cvt_pk_bf16_f32 %0, %1, %2" : "=v"(r) : "v"(lo), "v"(hi));
  return r;
}

// ---------------- transpose body: W[K][N] tile (by,bx) -> WT[N][K] --------
static __device__ __forceinline__ void conv_body(
    const float* __restrict__ W, u16* __restrict__ WT, int K, int N,
    int bx, int by, float (*tile)[33], int tx, int ty)
{
  #pragma unroll
  for (int i = 0; i < 32; i += 8)
    tile[ty + i][tx] = W[(size_t)(by + ty + i) * N + bx + tx];
  __syncthreads();
  #pragma unroll
  for (int i = 0; i < 32; i += 8)
    WT[(size_t)(bx + ty + i) * K + by + tx] = f2bf(tile[tx][ty + i]);
}

// ---- fused opening launch: LN1 + ALL weight converts + wbar (input-only) -
__global__ __launch_bounds__(256) void fused_pre_kernel(
    const float* __restrict__ x, const float* __restrict__ ln1_g,
    const float* __restrict__ ln1_b, u16* __restrict__ b_h,
    float* __restrict__ b_hf,
    const float* __restrict__ qkv_w, u16* __restrict__ w_qkvT,
    const float* __restrict__ proj_w, u16* __restrict__ w_projT,
    const float* __restrict__ fc1_w, u16* __restrict__ w_fc1T,
    const float* __restrict__ fc2_w, u16* __restrict__ w_fc2T,
    float* __restrict__ wbar)
{
  __shared__ float tile[32][33];
  __shared__ float rs[4], rss[4];
  const int bid = blockIdx.x;
  const int t = threadIdx.x;
  const int tx = t & 31, ty = t >> 5;
  if (bid < 2048) {            // ---- LN1 (verbatim ln body) ----
    const int row = bid;
    const float* xr = x + (size_t)row * C_DIM;
    float4 xv = *(const float4*)(xr + t * 4);
    float s  = xv.x + xv.y + xv.z + xv.w;
    float ss = xv.x*xv.x + xv.y*xv.y + xv.z*xv.z + xv.w*xv.w;
    #pragma unroll
    for (int off = 1; off < 64; off <<= 1) {
      s  += __shfl_xor(s, off);
      ss += __shfl_xor(ss, off);
    }
    const int w = t >> 6;
    if ((t & 63) == 0) { rs[w] = s; rss[w] = ss; }
    __syncthreads();
    s  = rs[0] + rs[1] + rs[2] + rs[3];
    ss = rss[0] + rss[1] + rss[2] + rss[3];
    const float mean = s * (1.0f / C_DIM);
    const float var  = ss * (1.0f / C_DIM) - mean * mean;
    const float inv  = rsqrtf(var + 1e-5f);
    float4 gv = *(const float4*)(ln1_g + t * 4);
    float4 bv = *(const float4*)(ln1_b + t * 4);
    float4 o;
    o.x = (xv.x - mean) * inv * gv.x + bv.x;
    o.y = (xv.y - mean) * inv * gv.y + bv.y;
    o.z = (xv.z - mean) * inv * gv.z + bv.z;
    o.w = (xv.w - mean) * inv * gv.w + bv.w;
    ushort4 o4;
    o4.x = f2bf(o.x); o4.y = f2bf(o.y); o4.z = f2bf(o.z); o4.w = f2bf(o.w);
    *(ushort4*)(b_h + (size_t)row * C_DIM + t * 4) = o4;
    *(float4*)(b_hf + (size_t)row * C_DIM + t * 4) = o;
  } else if (bid < 5120) {     // ---- qkv^T: 96 x 32 tiles ----
    const int b2 = bid - 2048;
    conv_body(qkv_w, w_qkvT, 1024, 3072, (b2 % 96) * 32, (b2 / 96) * 32, tile, tx, ty);
  } else if (bid < 6144) {     // ---- proj^T: 32 x 32 tiles ----
    const int b2 = bid - 5120;
    conv_body(proj_w, w_projT, 1024, 1024, (b2 % 32) * 32, (b2 / 32) * 32, tile, tx, ty);
  } else if (bid < 10240) {    // ---- fc1^T: 128 x 32 tiles ----
    const int b2 = bid - 6144;
    conv_body(fc1_w, w_fc1T, 1024, 4096, (b2 % 128) * 32, (b2 / 128) * 32, tile, tx, ty);
  } else if (bid < 14336) {    // ---- fc2^T: 32 x 128 tiles ----
    const int b2 = bid - 10240;
    conv_body(fc2_w, w_fc2T, 4096, 1024, (b2 % 32) * 32, (b2 / 32) * 32, tile, tx, ty);
  } else {                     // ---- wbar: 256 blocks ----
    const int idx = (bid - 14336) * 256 + t;   // c*64 + d
    const int c = idx >> 6, d = idx & 63;
    float s = 0.f;
    #pragma unroll
    for (int h = 0; h < 16; h++)
      s += qkv_w[(size_t)c * 3072 + 1024 + h * 64 + d];
    wbar[idx] = s * (1.0f / 16.0f);
  }
}

// -------- fused divide + LN2: v = xm/size -> outx/outs, LN(v) -> h2 -------
__global__ __launch_bounds__(256) void divide_ln2_kernel(
    const float* __restrict__ xm, const float* __restrict__ sizem,
    const float* __restrict__ g, const float* __restrict__ b,
    float* __restrict__ outx, float* __restrict__ outs,
    u16* __restrict__ h2)
{
  const int row = blockIdx.x;
  const int t = threadIdx.x;
  const float sz = sizem[row];
  float4 xv = *(const float4*)(xm + (size_t)row * C_DIM + t * 4);
  xv.x = xv.x / sz; xv.y = xv.y / sz; xv.z = xv.z / sz; xv.w = xv.w / sz;
  *(float4*)(outx + (size_t)row * C_DIM + t * 4) = xv;
  if (t == 0) outs[row] = sz;
  float s  = xv.x + xv.y + xv.z + xv.w;
  float ss = xv.x*xv.x + xv.y*xv.y + xv.z*xv.z + xv.w*xv.w;
  #pragma unroll
  for (int off = 1; off < 64; off <<= 1) {
    s  += __shfl_xor(s, off);
    ss += __shfl_xor(ss, off);
  }
  __shared__ float rs[4], rss[4];
  const int w = t >> 6;
  if ((t & 63) == 0) { rs[w] = s; rss[w] = ss; }
  __syncthreads();
  s  = rs[0] + rs[1] + rs[2] + rs[3];
  ss = rss[0] + rss[1] + rss[2] + rss[3];
  const float mean = s * (1.0f / C_DIM);
  const float var  = ss * (1.0f / C_DIM) - mean * mean;
  const float inv  = rsqrtf(var + 1e-5f);
  float4 gv = *(const float4*)(g + t * 4);
  float4 bv = *(const float4*)(b + t * 4);
  float4 o;
  o.x = (xv.x - mean) * inv * gv.x + bv.x;
  o.y = (xv.y - mean) * inv * gv.y + bv.y;
  o.z = (xv.z - mean) * inv * gv.z + bv.z;
  o.w = (xv.w - mean) * inv * gv.w + bv.w;
  ushort4 o4;
  o4.x = f2bf(o.x); o4.y = f2bf(o.y); o4.z = f2bf(o.z); o4.w = f2bf(o.w);
  *(ushort4*)(h2 + (size_t)row * C_DIM + t * 4) = o4;
}

// ---------------- bf16 MFMA GEMM: C[M,N] = A[M,K] @ BT[N,K]^T -------------
// R6 geometry (proven): BN=64, LDS double-buffer, one barrier/iter.
// SPLIT>1: partitioned slices. VTOUT: blocks with bn>=2048 (V-third of the
// QKV GEMM) store the C-tile TRANSPOSED to vt[d][token] via an LDS
// transpose (dead As staging, stride-132 pad), values = same RNE bf16.
template<int BM, int BN, int SPLIT, bool BIAS, bool GELU, bool RES, bool OUT_BF16, bool VTOUT = false>
__global__ __launch_bounds__(256) void gemm_mfma(
    const u16* __restrict__ A,   // [>=gridDim.y*BM][K] bf16 (readable padding)
    const u16* __restrict__ BT,  // [N][K] bf16
    const float* __restrict__ bias, const float* __restrict__ res,
    void* __restrict__ Cout, int M, int N, int K)
{
  constexpr int TM = BM / 32;                 // 16x16 tiles per wave (rows)
  constexpr int TN = BN / 32;                 // 16x16 tiles per wave (cols)
  __shared__ u16 As[2][BM * 64] __attribute__((aligned(16)));
  __shared__ u16 Bs[2][BN * 64] __attribute__((aligned(16)));
  const int tid  = threadIdx.x;
  const int lane = tid & 63;
  const int w    = tid >> 6;
  const int bm = blockIdx.y * BM;
  const int bn = blockIdx.x * BN;
  const int wm = (w >> 1) * (BM / 2);
  const int wn = (w & 1) * (BN / 2);

  f32x4 acc[TM][TN] = {};

  const int rl = lane >> 3;                 // row-in-8-group
  const int cg = (lane & 7) ^ rl;           // swizzled source chunk

  const int kb = (K / SPLIT) * blockIdx.z;
  const int ke = kb + K / SPLIT;

#define GEMM_STAGE(buf, k0_)                                                   \
  {                                                                            \
    _Pragma("unroll")                                                          \
    for (int i = 0; i < BM / 32; i++) {                                        \
      const int r = w * (BM / 4) + i * 8 + rl;                                 \
      __builtin_amdgcn_global_load_lds(                                        \
          (const __attribute__((address_space(1))) void*)(A + (size_t)(bm + r) * K + (k0_) + cg * 8), \
          (__attribute__((address_space(3))) void*)(&As[buf][(w * (BM / 4) + i * 8) * 64]), \
          16, 0, 0);                                                           \
    }                                                                          \
    _Pragma("unroll")                                                          \
    for (int i = 0; i < BN / 32; i++) {                                        \
      const int r = w * (BN / 4) + i * 8 + rl;                                 \
      __builtin_amdgcn_global_load_lds(                                        \
          (const __attribute__((address_space(1))) void*)(BT + (size_t)(bn + r) * K + (k0_) + cg * 8), \
          (__attribute__((address_space(3))) void*)(&Bs[buf][(w * (BN / 4) + i * 8) * 64]), \
          16, 0, 0);                                                           \
    }                                                                          \
  }

  // prologue: stage first K-tile into buffer 0
  GEMM_STAGE(0, kb);
  __syncthreads();

  int cur = 0;
  for (int k0 = kb; k0 < ke; k0 += 64) {
    // issue next tile's loads into the other buffer (overlap compute)
    if (k0 + 64 < ke) GEMM_STAGE(cur ^ 1, k0 + 64);

    #pragma unroll
    for (int kk = 0; kk < 2; kk++) {
      bf16x8 af[TM], bfr[TN];
      const int slot = (kk * 4 + (lane >> 4)) ^ (lane & 7);
      #pragma unroll
      for (int i = 0; i < TM; i++)
        af[i] = *(const bf16x8*)&As[cur][(wm + i * 16 + (lane & 15)) * 64 + slot * 8];
      #pragma unroll
      for (int j = 0; j < TN; j++)
        bfr[j] = *(const bf16x8*)&Bs[cur][(wn + j * 16 + (lane & 15)) * 64 + slot * 8];
      __builtin_amdgcn_s_setprio(1);
      #pragma unroll
      for (int i = 0; i < TM; i++)
        #pragma unroll
        for (int j = 0; j < TN; j++)
          acc[i][j] = __builtin_amdgcn_mfma_f32_16x16x32_bf16(af[i], bfr[j], acc[i][j], 0, 0, 0);
      __builtin_amdgcn_s_setprio(0);
    }
    // one barrier/iter: (a) implicit vmcnt(0) makes buf[cur^1]'s staged
    // loads visible for next compute; (b) all waves done reading buf[cur]
    // so next iteration may overwrite it.
    __syncthreads();
    cur ^= 1;
  }
#undef GEMM_STAGE

  if constexpr (VTOUT) {
    if (bn >= 2048) {
      // transposed V store: tile[n_local][m_local], stride 132 u16
      // (264B rows -> 2-way banks, b64-aligned). As is dead (post-barrier).
      u16* tile = (u16*)&As[0][0];
      #pragma unroll
      for (int i = 0; i < TM; i++)
        #pragma unroll
        for (int j = 0; j < TN; j++) {
          const int nl = wn + j * 16 + (lane & 15);
          const int mb = wm + i * 16 + (lane >> 4) * 4;
          uint2 pk;
          pk.x = cvt_pk_bf16(acc[i][j][0], acc[i][j][1]);
          pk.y = cvt_pk_bf16(acc[i][j][2], acc[i][j][3]);
          *(uint2*)&tile[nl * 132 + mb] = pk;
        }
      __syncthreads();
      u16* vt = (u16*)res;               // vt base smuggled via res
      const int row = tid >> 2;          // 0..63  (n_local)
      const int cc  = (tid & 3) * 32;    // m chunk
      #pragma unroll
      for (int c4 = 0; c4 < 8; c4++) {
        ushort4 v4 = *(const ushort4*)&tile[row * 132 + cc + c4 * 4];
        *(ushort4*)&vt[(size_t)(bn - 2048 + row) * 2048 + bm + cc + c4 * 4] = v4;
      }
      return;
    }
  }

  if constexpr (SPLIT > 1) {
    // partitioned plain stores: slice z at Cf + z*M*N (sole writer)
    float* Cf = (float*)Cout + (size_t)blockIdx.z * ((size_t)M * N);
    #pragma unroll
    for (int i = 0; i < TM; i++)
      #pragma unroll
      for (int r = 0; r < 4; r++) {
        const int m = bm + wm + i * 16 + (lane >> 4) * 4 + r;
        if (m < M) {
          #pragma unroll
          for (int j = 0; j < TN; j++) {
            const int n = bn + wn + j * 16 + (lane & 15);
            Cf[(size_t)m * N + n] = acc[i][j][r];
          }
        }
      }
  } else {
    #pragma unroll
    for (int i = 0; i < TM; i++) {
      #pragma unroll
      for (int r = 0; r < 4; r++) {
        const int m = bm + wm + i * 16 + (lane >> 4) * 4 + r;
        if (m < M) {
          #pragma unroll
          for (int j = 0; j < TN; j++) {
            const int n = bn + wn + j * 16 + (lane & 15);
            float v = acc[i][j][r];
            if (BIAS) v += bias[n];
            if (GELU) v = 0.5f * v * (1.0f + erff(v * 0.70710678118654752f));
            if (RES)  v += res[(size_t)m * N + n];
            if (OUT_BF16) ((u16*)Cout)[(size_t)m * N + n] = f2bf(v);
            else          ((float*)Cout)[(size_t)m * N + n] = v;
          }
        }
      }
    }
  }
}

// ------ split-K epilogue: out += sum(4 slices) + bias (in-place res) ------
__global__ __launch_bounds__(256) void splitk_epilogue_kernel(
    const float* __restrict__ acc, const float* __restrict__ bias,
    float* __restrict__ out, int M)
{
  const int idx = blockIdx.x * 256 + threadIdx.x;   // float4 index
  if (idx >= M * 256) return;
  const size_t S = (size_t)M * 256;                 // slice stride in float4
  const float4* a4 = (const float4*)acc;
  float4 a0 = a4[idx], a1 = a4[idx + S], a2 = a4[idx + 2 * S], a3 = a4[idx + 3 * S];
  float4 bv = *(const float4*)(bias + (idx & 255) * 4);
  float4 o = *(const float4*)(out + (size_t)idx * 4);
  o.x += (a0.x + a1.x) + (a2.x + a3.x) + bv.x;
  o.y += (a0.y + a1.y) + (a2.y + a3.y) + bv.y;
  o.z += (a0.z + a1.z) + (a2.z + a3.z) + bv.z;
  o.w += (a0.w + a1.w) + (a2.w + a3.w) + bv.w;
  *(float4*)(out + (size_t)idx * 4) = o;
}

// ---- fused MFMA flash attention + metric (flattened 1D grid) -------------
// bid < 1024: attn block (x=bid&31, h=(bid>>5)&15, z=bid>>9), SPLIT=2.
// bid >= 1024: metric block n0 = (bid-1024)*4 (16KB LDS, unioned).
// NOTE (R13 post-mortem): opart must NOT overlay b_hf — metric blocks read
// hf concurrently with attn blocks writing opart. opart lives in fresh ws.
__global__ __launch_bounds__(256) void attn_metric_kernel(
    const u16* __restrict__ qkv, const u16* __restrict__ vt,
    const float* __restrict__ sz, float* __restrict__ opart,
    float* __restrict__ lpart,
    const float* __restrict__ hf, const float* __restrict__ wbar,
    float* __restrict__ metric)
{
  __shared__ __attribute__((aligned(16))) char smem[37888];
  const int bid = blockIdx.x;
  const int tid = threadIdx.x;

  if (bid >= 1024) {   // ---------------- metric branch ----------------
    float (*hs)[1024] = (float(*)[1024])smem;
    const int n0 = (bid - 1024) * 4;
    const int t = tid;
    #pragma unroll
    for (int i = 0; i < 4; i++)
      *(float4*)&hs[i][t * 4] = *(const float4*)(hf + (size_t)(n0 + i) * 1024 + t * 4);
    __syncthreads();
    const int d = t & 63;
    const float* hsw = hs[t >> 6];
    float a0=0,a1=0,a2=0,a3=0,a4=0,a5=0,a6=0,a7=0;
    for (int c = 0; c < 1024; c += 8) {
      a0 += hsw[c+0] * wbar[(c+0)*64 + d];
      a1 += hsw[c+1] * wbar[(c+1)*64 + d];
      a2 += hsw[c+2] * wbar[(c+2)*64 + d];
      a3 += hsw[c+3] * wbar[(c+3)*64 + d];
      a4 += hsw[c+4] * wbar[(c+4)*64 + d];
      a5 += hsw[c+5] * wbar[(c+5)*64 + d];
      a6 += hsw[c+6] * wbar[(c+6)*64 + d];
      a7 += hsw[c+7] * wbar[(c+7)*64 + d];
    }
    float s = ((a0+a1)+(a2+a3)) + ((a4+a5)+(a6+a7));
    float sq = s * s;
    #pragma unroll
    for (int off = 1; off < 64; off <<= 1) sq += __shfl_xor(sq, off);
    metric[(size_t)(n0 + (t >> 6)) * 64 + d] = s / sqrtf(sq);
    return;
  }

  // ---------------- attention branch (R4 structure, SPLIT=2) -------------
  u16* KsB   = (u16*)smem;                 // [2][64*64]
  u16* Vts   = (u16*)(smem + 16384);       // [64*64]
  u16* PsB   = (u16*)(smem + 24576);       // [4][16*72]
  float* lball = (float*)(smem + 33792);   // [1024]

  const int qx = bid & 31, h = (bid >> 5) & 15, z = bid >> 9;
  const int q0 = qx * 64;
  const int lane = tid & 63;
  const int w    = tid >> 6;
  const int col  = lane & 15;
  const int quad = lane >> 4;

  bf16x8 qf[2];
  {
    const u16* qp = qkv + (size_t)(q0 + w * 16 + col) * 3072 + h * 64 + quad * 8;
    qf[0] = *(const bf16x8*)(qp);
    qf[1] = *(const bf16x8*)(qp + 32);
  }

  float l_lane = 0.f;          // all partials belong to q = q0 + w*16 + col
  f32x4 oacc[4] = {};

  const int rl = lane >> 3;
  const int cg = (lane & 7) ^ rl;
  const int kb = z * (N_TOK / 2);
  const int ke = kb + N_TOK / 2;

  constexpr float kScaleLog2e = 0.18033688011112042f;  // 0.125*log2(e)

  // ---- prologue: stage K[0], V[0]; precompute ALL log2(size) once ----
  #pragma unroll
  for (int i = 0; i < 2; i++) {
    const int r = w * 16 + i * 8 + rl;
    __builtin_amdgcn_global_load_lds(
        (const __attribute__((address_space(1))) void*)(qkv + (size_t)(kb + r) * 3072 + 1024 + h * 64 + cg * 8),
        (__attribute__((address_space(3))) void*)(&KsB[(w * 16 + i * 8) * 64]),
        16, 0, 0);
    __builtin_amdgcn_global_load_lds(
        (const __attribute__((address_space(1))) void*)(vt + (size_t)(h * 64 + r) * 2048 + kb + cg * 8),
        (__attribute__((address_space(3))) void*)(&Vts[(w * 16 + i * 8) * 64]),
        16, 0, 0);
  }
  #pragma unroll
  for (int i = tid; i < N_TOK / 2; i += 256)
    lball[i] = __builtin_amdgcn_logf(sz[kb + i]);   // v_log_f32 = log2
  __syncthreads();   // drains prologue staging (vmcnt + lgkmcnt)

  int cur = 0;
  for (int kt = kb; kt < ke; kt += 64) {
    const int nxt = cur ^ 1;
    const bool has_next = (kt + 64 < ke);   // block-uniform

    // ---- issue NEXT K tile into the other K buffer (full-iter overlap) ---
    if (has_next) {
      #pragma unroll
      for (int i = 0; i < 2; i++) {
        const int r = w * 16 + i * 8 + rl;
        __builtin_amdgcn_global_load_lds(
            (const __attribute__((address_space(1))) void*)(qkv + (size_t)(kt + 64 + r) * 3072 + 1024 + h * 64 + cg * 8),
            (__attribute__((address_space(3))) void*)(&KsB[nxt * 4096 + (w * 16 + i * 8) * 64]),
            16, 0, 0);
      }
    }

    // ---- S^T = K Q^T : lane holds S^T[key = jt*16+quad*4+r][q = col] ----
    const u16* Kc = KsB + cur * 4096;
    f32x4 sacc[4] = {};
    #pragma unroll
    for (int kk = 0; kk < 2; kk++) {
      const int slot = (kk * 4 + quad) ^ (lane & 7);
      bf16x8 kf[4];
      #pragma unroll
      for (int jt = 0; jt < 4; jt++)
        kf[jt] = *(const bf16x8*)&Kc[(jt * 16 + col) * 64 + slot * 8];
      __builtin_amdgcn_s_setprio(1);
      #pragma unroll
      for (int jt = 0; jt < 4; jt++)
        sacc[jt] = __builtin_amdgcn_mfma_f32_16x16x32_bf16(kf[jt], qf[kk], sacc[jt], 0, 0, 0);
      __builtin_amdgcn_s_setprio(0);
    }

    // exp2-domain softmax weights + packed P-writes (4x b64), l per-lane
    u16* pw = PsB + w * (16 * 72);
    const float* lbp = &lball[kt - kb];
    #pragma unroll
    for (int jt = 0; jt < 4; jt++) {
      float4 lb4 = *(const float4*)&lbp[jt * 16 + quad * 4];
      const float p0 = __builtin_amdgcn_exp2f(fmaf(sacc[jt][0], kScaleLog2e, lb4.x));
      const float p1 = __builtin_amdgcn_exp2f(fmaf(sacc[jt][1], kScaleLog2e, lb4.y));
      const float p2 = __builtin_amdgcn_exp2f(fmaf(sacc[jt][2], kScaleLog2e, lb4.z));
      const float p3 = __builtin_amdgcn_exp2f(fmaf(sacc[jt][3], kScaleLog2e, lb4.w));
      l_lane += (p0 + p1) + (p2 + p3);
      uint2 pkk;
      pkk.x = cvt_pk_bf16(p0, p1);
      pkk.y = cvt_pk_bf16(p2, p3);
      *(uint2*)&pw[col * 72 + jt * 16 + quad * 4] = pkk;
    }
    // same-wave LDS RAW -> lgkmcnt (verified pattern); rows 144B apart
    bf16x8 pf[2];
    #pragma unroll
    for (int kk = 0; kk < 2; kk++)
      pf[kk] = *(const bf16x8*)&pw[col * 72 + kk * 32 + quad * 8];

    // barrier A: implicit vmcnt(0) drains V[this tile] (issued last iter,
    // had the whole QK+softmax above to load) + K[nxt] (usually done too)
    __syncthreads();

    // O += P V (A = P rows=q, B = V^T)
    #pragma unroll
    for (int kk = 0; kk < 2; kk++) {
      const int slot = (kk * 4 + quad) ^ (lane & 7);
      bf16x8 vf[4];
      #pragma unroll
      for (int nt = 0; nt < 4; nt++)
        vf[nt] = *(const bf16x8*)&Vts[(nt * 16 + col) * 64 + slot * 8];
      __builtin_amdgcn_s_setprio(1);
      #pragma unroll
      for (int nt = 0; nt < 4; nt++)
        oacc[nt] = __builtin_amdgcn_mfma_f32_16x16x32_bf16(pf[kk], vf[nt], oacc[nt], 0, 0, 0);
      __builtin_amdgcn_s_setprio(0);
    }

    // barrier B: all waves done reading Vts -> safe to overwrite
    __syncthreads();

    // ---- issue NEXT V tile into the single V buffer (overlaps next QK) --
    if (has_next) {
      #pragma unroll
      for (int i = 0; i < 2; i++) {
        const int r = w * 16 + i * 8 + rl;
        __builtin_amdgcn_global_load_lds(
            (const __attribute__((address_space(1))) void*)(vt + (size_t)(h * 64 + r) * 2048 + kt + 64 + cg * 8),
            (__attribute__((address_space(3))) void*)(&Vts[(w * 16 + i * 8) * 64]),
            16, 0, 0);
      }
    }
    cur = nxt;
  }

  // l: sum the 4 quads of each col group (once)
  l_lane += __shfl_xor(l_lane, 16);
  l_lane += __shfl_xor(l_lane, 32);

  // partitioned plain stores (sole writer per (q,h,z) — no atomics)
  float* osl = opart + (size_t)z * ((size_t)N_TOK * 1024);
  #pragma unroll
  for (int r = 0; r < 4; r++) {
    const int q = q0 + w * 16 + quad * 4 + r;
    float* op = osl + (size_t)q * 1024 + h * 64 + col;
    #pragma unroll
    for (int nt = 0; nt < 4; nt++)
      op[nt * 16] = oacc[nt][r];
  }
  if (quad == 0)
    lpart[(size_t)z * (N_TOK * 16) + (q0 + w * 16 + col) * 16 + h] = l_lane;
}

// ------ fused attn-normalize + merge-score (independent work, packed) -----
__global__ __launch_bounds__(256) void norm_score_kernel(
    const float* __restrict__ opart, const float* __restrict__ lpart,
    u16* __restrict__ xa,
    const float* __restrict__ metric, const float* __restrict__ thr,
    int* __restrict__ mask, int* __restrict__ node)
{
  __shared__ float a[4][64];
  __shared__ float bw_[4][4];
  __shared__ int biw_[4][4];
  const int bid = blockIdx.x;
  const int t = threadIdx.x;
  if (bid < 2048) {
    const int q = bid;
    const int c = t * 4;
    float4 o0 = *(const float4*)(opart + (size_t)q * 1024 + c);
    float4 o1 = *(const float4*)(opart + (size_t)N_TOK * 1024 + (size_t)q * 1024 + c);
    const float l0 = lpart[q * 16 + (c >> 6)];
    const float l1 = lpart[N_TOK * 16 + q * 16 + (c >> 6)];
    const float inv = 1.0f / (l0 + l1);
    ushort4 o4;
    o4.x = f2bf((o0.x + o1.x) * inv); o4.y = f2bf((o0.y + o1.y) * inv);
    o4.z = f2bf((o0.z + o1.z) * inv); o4.w = f2bf((o0.w + o1.w) * inv);
    *(ushort4*)(xa + (size_t)q * 1024 + c) = o4;
    return;
  }
  const int s0 = (bid - 2048) * 4;
  a[t >> 6][t & 63] = metric[(size_t)(2 * (s0 + (t >> 6))) * 64 + (t & 63)];
  __syncthreads();
  float best[4] = {-INFINITY, -INFINITY, -INFINITY, -INFINITY};
  int besti[4] = {0, 0, 0, 0};
  for (int m = t; m < 1024; m += 256) {
    const float* bp = metric + (size_t)(2 * m + 1) * 64;
    float s[4] = {0.f, 0.f, 0.f, 0.f};
    #pragma unroll
    for (int d = 0; d < 64; d += 4) {
      float4 bv = *(const float4*)(bp + d);
      #pragma unroll
      for (int j = 0; j < 4; j++) {
        float4 av = *(const float4*)&a[j][d];
        s[j] += av.x*bv.x + av.y*bv.y + av.z*bv.z + av.w*bv.w;
      }
    }
    #pragma unroll
    for (int j = 0; j < 4; j++)
      if (s[j] > best[j]) { best[j] = s[j]; besti[j] = m; }   // ascending m
  }
  #pragma unroll
  for (int j = 0; j < 4; j++) {
    float b = best[j]; int bi = besti[j];
    #pragma unroll
    for (int off = 1; off < 64; off <<= 1) {
      float ov = __shfl_xor(b, off);
      int   oi = __shfl_xor(bi, off);
      if (ov > b || (ov == b && oi < bi)) { b = ov; bi = oi; }
    }
    best[j] = b; besti[j] = bi;
  }
  const int wv = t >> 6;
  if ((t & 63) == 0) {
    #pragma unroll
    for (int j = 0; j < 4; j++) { bw_[wv][j] = best[j]; biw_[wv][j] = besti[j]; }
  }
  __syncthreads();
  if (t < 4) {
    const int j = t;
    float b = bw_[0][j]; int bi = biw_[0][j];
    for (int ww = 1; ww < 4; ww++)
      if (bw_[ww][j] > b || (bw_[ww][j] == b && biw_[ww][j] < bi)) { b = bw_[ww][j]; bi = biw_[ww][j]; }
    const int n = s0 + j;
    if (n == 0) { mask[0] = 0; node[0] = 0; }
    else { mask[n] = (b > thr[0]) ? 1 : 0; node[n] = bi; }
  }
}

// ------ build merged rows; scan folded in (pos computed per-block) --------
__global__ __launch_bounds__(256) void build_kernel(
    const float* __restrict__ xres, const float* __restrict__ sz,
    const int* __restrict__ mask, float* __restrict__ xm,
    float* __restrict__ sizem, int U)
{
  const int b = blockIdx.x;
  const int t = threadIdx.x;
  __shared__ int red[4];
  int srow, orow;
  if (b < 1024) { srow = 2 * b + 1; orow = U + b; }
  else {
    const int i = b - 1024;
    if (mask[i]) return;
    int cnt = 0;
    for (int j = t; j < i; j += 256) cnt += mask[j] ? 0 : 1;
    #pragma unroll
    for (int off = 1; off < 64; off <<= 1) cnt += __shfl_xor(cnt, off);
    if ((t & 63) == 0) red[t >> 6] = cnt;
    __syncthreads();
    orow = red[0] + red[1] + red[2] + red[3];
    srow = 2 * i;
  }
  const float ssz = sz[srow];
  const float* xp = xres + (size_t)srow * 1024;
  float* op = xm + (size_t)orow * 1024;
  const int c = t * 4;
  float4 v = *(const float4*)(xp + c);
  v.x *= ssz; v.y *= ssz; v.z *= ssz; v.w *= ssz;
  *(float4*)(op + c) = v;
  if (t == 0) sizem[orow] = ssz;
}

// ---------------- scatter-add merged src tokens into dst rows -------------
__global__ __launch_bounds__(256) void merge_add_kernel(
    const float* __restrict__ xres, const float* __restrict__ sz,
    const int* __restrict__ mask, const int* __restrict__ node,
    float* __restrict__ xm, float* __restrict__ sizem, int U)
{
  const int i = blockIdx.x;
  if (!mask[i]) return;
  const int t = threadIdx.x;
  const int srow = 2 * i;
  const int orow = U + node[i];
  const float ssz = sz[srow];
  const float* xp = xres + (size_t)srow * 1024;
  float* op = xm + (size_t)orow * 1024;
  for (int c = t; c < 1024; c += 256)
    atomicAdd(op + c, xp[c] * ssz);
  if (t == 0) atomicAdd(sizem + orow, ssz);
}

extern "C" void kernel_launch(void* const* d_in, const int* in_sizes, int n_in,
                              void* d_out, int out_size, void* d_ws, size_t ws_size,
                              hipStream_t stream) {
  const float* x      = (const float*)d_in[0];
  const float* sz     = (const float*)d_in[1];
  const float* qkv_w  = (const float*)d_in[2];
  const float* proj_w = (const float*)d_in[3];
  const float* proj_b = (const float*)d_in[4];
  const float* ln1_g  = (const float*)d_in[5];
  const float* ln1_b  = (const float*)d_in[6];
  const float* ln2_g  = (const float*)d_in[7];
  const float* ln2_b  = (const float*)d_in[8];
  const float* fc1_w  = (const float*)d_in[9];
  const float* fc1_b  = (const float*)d_in[10];
  const float* fc2_w  = (const float*)d_in[11];
  const float* fc2_b  = (const float*)d_in[12];
  const float* thr    = (const float*)d_in[13];

  const int M = out_size / 1025;
  const int U = M - 1024;
  const size_t MB = 1u << 20;
  const size_t KB = 1u << 10;

  // workspace layout (ws = 256 MiB):
  //  [0,6)   w_qkvT          [6,7)   wbar/met/mask/node
  //  [7,7.25) lpart          [8,10)  w_projT
  //  [10,22) b_qkv -> b_xa[10,14) -> b_xm[10,18)
  //  [22,30) b_hf (live through attn_metric!) -> b_xres (after metric)
  //  [30,34) b_h (dead after QKV GEMM)
  //  [71,79) w_fc1T  [79,87) w_fc2T  [87,104) b_g
  //  [104,108) b_h2  [108,142) b_facc  [142,146) vt
  //  [146,162) opart (FRESH — must not overlay b_hf; R13 race fix)
  char* ws = (char*)d_ws;
  u16*   w_qkvT  = (u16*)(ws + 0);
  float* b_wbar  = (float*)(ws + 6 * MB);
  float* b_met   = (float*)(ws + 6 * MB + 256 * KB);
  int*   b_mask  = (int*)(ws + 6 * MB + 768 * KB);
  int*   b_node  = b_mask + 1024;
  float* b_szm   = (float*)(b_node + 1024);
  float* b_lpart = (float*)(ws + 7 * MB);            // 2 x 128KB slices
  u16*   w_projT = (u16*)(ws + 8 * MB);
  u16*   b_qkv   = (u16*)(ws + 10 * MB);
  u16*   b_xa    = (u16*)(ws + 10 * MB);   // over dead b_qkv (after attn)
  float* b_xm    = (float*)(ws + 10 * MB);   // over dead b_xa (after proj)
  float* b_hf    = (float*)(ws + 22 * MB);
  float* b_xres  = (float*)(ws + 22 * MB);   // over dead b_hf (post-metric)
  u16*   b_h     = (u16*)(ws + 30 * MB);
  u16*   w_fc1T  = (u16*)(ws + 71 * MB);
  u16*   w_fc2T  = (u16*)(ws + 79 * MB);
  u16*   b_g     = (u16*)(ws + 87 * MB);
  u16*   b_h2    = (u16*)(ws + 104 * MB);
  float* b_facc  = (float*)(ws + 108 * MB);  // 4 partitioned slices
  u16*   b_vt    = (u16*)(ws + 142 * MB);    // written by QKV GEMM
  float* b_opart = (float*)(ws + 146 * MB);  // 2 x 8MB slices, FRESH

  float* outx = (float*)d_out;
  float* outs = outx + (size_t)M * 1024;

  // 1. fused opening launch: LN1 + ALL weight converts + wbar
  fused_pre_kernel<<<14592, 256, 0, stream>>>(
      x, ln1_g, ln1_b, b_h, b_hf,
      qkv_w, w_qkvT, proj_w, w_projT, fc1_w, w_fc1T, fc2_w, w_fc2T, b_wbar);
  // 2. QKV GEMM; V-third blocks store TRANSPOSED into b_vt (vt via res arg)
  gemm_mfma<128, 64, 1, false, false, false, true, true><<<dim3(48, 16), 256, 0, stream>>>(
      b_h, w_qkvT, nullptr, (const float*)b_vt, b_qkv, 2048, 3072, 1024);
  // 3. fused MFMA attention + metric (flattened grid: 1024 attn + 512 metric)
  attn_metric_kernel<<<1536, 256, 0, stream>>>(
      b_qkv, b_vt, sz, b_opart, b_lpart, b_hf, b_wbar, b_met);
  // 4. fused attn-normalize + merge-score (independent, packed)
  norm_score_kernel<<<2304, 256, 0, stream>>>(b_opart, b_lpart, b_xa, b_met, thr, b_mask, b_node);
  // 5. proj GEMM + bias + residual(x) -> xres fp32 — 512 blocks
  gemm_mfma<64, 64, 1, true, false, true, false><<<dim3(16, 32), 256, 0, stream>>>(
      b_xa, w_projT, proj_b, x, b_xres, 2048, 1024, 1024);
  // 6. build merged rows (scan folded in)
  build_kernel<<<2048, 256, 0, stream>>>(b_xres, sz, b_mask, b_xm, b_szm, U);
  // 7. scatter-add merged src tokens
  merge_add_kernel<<<1024, 256, 0, stream>>>(b_xres, sz, b_mask, b_node, b_xm, b_szm, U);
  // 8. fused divide + LN2 (one block per row): outx, outs, h2
  divide_ln2_kernel<<<M, 256, 0, stream>>>(b_xm, b_szm, ln2_g, ln2_b, outx, outs, b_h2);
  // 9. fc1 + bias + exact GELU -> bf16 — 768 blocks
  gemm_mfma<128, 64, 1, true, true, false, true><<<dim3(64, (M + 127) / 128), 256, 0, stream>>>(
      b_h2, w_fc1T, fc1_b, nullptr, b_g, M, 4096, 1024);
  // 10. fc2 split-K=4, partitioned slices (no memset, no atomics)
  gemm_mfma<128, 64, 4, false, false, false, false><<<dim3(16, (M + 127) / 128, 4), 256, 0, stream>>>(
      b_g, w_fc2T, nullptr, nullptr, b_facc, M, 1024, 4096);
  // 11. fc2 epilogue: outx += sum(4 slices) + bias (residual in-place)
  splitk_epilogue_kernel<<<(M * 256 + 255) / 256, 256, 0, stream>>>(
      b_facc, fc2_b, outx, M);
  (void)in_sizes; (void)n_in; (void)ws_size;
}

// Round 15
// 283.534 us; speedup vs baseline: 1.2207x; 1.0005x over previous
//
#include <hip/hip_runtime.h>
#include <math.h>

typedef unsigned short u16;
typedef __attribute__((ext_vector_type(8))) short bf16x8;
typedef __attribute__((ext_vector_type(4))) float f32x4;

#define C_DIM 1024
#define N_TOK 2048

static __device__ __forceinline__ u16 f2bf(float f) {
  union { float f; unsigned u; } v; v.f = f;
  unsigned r = v.u + 0x7fff + ((v.u >> 16) & 1);
  return (u16)(r >> 16);
}

// packed f32x2 -> bf16x2 (RNE, same rounding as f2bf) in ONE VALU op
static __device__ __forceinline__ unsigned cvt_pk_bf16(float lo, float hi) {
  unsigned r;
  asm("v_cvt_pk_bf16_f32 %0, %1, %2" : "=v"(r) : "v"(lo), "v"(hi));
  return r;
}

// ---------------- transpose body: W[K][N] tile (by,bx) -> WT[N][K] --------
static __device__ __forceinline__ void conv_body(
    const float* __restrict__ W, u16* __restrict__ WT, int K, int N,
    int bx, int by, float (*tile)[33], int tx, int ty)
{
  #pragma unroll
  for (int i = 0; i < 32; i += 8)
    tile[ty + i][tx] = W[(size_t)(by + ty + i) * N + bx + tx];
  __syncthreads();
  #pragma unroll
  for (int i = 0; i < 32; i += 8)
    WT[(size_t)(bx + ty + i) * K + by + tx] = f2bf(tile[tx][ty + i]);
}

// ---- fused opening launch: LN1 + ALL weight converts + wbar (input-only) -
__global__ __launch_bounds__(256) void fused_pre_kernel(
    const float* __restrict__ x, const float* __restrict__ ln1_g,
    const float* __restrict__ ln1_b, u16* __restrict__ b_h,
    float* __restrict__ b_hf,
    const float* __restrict__ qkv_w, u16* __restrict__ w_qkvT,
    const float* __restrict__ proj_w, u16* __restrict__ w_projT,
    const float* __restrict__ fc1_w, u16* __restrict__ w_fc1T,
    const float* __restrict__ fc2_w, u16* __restrict__ w_fc2T,
    float* __restrict__ wbar)
{
  __shared__ float tile[32][33];
  __shared__ float rs[4], rss[4];
  const int bid = blockIdx.x;
  const int t = threadIdx.x;
  const int tx = t & 31, ty = t >> 5;
  if (bid < 2048) {            // ---- LN1 (verbatim ln body) ----
    const int row = bid;
    const float* xr = x + (size_t)row * C_DIM;
    float4 xv = *(const float4*)(xr + t * 4);
    float s  = xv.x + xv.y + xv.z + xv.w;
    float ss = xv.x*xv.x + xv.y*xv.y + xv.z*xv.z + xv.w*xv.w;
    #pragma unroll
    for (int off = 1; off < 64; off <<= 1) {
      s  += __shfl_xor(s, off);
      ss += __shfl_xor(ss, off);
    }
    const int w = t >> 6;
    if ((t & 63) == 0) { rs[w] = s; rss[w] = ss; }
    __syncthreads();
    s  = rs[0] + rs[1] + rs[2] + rs[3];
    ss = rss[0] + rss[1] + rss[2] + rss[3];
    const float mean = s * (1.0f / C_DIM);
    const float var  = ss * (1.0f / C_DIM) - mean * mean;
    const float inv  = rsqrtf(var + 1e-5f);
    float4 gv = *(const float4*)(ln1_g + t * 4);
    float4 bv = *(const float4*)(ln1_b + t * 4);
    float4 o;
    o.x = (xv.x - mean) * inv * gv.x + bv.x;
    o.y = (xv.y - mean) * inv * gv.y + bv.y;
    o.z = (xv.z - mean) * inv * gv.z + bv.z;
    o.w = (xv.w - mean) * inv * gv.w + bv.w;
    ushort4 o4;
    o4.x = f2bf(o.x); o4.y = f2bf(o.y); o4.z = f2bf(o.z); o4.w = f2bf(o.w);
    *(ushort4*)(b_h + (size_t)row * C_DIM + t * 4) = o4;
    *(float4*)(b_hf + (size_t)row * C_DIM + t * 4) = o;
  } else if (bid < 5120) {     // ---- qkv^T: 96 x 32 tiles ----
    const int b2 = bid - 2048;
    conv_body(qkv_w, w_qkvT, 1024, 3072, (b2 % 96) * 32, (b2 / 96) * 32, tile, tx, ty);
  } else if (bid < 6144) {     // ---- proj^T: 32 x 32 tiles ----
    const int b2 = bid - 5120;
    conv_body(proj_w, w_projT, 1024, 1024, (b2 % 32) * 32, (b2 / 32) * 32, tile, tx, ty);
  } else if (bid < 10240) {    // ---- fc1^T: 128 x 32 tiles ----
    const int b2 = bid - 6144;
    conv_body(fc1_w, w_fc1T, 1024, 4096, (b2 % 128) * 32, (b2 / 128) * 32, tile, tx, ty);
  } else if (bid < 14336) {    // ---- fc2^T: 32 x 128 tiles ----
    const int b2 = bid - 10240;
    conv_body(fc2_w, w_fc2T, 4096, 1024, (b2 % 32) * 32, (b2 / 32) * 32, tile, tx, ty);
  } else {                     // ---- wbar: 256 blocks ----
    const int idx = (bid - 14336) * 256 + t;   // c*64 + d
    const int c = idx >> 6, d = idx & 63;
    float s = 0.f;
    #pragma unroll
    for (int h = 0; h < 16; h++)
      s += qkv_w[(size_t)c * 3072 + 1024 + h * 64 + d];
    wbar[idx] = s * (1.0f / 16.0f);
  }
}

// -------- fused divide + LN2: v = xm/size -> outx/outs, LN(v) -> h2 -------
__global__ __launch_bounds__(256) void divide_ln2_kernel(
    const float* __restrict__ xm, const float* __restrict__ sizem,
    const float* __restrict__ g, const float* __restrict__ b,
    float* __restrict__ outx, float* __restrict__ outs,
    u16* __restrict__ h2)
{
  const int row = blockIdx.x;
  const int t = threadIdx.x;
  const float sz = sizem[row];
  float4 xv = *(const float4*)(xm + (size_t)row * C_DIM + t * 4);
  xv.x = xv.x / sz; xv.y = xv.y / sz; xv.z = xv.z / sz; xv.w = xv.w / sz;
  *(float4*)(outx + (size_t)row * C_DIM + t * 4) = xv;
  if (t == 0) outs[row] = sz;
  float s  = xv.x + xv.y + xv.z + xv.w;
  float ss = xv.x*xv.x + xv.y*xv.y + xv.z*xv.z + xv.w*xv.w;
  #pragma unroll
  for (int off = 1; off < 64; off <<= 1) {
    s  += __shfl_xor(s, off);
    ss += __shfl_xor(ss, off);
  }
  __shared__ float rs[4], rss[4];
  const int w = t >> 6;
  if ((t & 63) == 0) { rs[w] = s; rss[w] = ss; }
  __syncthreads();
  s  = rs[0] + rs[1] + rs[2] + rs[3];
  ss = rss[0] + rss[1] + rss[2] + rss[3];
  const float mean = s * (1.0f / C_DIM);
  const float var  = ss * (1.0f / C_DIM) - mean * mean;
  const float inv  = rsqrtf(var + 1e-5f);
  float4 gv = *(const float4*)(g + t * 4);
  float4 bv = *(const float4*)(b + t * 4);
  float4 o;
  o.x = (xv.x - mean) * inv * gv.x + bv.x;
  o.y = (xv.y - mean) * inv * gv.y + bv.y;
  o.z = (xv.z - mean) * inv * gv.z + bv.z;
  o.w = (xv.w - mean) * inv * gv.w + bv.w;
  ushort4 o4;
  o4.x = f2bf(o.x); o4.y = f2bf(o.y); o4.z = f2bf(o.z); o4.w = f2bf(o.w);
  *(ushort4*)(h2 + (size_t)row * C_DIM + t * 4) = o4;
}

// ---------------- bf16 MFMA GEMM: C[M,N] = A[M,K] @ BT[N,K]^T -------------
// R6 geometry (proven): BN=64, LDS double-buffer, one barrier/iter.
// SPLIT>1: partitioned slices.
template<int BM, int BN, int SPLIT, bool BIAS, bool GELU, bool RES, bool OUT_BF16>
__global__ __launch_bounds__(256) void gemm_mfma(
    const u16* __restrict__ A,   // [>=gridDim.y*BM][K] bf16 (readable padding)
    const u16* __restrict__ BT,  // [N][K] bf16
    const float* __restrict__ bias, const float* __restrict__ res,
    void* __restrict__ Cout, int M, int N, int K)
{
  constexpr int TM = BM / 32;                 // 16x16 tiles per wave (rows)
  constexpr int TN = BN / 32;                 // 16x16 tiles per wave (cols)
  __shared__ u16 As[2][BM * 64] __attribute__((aligned(16)));
  __shared__ u16 Bs[2][BN * 64] __attribute__((aligned(16)));
  const int tid  = threadIdx.x;
  const int lane = tid & 63;
  const int w    = tid >> 6;
  const int bm = blockIdx.y * BM;
  const int bn = blockIdx.x * BN;
  const int wm = (w >> 1) * (BM / 2);
  const int wn = (w & 1) * (BN / 2);

  f32x4 acc[TM][TN] = {};

  const int rl = lane >> 3;                 // row-in-8-group
  const int cg = (lane & 7) ^ rl;           // swizzled source chunk

  const int kb = (K / SPLIT) * blockIdx.z;
  const int ke = kb + K / SPLIT;

#define GEMM_STAGE(buf, k0_)                                                   \
  {                                                                            \
    _Pragma("unroll")                                                          \
    for (int i = 0; i < BM / 32; i++) {                                        \
      const int r = w * (BM / 4) + i * 8 + rl;                                 \
      __builtin_amdgcn_global_load_lds(                                        \
          (const __attribute__((address_space(1))) void*)(A + (size_t)(bm + r) * K + (k0_) + cg * 8), \
          (__attribute__((address_space(3))) void*)(&As[buf][(w * (BM / 4) + i * 8) * 64]), \
          16, 0, 0);                                                           \
    }                                                                          \
    _Pragma("unroll")                                                          \
    for (int i = 0; i < BN / 32; i++) {                                        \
      const int r = w * (BN / 4) + i * 8 + rl;                                 \
      __builtin_amdgcn_global_load_lds(                                        \
          (const __attribute__((address_space(1))) void*)(BT + (size_t)(bn + r) * K + (k0_) + cg * 8), \
          (__attribute__((address_space(3))) void*)(&Bs[buf][(w * (BN / 4) + i * 8) * 64]), \
          16, 0, 0);                                                           \
    }                                                                          \
  }

  // prologue: stage first K-tile into buffer 0
  GEMM_STAGE(0, kb);
  __syncthreads();

  int cur = 0;
  for (int k0 = kb; k0 < ke; k0 += 64) {
    // issue next tile's loads into the other buffer (overlap compute)
    if (k0 + 64 < ke) GEMM_STAGE(cur ^ 1, k0 + 64);

    #pragma unroll
    for (int kk = 0; kk < 2; kk++) {
      bf16x8 af[TM], bfr[TN];
      const int slot = (kk * 4 + (lane >> 4)) ^ (lane & 7);
      #pragma unroll
      for (int i = 0; i < TM; i++)
        af[i] = *(const bf16x8*)&As[cur][(wm + i * 16 + (lane & 15)) * 64 + slot * 8];
      #pragma unroll
      for (int j = 0; j < TN; j++)
        bfr[j] = *(const bf16x8*)&Bs[cur][(wn + j * 16 + (lane & 15)) * 64 + slot * 8];
      __builtin_amdgcn_s_setprio(1);
      #pragma unroll
      for (int i = 0; i < TM; i++)
        #pragma unroll
        for (int j = 0; j < TN; j++)
          acc[i][j] = __builtin_amdgcn_mfma_f32_16x16x32_bf16(af[i], bfr[j], acc[i][j], 0, 0, 0);
      __builtin_amdgcn_s_setprio(0);
    }
    __syncthreads();
    cur ^= 1;
  }
#undef GEMM_STAGE

  if constexpr (SPLIT > 1) {
    // partitioned plain stores: slice z at Cf + z*M*N (sole writer)
    float* Cf = (float*)Cout + (size_t)blockIdx.z * ((size_t)M * N);
    #pragma unroll
    for (int i = 0; i < TM; i++)
      #pragma unroll
      for (int r = 0; r < 4; r++) {
        const int m = bm + wm + i * 16 + (lane >> 4) * 4 + r;
        if (m < M) {
          #pragma unroll
          for (int j = 0; j < TN; j++) {
            const int n = bn + wn + j * 16 + (lane & 15);
            Cf[(size_t)m * N + n] = acc[i][j][r];
          }
        }
      }
  } else {
    #pragma unroll
    for (int i = 0; i < TM; i++) {
      #pragma unroll
      for (int r = 0; r < 4; r++) {
        const int m = bm + wm + i * 16 + (lane >> 4) * 4 + r;
        if (m < M) {
          #pragma unroll
          for (int j = 0; j < TN; j++) {
            const int n = bn + wn + j * 16 + (lane & 15);
            float v = acc[i][j][r];
            if (BIAS) v += bias[n];
            if (GELU) v = 0.5f * v * (1.0f + erff(v * 0.70710678118654752f));
            if (RES)  v += res[(size_t)m * N + n];
            if (OUT_BF16) ((u16*)Cout)[(size_t)m * N + n] = f2bf(v);
            else          ((float*)Cout)[(size_t)m * N + n] = v;
          }
        }
      }
    }
  }
}

// ---- fused QKV GEMM (+VT transpose out) + metric (flattened 1D grid) -----
// bid < 768: GEMM block (bx = bid%48 -> bn, by = bid/48 -> bm); V-third
//   (bn>=2048) stores C-tile TRANSPOSED into vt[d][token] via LDS.
// bid >= 768: metric block n0 = (bid-768)*4 — metric's deps (hf, wbar) are
//   ready before this launch; packing here (throughput-bound GEMM host)
//   instead of the latency-sensitive attn launch (R14: cost attn +15us).
__global__ __launch_bounds__(256) void qkv_metric_kernel(
    const u16* __restrict__ A, const u16* __restrict__ BT,
    u16* __restrict__ vt, u16* __restrict__ Cout,
    const float* __restrict__ hf, const float* __restrict__ wbar,
    float* __restrict__ metric)
{
  __shared__ __attribute__((aligned(16))) char smem[49152];
  const int bid = blockIdx.x;
  const int tid = threadIdx.x;

  if (bid >= 768) {   // ---------------- metric branch ----------------
    float (*hs)[1024] = (float(*)[1024])smem;
    const int n0 = (bid - 768) * 4;
    const int t = tid;
    #pragma unroll
    for (int i = 0; i < 4; i++)
      *(float4*)&hs[i][t * 4] = *(const float4*)(hf + (size_t)(n0 + i) * 1024 + t * 4);
    __syncthreads();
    const int d = t & 63;
    const float* hsw = hs[t >> 6];
    float a0=0,a1=0,a2=0,a3=0,a4=0,a5=0,a6=0,a7=0;
    for (int c = 0; c < 1024; c += 8) {
      a0 += hsw[c+0] * wbar[(c+0)*64 + d];
      a1 += hsw[c+1] * wbar[(c+1)*64 + d];
      a2 += hsw[c+2] * wbar[(c+2)*64 + d];
      a3 += hsw[c+3] * wbar[(c+3)*64 + d];
      a4 += hsw[c+4] * wbar[(c+4)*64 + d];
      a5 += hsw[c+5] * wbar[(c+5)*64 + d];
      a6 += hsw[c+6] * wbar[(c+6)*64 + d];
      a7 += hsw[c+7] * wbar[(c+7)*64 + d];
    }
    float s = ((a0+a1)+(a2+a3)) + ((a4+a5)+(a6+a7));
    float sq = s * s;
    #pragma unroll
    for (int off = 1; off < 64; off <<= 1) sq += __shfl_xor(sq, off);
    metric[(size_t)(n0 + (t >> 6)) * 64 + d] = s / sqrtf(sq);
    return;
  }

  // ---------------- GEMM branch: BM=128, BN=64, K=1024, M=2048, N=3072 ----
  constexpr int BM = 128, BN = 64, TM = 4, TN = 2, K = 1024;
  u16 (*As)[BM * 64] = (u16(*)[BM * 64])smem;            // 2 x 16KB
  u16 (*Bs)[BN * 64] = (u16(*)[BN * 64])(smem + 32768);  // 2 x 8KB
  const int lane = tid & 63;
  const int w    = tid >> 6;
  const int bm = (bid / 48) * BM;
  const int bn = (bid % 48) * BN;
  const int wm = (w >> 1) * (BM / 2);
  const int wn = (w & 1) * (BN / 2);

  f32x4 acc[TM][TN] = {};

  const int rl = lane >> 3;
  const int cg = (lane & 7) ^ rl;

#define QKV_STAGE(buf, k0_)                                                    \
  {                                                                            \
    _Pragma("unroll")                                                          \
    for (int i = 0; i < BM / 32; i++) {                                        \
      const int r = w * (BM / 4) + i * 8 + rl;                                 \
      __builtin_amdgcn_global_load_lds(                                        \
          (const __attribute__((address_space(1))) void*)(A + (size_t)(bm + r) * K + (k0_) + cg * 8), \
          (__attribute__((address_space(3))) void*)(&As[buf][(w * (BM / 4) + i * 8) * 64]), \
          16, 0, 0);                                                           \
    }                                                                          \
    _Pragma("unroll")                                                          \
    for (int i = 0; i < BN / 32; i++) {                                        \
      const int r = w * (BN / 4) + i * 8 + rl;                                 \
      __builtin_amdgcn_global_load_lds(                                        \
          (const __attribute__((address_space(1))) void*)(BT + (size_t)(bn + r) * K + (k0_) + cg * 8), \
          (__attribute__((address_space(3))) void*)(&Bs[buf][(w * (BN / 4) + i * 8) * 64]), \
          16, 0, 0);                                                           \
    }                                                                          \
  }

  QKV_STAGE(0, 0);
  __syncthreads();

  int cur = 0;
  for (int k0 = 0; k0 < K; k0 += 64) {
    if (k0 + 64 < K) QKV_STAGE(cur ^ 1, k0 + 64);

    #pragma unroll
    for (int kk = 0; kk < 2; kk++) {
      bf16x8 af[TM], bfr[TN];
      const int slot = (kk * 4 + (lane >> 4)) ^ (lane & 7);
      #pragma unroll
      for (int i = 0; i < TM; i++)
        af[i] = *(const bf16x8*)&As[cur][(wm + i * 16 + (lane & 15)) * 64 + slot * 8];
      #pragma unroll
      for (int j = 0; j < TN; j++)
        bfr[j] = *(const bf16x8*)&Bs[cur][(wn + j * 16 + (lane & 15)) * 64 + slot * 8];
      __builtin_amdgcn_s_setprio(1);
      #pragma unroll
      for (int i = 0; i < TM; i++)
        #pragma unroll
        for (int j = 0; j < TN; j++)
          acc[i][j] = __builtin_amdgcn_mfma_f32_16x16x32_bf16(af[i], bfr[j], acc[i][j], 0, 0, 0);
      __builtin_amdgcn_s_setprio(0);
    }
    __syncthreads();
    cur ^= 1;
  }
#undef QKV_STAGE

  if (bn >= 2048) {
    // transposed V store: tile[n_local][m_local], stride 132 u16
    u16* tile = (u16*)&As[0][0];
    #pragma unroll
    for (int i = 0; i < TM; i++)
      #pragma unroll
      for (int j = 0; j < TN; j++) {
        const int nl = wn + j * 16 + (lane & 15);
        const int mb = wm + i * 16 + (lane >> 4) * 4;
        uint2 pk;
        pk.x = cvt_pk_bf16(acc[i][j][0], acc[i][j][1]);
        pk.y = cvt_pk_bf16(acc[i][j][2], acc[i][j][3]);
        *(uint2*)&tile[nl * 132 + mb] = pk;
      }
    __syncthreads();
    const int row = tid >> 2;          // 0..63  (n_local)
    const int cc  = (tid & 3) * 32;    // m chunk
    #pragma unroll
    for (int c4 = 0; c4 < 8; c4++) {
      ushort4 v4 = *(const ushort4*)&tile[row * 132 + cc + c4 * 4];
      *(ushort4*)&vt[(size_t)(bn - 2048 + row) * 2048 + bm + cc + c4 * 4] = v4;
    }
    return;
  }

  #pragma unroll
  for (int i = 0; i < TM; i++)
    #pragma unroll
    for (int r = 0; r < 4; r++) {
      const int m = bm + wm + i * 16 + (lane >> 4) * 4 + r;
      #pragma unroll
      for (int j = 0; j < TN; j++) {
        const int n = bn + wn + j * 16 + (lane & 15);
        Cout[(size_t)m * 3072 + n] = f2bf(acc[i][j][r]);
      }
    }
}

// ------ split-K epilogue: out += sum(4 slices) + bias (in-place res) ------
__global__ __launch_bounds__(256) void splitk_epilogue_kernel(
    const float* __restrict__ acc, const float* __restrict__ bias,
    float* __restrict__ out, int M)
{
  const int idx = blockIdx.x * 256 + threadIdx.x;   // float4 index
  if (idx >= M * 256) return;
  const size_t S = (size_t)M * 256;                 // slice stride in float4
  const float4* a4 = (const float4*)acc;
  float4 a0 = a4[idx], a1 = a4[idx + S], a2 = a4[idx + 2 * S], a3 = a4[idx + 3 * S];
  float4 bv = *(const float4*)(bias + (idx & 255) * 4);
  float4 o = *(const float4*)(out + (size_t)idx * 4);
  o.x += (a0.x + a1.x) + (a2.x + a3.x) + bv.x;
  o.y += (a0.y + a1.y) + (a2.y + a3.y) + bv.y;
  o.z += (a0.z + a1.z) + (a2.z + a3.z) + bv.z;
  o.w += (a0.w + a1.w) + (a2.w + a3.w) + bv.w;
  *(float4*)(out + (size_t)idx * 4) = o;
}

// ---------------- MFMA flash attention (pure, R4/R12 proven form) ---------
// K double-buffered, V single-buffered, 2 barriers/iter, 4 blocks/CU,
// partitioned outputs (plain stores, no atomics). SPLIT=2.
template<int SPLIT>
__global__ __launch_bounds__(256) void attn_mfma(
    const u16* __restrict__ qkv, const u16* __restrict__ vt,
    const float* __restrict__ sz, float* __restrict__ opart,
    float* __restrict__ lpart)
{
  const int h   = blockIdx.y;
  const int q0  = blockIdx.x * 64;
  const int tid = threadIdx.x;
  const int lane = tid & 63;
  const int w    = tid >> 6;
  const int col  = lane & 15;
  const int quad = lane >> 4;

  __shared__ u16 Ks [2][64 * 64] __attribute__((aligned(16)));
  __shared__ u16 Vts[64 * 64] __attribute__((aligned(16)));
  __shared__ u16 Ps[4][16 * 72] __attribute__((aligned(16)));
  __shared__ float lball[N_TOK / SPLIT];

  bf16x8 qf[2];
  {
    const u16* qp = qkv + (size_t)(q0 + w * 16 + col) * 3072 + h * 64 + quad * 8;
    qf[0] = *(const bf16x8*)(qp);
    qf[1] = *(const bf16x8*)(qp + 32);
  }

  float l_lane = 0.f;
  f32x4 oacc[4] = {};

  const int rl = lane >> 3;
  const int cg = (lane & 7) ^ rl;
  const int kb = blockIdx.z * (N_TOK / SPLIT);
  const int ke = kb + N_TOK / SPLIT;

  constexpr float kScaleLog2e = 0.18033688011112042f;  // 0.125*log2(e)

  #pragma unroll
  for (int i = 0; i < 2; i++) {
    const int r = w * 16 + i * 8 + rl;
    __builtin_amdgcn_global_load_lds(
        (const __attribute__((address_space(1))) void*)(qkv + (size_t)(kb + r) * 3072 + 1024 + h * 64 + cg * 8),
        (__attribute__((address_space(3))) void*)(&Ks[0][(w * 16 + i * 8) * 64]),
        16, 0, 0);
    __builtin_amdgcn_global_load_lds(
        (const __attribute__((address_space(1))) void*)(vt + (size_t)(h * 64 + r) * 2048 + kb + cg * 8),
        (__attribute__((address_space(3))) void*)(&Vts[(w * 16 + i * 8) * 64]),
        16, 0, 0);
  }
  #pragma unroll
  for (int i = tid; i < N_TOK / SPLIT; i += 256)
    lball[i] = __builtin_amdgcn_logf(sz[kb + i]);   // v_log_f32 = log2
  __syncthreads();

  int cur = 0;
  for (int kt = kb; kt < ke; kt += 64) {
    const int nxt = cur ^ 1;
    const bool has_next = (kt + 64 < ke);

    if (has_next) {
      #pragma unroll
      for (int i = 0; i < 2; i++) {
        const int r = w * 16 + i * 8 + rl;
        __builtin_amdgcn_global_load_lds(
            (const __attribute__((address_space(1))) void*)(qkv + (size_t)(kt + 64 + r) * 3072 + 1024 + h * 64 + cg * 8),
            (__attribute__((address_space(3))) void*)(&Ks[nxt][(w * 16 + i * 8) * 64]),
            16, 0, 0);
      }
    }

    const u16* Kc = Ks[cur];
    f32x4 sacc[4] = {};
    #pragma unroll
    for (int kk = 0; kk < 2; kk++) {
      const int slot = (kk * 4 + quad) ^ (lane & 7);
      bf16x8 kf[4];
      #pragma unroll
      for (int jt = 0; jt < 4; jt++)
        kf[jt] = *(const bf16x8*)&Kc[(jt * 16 + col) * 64 + slot * 8];
      __builtin_amdgcn_s_setprio(1);
      #pragma unroll
      for (int jt = 0; jt < 4; jt++)
        sacc[jt] = __builtin_amdgcn_mfma_f32_16x16x32_bf16(kf[jt], qf[kk], sacc[jt], 0, 0, 0);
      __builtin_amdgcn_s_setprio(0);
    }

    u16* pw = Ps[w];
    const float* lbp = &lball[kt - kb];
    #pragma unroll
    for (int jt = 0; jt < 4; jt++) {
      float4 lb4 = *(const float4*)&lbp[jt * 16 + quad * 4];
      const float p0 = __builtin_amdgcn_exp2f(fmaf(sacc[jt][0], kScaleLog2e, lb4.x));
      const float p1 = __builtin_amdgcn_exp2f(fmaf(sacc[jt][1], kScaleLog2e, lb4.y));
      const float p2 = __builtin_amdgcn_exp2f(fmaf(sacc[jt][2], kScaleLog2e, lb4.z));
      const float p3 = __builtin_amdgcn_exp2f(fmaf(sacc[jt][3], kScaleLog2e, lb4.w));
      l_lane += (p0 + p1) + (p2 + p3);
      uint2 pkk;
      pkk.x = cvt_pk_bf16(p0, p1);
      pkk.y = cvt_pk_bf16(p2, p3);
      *(uint2*)&pw[col * 72 + jt * 16 + quad * 4] = pkk;
    }
    bf16x8 pf[2];
    #pragma unroll
    for (int kk = 0; kk < 2; kk++)
      pf[kk] = *(const bf16x8*)&pw[col * 72 + kk * 32 + quad * 8];

    __syncthreads();

    #pragma unroll
    for (int kk = 0; kk < 2; kk++) {
      const int slot = (kk * 4 + quad) ^ (lane & 7);
      bf16x8 vf[4];
      #pragma unroll
      for (int nt = 0; nt < 4; nt++)
        vf[nt] = *(const bf16x8*)&Vts[(nt * 16 + col) * 64 + slot * 8];
      __builtin_amdgcn_s_setprio(1);
      #pragma unroll
      for (int nt = 0; nt < 4; nt++)
        oacc[nt] = __builtin_amdgcn_mfma_f32_16x16x32_bf16(pf[kk], vf[nt], oacc[nt], 0, 0, 0);
      __builtin_amdgcn_s_setprio(0);
    }

    __syncthreads();

    if (has_next) {
      #pragma unroll
      for (int i = 0; i < 2; i++) {
        const int r = w * 16 + i * 8 + rl;
        __builtin_amdgcn_global_load_lds(
            (const __attribute__((address_space(1))) void*)(vt + (size_t)(h * 64 + r) * 2048 + kt + 64 + cg * 8),
            (__attribute__((address_space(3))) void*)(&Vts[(w * 16 + i * 8) * 64]),
            16, 0, 0);
      }
    }
    cur = nxt;
  }

  l_lane += __shfl_xor(l_lane, 16);
  l_lane += __shfl_xor(l_lane, 32);

  float* osl = opart + (size_t)blockIdx.z * ((size_t)N_TOK * 1024);
  #pragma unroll
  for (int r = 0; r < 4; r++) {
    const int q = q0 + w * 16 + quad * 4 + r;
    float* op = osl + (size_t)q * 1024 + h * 64 + col;
    #pragma unroll
    for (int nt = 0; nt < 4; nt++)
      op[nt * 16] = oacc[nt][r];
  }
  if (quad == 0)
    lpart[(size_t)blockIdx.z * (N_TOK * 16) + (q0 + w * 16 + col) * 16 + h] = l_lane;
}

// ------ fused attn-normalize + merge-score (independent work, packed) -----
__global__ __launch_bounds__(256) void norm_score_kernel(
    const float* __restrict__ opart, const float* __restrict__ lpart,
    u16* __restrict__ xa,
    const float* __restrict__ metric, const float* __restrict__ thr,
    int* __restrict__ mask, int* __restrict__ node)
{
  __shared__ float a[4][64];
  __shared__ float bw_[4][4];
  __shared__ int biw_[4][4];
  const int bid = blockIdx.x;
  const int t = threadIdx.x;
  if (bid < 2048) {
    const int q = bid;
    const int c = t * 4;
    float4 o0 = *(const float4*)(opart + (size_t)q * 1024 + c);
    float4 o1 = *(const float4*)(opart + (size_t)N_TOK * 1024 + (size_t)q * 1024 + c);
    const float l0 = lpart[q * 16 + (c >> 6)];
    const float l1 = lpart[N_TOK * 16 + q * 16 + (c >> 6)];
    const float inv = 1.0f / (l0 + l1);
    ushort4 o4;
    o4.x = f2bf((o0.x + o1.x) * inv); o4.y = f2bf((o0.y + o1.y) * inv);
    o4.z = f2bf((o0.z + o1.z) * inv); o4.w = f2bf((o0.w + o1.w) * inv);
    *(ushort4*)(xa + (size_t)q * 1024 + c) = o4;
    return;
  }
  const int s0 = (bid - 2048) * 4;
  a[t >> 6][t & 63] = metric[(size_t)(2 * (s0 + (t >> 6))) * 64 + (t & 63)];
  __syncthreads();
  float best[4] = {-INFINITY, -INFINITY, -INFINITY, -INFINITY};
  int besti[4] = {0, 0, 0, 0};
  for (int m = t; m < 1024; m += 256) {
    const float* bp = metric + (size_t)(2 * m + 1) * 64;
    float s[4] = {0.f, 0.f, 0.f, 0.f};
    #pragma unroll
    for (int d = 0; d < 64; d += 4) {
      float4 bv = *(const float4*)(bp + d);
      #pragma unroll
      for (int j = 0; j < 4; j++) {
        float4 av = *(const float4*)&a[j][d];
        s[j] += av.x*bv.x + av.y*bv.y + av.z*bv.z + av.w*bv.w;
      }
    }
    #pragma unroll
    for (int j = 0; j < 4; j++)
      if (s[j] > best[j]) { best[j] = s[j]; besti[j] = m; }   // ascending m
  }
  #pragma unroll
  for (int j = 0; j < 4; j++) {
    float b = best[j]; int bi = besti[j];
    #pragma unroll
    for (int off = 1; off < 64; off <<= 1) {
      float ov = __shfl_xor(b, off);
      int   oi = __shfl_xor(bi, off);
      if (ov > b || (ov == b && oi < bi)) { b = ov; bi = oi; }
    }
    best[j] = b; besti[j] = bi;
  }
  const int wv = t >> 6;
  if ((t & 63) == 0) {
    #pragma unroll
    for (int j = 0; j < 4; j++) { bw_[wv][j] = best[j]; biw_[wv][j] = besti[j]; }
  }
  __syncthreads();
  if (t < 4) {
    const int j = t;
    float b = bw_[0][j]; int bi = biw_[0][j];
    for (int ww = 1; ww < 4; ww++)
      if (bw_[ww][j] > b || (bw_[ww][j] == b && biw_[ww][j] < bi)) { b = bw_[ww][j]; bi = biw_[ww][j]; }
    const int n = s0 + j;
    if (n == 0) { mask[0] = 0; node[0] = 0; }
    else { mask[n] = (b > thr[0]) ? 1 : 0; node[n] = bi; }
  }
}

// ------ build merged rows; scan folded in (pos computed per-block) --------
__global__ __launch_bounds__(256) void build_kernel(
    const float* __restrict__ xres, const float* __restrict__ sz,
    const int* __restrict__ mask, float* __restrict__ xm,
    float* __restrict__ sizem, int U)
{
  const int b = blockIdx.x;
  const int t = threadIdx.x;
  __shared__ int red[4];
  int srow, orow;
  if (b < 1024) { srow = 2 * b + 1; orow = U + b; }
  else {
    const int i = b - 1024;
    if (mask[i]) return;
    int cnt = 0;
    for (int j = t; j < i; j += 256) cnt += mask[j] ? 0 : 1;
    #pragma unroll
    for (int off = 1; off < 64; off <<= 1) cnt += __shfl_xor(cnt, off);
    if ((t & 63) == 0) red[t >> 6] = cnt;
    __syncthreads();
    orow = red[0] + red[1] + red[2] + red[3];
    srow = 2 * i;
  }
  const float ssz = sz[srow];
  const float* xp = xres + (size_t)srow * 1024;
  float* op = xm + (size_t)orow * 1024;
  const int c = t * 4;
  float4 v = *(const float4*)(xp + c);
  v.x *= ssz; v.y *= ssz; v.z *= ssz; v.w *= ssz;
  *(float4*)(op + c) = v;
  if (t == 0) sizem[orow] = ssz;
}

// ---------------- scatter-add merged src tokens into dst rows -------------
__global__ __launch_bounds__(256) void merge_add_kernel(
    const float* __restrict__ xres, const float* __restrict__ sz,
    const int* __restrict__ mask, const int* __restrict__ node,
    float* __restrict__ xm, float* __restrict__ sizem, int U)
{
  const int i = blockIdx.x;
  if (!mask[i]) return;
  const int t = threadIdx.x;
  const int srow = 2 * i;
  const int orow = U + node[i];
  const float ssz = sz[srow];
  const float* xp = xres + (size_t)srow * 1024;
  float* op = xm + (size_t)orow * 1024;
  for (int c = t; c < 1024; c += 256)
    atomicAdd(op + c, xp[c] * ssz);
  if (t == 0) atomicAdd(sizem + orow, ssz);
}

extern "C" void kernel_launch(void* const* d_in, const int* in_sizes, int n_in,
                              void* d_out, int out_size, void* d_ws, size_t ws_size,
                              hipStream_t stream) {
  const float* x      = (const float*)d_in[0];
  const float* sz     = (const float*)d_in[1];
  const float* qkv_w  = (const float*)d_in[2];
  const float* proj_w = (const float*)d_in[3];
  const float* proj_b = (const float*)d_in[4];
  const float* ln1_g  = (const float*)d_in[5];
  const float* ln1_b  = (const float*)d_in[6];
  const float* ln2_g  = (const float*)d_in[7];
  const float* ln2_b  = (const float*)d_in[8];
  const float* fc1_w  = (const float*)d_in[9];
  const float* fc1_b  = (const float*)d_in[10];
  const float* fc2_w  = (const float*)d_in[11];
  const float* fc2_b  = (const float*)d_in[12];
  const float* thr    = (const float*)d_in[13];

  const int M = out_size / 1025;
  const int U = M - 1024;
  const size_t MB = 1u << 20;
  const size_t KB = 1u << 10;

  // workspace layout (ws = 256 MiB):
  //  [0,6)   w_qkvT          [6,7)   wbar/met/mask/node
  //  [7,7.25) lpart          [8,10)  w_projT
  //  [10,22) b_qkv -> b_xa[10,14) -> b_xm[10,18)
  //  [22,30) b_hf (live through qkv_metric) -> b_xres (after metric)
  //  [30,34) b_h (dead after QKV GEMM)
  //  [71,79) w_fc1T  [79,87) w_fc2T  [87,104) b_g
  //  [104,108) b_h2  [108,142) b_facc  [142,146) vt
  //  [146,162) opart
  char* ws = (char*)d_ws;
  u16*   w_qkvT  = (u16*)(ws + 0);
  float* b_wbar  = (float*)(ws + 6 * MB);
  float* b_met   = (float*)(ws + 6 * MB + 256 * KB);
  int*   b_mask  = (int*)(ws + 6 * MB + 768 * KB);
  int*   b_node  = b_mask + 1024;
  float* b_szm   = (float*)(b_node + 1024);
  float* b_lpart = (float*)(ws + 7 * MB);            // 2 x 128KB slices
  u16*   w_projT = (u16*)(ws + 8 * MB);
  u16*   b_qkv   = (u16*)(ws + 10 * MB);
  u16*   b_xa    = (u16*)(ws + 10 * MB);   // over dead b_qkv (after attn)
  float* b_xm    = (float*)(ws + 10 * MB);   // over dead b_xa (after proj)
  float* b_hf    = (float*)(ws + 22 * MB);
  float* b_xres  = (float*)(ws + 22 * MB);   // over dead b_hf (post-metric)
  u16*   b_h     = (u16*)(ws + 30 * MB);
  u16*   w_fc1T  = (u16*)(ws + 71 * MB);
  u16*   w_fc2T  = (u16*)(ws + 79 * MB);
  u16*   b_g     = (u16*)(ws + 87 * MB);
  u16*   b_h2    = (u16*)(ws + 104 * MB);
  float* b_facc  = (float*)(ws + 108 * MB);  // 4 partitioned slices
  u16*   b_vt    = (u16*)(ws + 142 * MB);    // written by QKV GEMM
  float* b_opart = (float*)(ws + 146 * MB);  // 2 x 8MB slices

  float* outx = (float*)d_out;
  float* outs = outx + (size_t)M * 1024;

  // 1. fused opening launch: LN1 + ALL weight converts + wbar
  fused_pre_kernel<<<14592, 256, 0, stream>>>(
      x, ln1_g, ln1_b, b_h, b_hf,
      qkv_w, w_qkvT, proj_w, w_projT, fc1_w, w_fc1T, fc2_w, w_fc2T, b_wbar);
  // 2. fused QKV GEMM (+V transpose out) + metric (768 GEMM + 512 metric)
  qkv_metric_kernel<<<1280, 256, 0, stream>>>(
      b_h, w_qkvT, b_vt, b_qkv, b_hf, b_wbar, b_met);
  // 3. pure MFMA attention (R12-proven form, 40.4us)
  attn_mfma<2><<<dim3(32, 16, 2), 256, 0, stream>>>(b_qkv, b_vt, sz, b_opart, b_lpart);
  // 4. fused attn-normalize + merge-score (independent, packed)
  norm_score_kernel<<<2304, 256, 0, stream>>>(b_opart, b_lpart, b_xa, b_met, thr, b_mask, b_node);
  // 5. proj GEMM + bias + residual(x) -> xres fp32 — 512 blocks
  gemm_mfma<64, 64, 1, true, false, true, false><<<dim3(16, 32), 256, 0, stream>>>(
      b_xa, w_projT, proj_b, x, b_xres, 2048, 1024, 1024);
  // 6. build merged rows (scan folded in)
  build_kernel<<<2048, 256, 0, stream>>>(b_xres, sz, b_mask, b_xm, b_szm, U);
  // 7. scatter-add merged src tokens
  merge_add_kernel<<<1024, 256, 0, stream>>>(b_xres, sz, b_mask, b_node, b_xm, b_szm, U);
  // 8. fused divide + LN2 (one block per row): outx, outs, h2
  divide_ln2_kernel<<<M, 256, 0, stream>>>(b_xm, b_szm, ln2_g, ln2_b, outx, outs, b_h2);
  // 9. fc1 + bias + exact GELU -> bf16 — 768 blocks
  gemm_mfma<128, 64, 1, true, true, false, true><<<dim3(64, (M + 127) / 128), 256, 0, stream>>>(
      b_h2, w_fc1T, fc1_b, nullptr, b_g, M, 4096, 1024);
  // 10. fc2 split-K=4, partitioned slices (no memset, no atomics)
  gemm_mfma<128, 64, 4, false, false, false, false><<<dim3(16, (M + 127) / 128, 4), 256, 0, stream>>>(
      b_g, w_fc2T, nullptr, nullptr, b_facc, M, 1024, 4096);
  // 11. fc2 epilogue: outx += sum(4 slices) + bias (residual in-place)
  splitk_epilogue_kernel<<<(M * 256 + 255) / 256, 256, 0, stream>>>(
      b_facc, fc2_b, outx, M);
  (void)in_sizes; (void)n_in; (void)ws_size;
}